// Round 18
// baseline (964.793 us; speedup 1.0000x reference)
//
#include <hip/hip_runtime.h>

// Problem constants: B=4096, K=16, H=32, HM=128, STEPS=8
#define OFF_MS  524288
#define OFF_CS  557056
#define OFF_IP  1081344
#define OFF_CUM 1179648
#define OFF_EPS 1183744

#define HSTR 136   // padded bf16 row stride (272B -> 2-way banks)
#define BSTR 40    // padded bf16 row stride (80B)

// d_ws layout (u16): bf16 weights transposed to [n][k]
#define WA_PTP 0        // ptp_w2T [32][128]
#define WB_PTA 4096     // pta_w1T [128][32]
#define WC_PTA 8192     // pta_w2T [32][128]
#define WA_CAP 12288    // cap_w2T [32][128]
#define WB_CAA 16384    // caa_w1T [128][32]
#define WC_CAA 20480    // caa_w2T [32][128]

struct Params {
  const float *knn, *query, *fw1, *fb1, *fw2, *fb2, *fw3, *fb3, *qkv_w,
    *ptp_w1, *ptp_b1, *ptp_w2, *ptp_b2, *pta_w1, *pta_b1, *pta_w2, *pta_b2,
    *caq_w, *caq_b, *cak_w, *cak_b, *cav_w, *cav_b,
    *cap_w1, *cap_b1, *cap_w2, *cap_b2, *caa_w1, *caa_b1, *caa_w2, *caa_b2,
    *im_w1, *im_b1, *im_w2, *im_b2, *im_w3, *im_b3,
    *ep_w1, *ep_b1, *ep_w2, *ep_b2, *ep_w3, *ep_b3;
  float *o_ld, *o_ms, *o_cs, *o_ip, *o_cum, *o_eps;
};
static_assert(sizeof(Params) == 49 * sizeof(void*), "Params layout");

typedef float f32x4 __attribute__((ext_vector_type(4)));
typedef unsigned short u16x8 __attribute__((ext_vector_type(8)));

__device__ __forceinline__ unsigned short f2b(float x) {  // fp32->bf16 RNE
  unsigned u = __float_as_uint(x);
  u += 0x7fffu + ((u >> 16) & 1u);
  return (unsigned short)(u >> 16);
}
__device__ __forceinline__ float b2f(unsigned short x) {
  return __uint_as_float((unsigned)x << 16);
}
__device__ __forceinline__ unsigned pack2(float lo, float hi) {
  return (unsigned)f2b(lo) | ((unsigned)f2b(hi) << 16);
}

#define MFMA(acc, a, bb) \
  asm volatile("s_nop 2\n\tv_mfma_f32_16x16x32_bf16 %0, %1, %2, %0" \
               : "+v"(acc) : "v"(a), "v"(bb))
#define MFMA_FENCE(acc) asm volatile("s_nop 7\n\ts_nop 7" : "+v"(acc))

// Prep: transpose+convert the 6 MFMA weight matrices into d_ws (once/launch).
__global__ void prep_kernel(Params p, unsigned short* ws) {
  const int t = blockIdx.x * 256 + threadIdx.x;  // 0..4095
  const int n = t >> 7, k = t & 127;
  ws[WA_PTP + t] = f2b(p.ptp_w2[k * 32 + n]);
  ws[WC_PTA + t] = f2b(p.pta_w2[k * 32 + n]);
  ws[WA_CAP + t] = f2b(p.cap_w2[k * 32 + n]);
  ws[WC_CAA + t] = f2b(p.caa_w2[k * 32 + n]);
  const int n2 = t >> 5, k2 = t & 31;
  ws[WB_PTA + t] = f2b(p.pta_w1[k2 * 128 + n2]);
  ws[WB_CAA + t] = f2b(p.caa_w1[k2 * 128 + n2]);
}

// WAVE-PER-BATCH (round 16: 452us, 120 VGPR, no spill). Round 17 showed the
// real occupancy limiter is LDS: 18.9KB/block -> exactly 8 blocks/CU.
// This round shrinks LDS to ~12.3KB -> 13 blocks/CU:
//  (1) s_hvb/s_hidb UNION (never simultaneously live: hv dies after
//      G1/secB, then G2/secC writes the hid tile; same-array accesses keep
//      DS ordering conservative -> correct without barriers).
//  (2) s_u scratch stored as bf16 (h1/h2, q|k, kk|vvb) -- every consumer
//      already passes through a bf16 rounding on the same path.
__launch_bounds__(64, 4)
__global__ void puray_kernel(Params p, const unsigned short* ws) {
  const int b = blockIdx.x;
  const int l = threadIdx.x;
  const int ln16 = l & 15, kg = l >> 4, k0 = kg * 8;

  __shared__ __align__(16) unsigned short s_work[16 * HSTR];  // hv THEN hid
  __shared__ __align__(16) unsigned short s_simb[16 * BSTR];
  __shared__ __align__(16) unsigned short s_ub[1024];  // bf16: h1|h2 ; q|k ; kk|vvb
  __shared__ float s_feats[512], s_v[512];
  __shared__ float s_coords[48], s_relv[48], s_reld[16];
  __shared__ float s_qry[3], s_op[3], s_qq[32], s_ca[32];
  __shared__ float s_cum;

  if (l < 48) s_coords[l] = p.knn[b * 48 + l];
  else if (l < 51) s_qry[l - 48] = p.query[b * 3 + (l - 48)];
  else if (l == 51) s_cum = 0.f;
  else if (l < 55) s_op[l - 52] = 0.f;
  __syncthreads();

  // ---- Phase A: feats (h1 -> s_ub[0:512], h2 -> s_ub[512:1024]) ----
  for (int m = 0; m < 8; ++m) {
    const int idx = l + 64 * m, pp = idx >> 5, jj = idx & 31;
    float a = p.fb1[jj];
    for (int c = 0; c < 3; ++c) a = fmaf(s_coords[pp * 3 + c], p.fw1[c * 32 + jj], a);
    s_ub[idx] = f2b(fmaxf(a, 0.f));
  }
  for (int m = 0; m < 8; ++m) {
    const int idx = l + 64 * m, pp = idx >> 5, jj = idx & 31;
    float a = p.fb2[jj];
    for (int i = 0; i < 32; ++i) a = fmaf(b2f(s_ub[pp * 32 + i]), p.fw2[i * 32 + jj], a);
    s_ub[512 + idx] = f2b(fmaxf(a, 0.f));
  }
  for (int m = 0; m < 8; ++m) {
    const int idx = l + 64 * m, pp = idx >> 5, jj = idx & 31;
    float a = p.fb3[jj];
    for (int i = 0; i < 32; ++i) a = fmaf(b2f(s_ub[512 + pp * 32 + i]), p.fw3[i * 32 + jj], a);
    s_feats[idx] = a;
  }
  // ---- Phase B: qkv -> s_ub (q|k) + s_v ----
  for (int m = 0; m < 24; ++m) {
    const int idx = l + 64 * m, pp = idx / 96, o = idx % 96;
    float a = 0.f;
    for (int i = 0; i < 32; ++i) a = fmaf(s_feats[pp * 32 + i], p.qkv_w[i * 96 + o], a);
    if (o < 32) s_ub[pp * 32 + o] = f2b(a);
    else if (o < 64) s_ub[512 + pp * 32 + o - 32] = f2b(a);
    else s_v[pp * 32 + o - 64] = a;
  }

  // ---- Phase C: one i-row at a time, all within the wave ----
  {
    const float* w1c = p.ptp_w1;
    const float* b1c = p.ptp_b1;
    const float* b2c = p.ptp_b2;
    const float* bh1 = p.pta_b1;
    const float* bh2 = p.pta_b2;
    const unsigned short* wsc = ws;
    for (int i = 0; i < 16; ++i) {
      asm volatile("" : "+s"(w1c), "+s"(b1c), "+s"(b2c), "+s"(bh1), "+s"(bh2), "+s"(wsc));
      const float c0 = s_coords[i * 3 + 0] - s_coords[ln16 * 3 + 0];
      const float c1 = s_coords[i * 3 + 1] - s_coords[ln16 * 3 + 1];
      const float c2 = s_coords[i * 3 + 2] - s_coords[ln16 * 3 + 2];
      // hv -> s_work (row ln16, d = kg*32 .. kg*32+31; 2 live values only)
      for (int x = 0; x < 32; x += 2) {
        const int d = kg * 32 + x;
        const float h0v = fmaxf(fmaf(c0, w1c[d],
                           fmaf(c1, w1c[128 + d],
                           fmaf(c2, w1c[256 + d], b1c[d]))), 0.f);
        const float h1v = fmaxf(fmaf(c0, w1c[d + 1],
                           fmaf(c1, w1c[128 + d + 1],
                           fmaf(c2, w1c[256 + d + 1], b1c[d + 1]))), 0.f);
        ((unsigned*)s_work)[(ln16 * HSTR + d) >> 1] = pack2(h0v, h1v);
      }
      f32x4 rpe0, rpe1;
      {  // G1 nb=0: rpe = hv @ ptp_w2 + b2 (A from LDS)
        const int n = ln16;
        const float bias = b2c[n];
        f32x4 acc = {bias, bias, bias, bias};
#pragma unroll
        for (int kk = 0; kk < 4; ++kk) {
          const u16x8 a = *(const u16x8*)&s_work[ln16 * HSTR + kk * 32 + k0];
          MFMA(acc, a, *(const u16x8*)&wsc[WA_PTP + n * 128 + kk * 32 + k0]);
        }
        MFMA_FENCE(acc);
        rpe0 = acc;
#pragma unroll
        for (int r2 = 0; r2 < 4; ++r2) {
          const int j = kg * 4 + r2;
          s_simb[j * BSTR + n] =
            f2b(b2f(s_ub[i * 32 + n]) - b2f(s_ub[512 + j * 32 + n]) + acc[r2]);
        }
      }
      {  // G1 nb=1
        const int n = 16 + ln16;
        const float bias = b2c[n];
        f32x4 acc = {bias, bias, bias, bias};
#pragma unroll
        for (int kk = 0; kk < 4; ++kk) {
          const u16x8 a = *(const u16x8*)&s_work[ln16 * HSTR + kk * 32 + k0];
          MFMA(acc, a, *(const u16x8*)&wsc[WA_PTP + n * 128 + kk * 32 + k0]);
        }
        MFMA_FENCE(acc);
        rpe1 = acc;
#pragma unroll
        for (int r2 = 0; r2 < 4; ++r2) {
          const int j = kg * 4 + r2;
          s_simb[j * BSTR + n] =
            f2b(b2f(s_ub[i * 32 + n]) - b2f(s_ub[512 + j * 32 + n]) + acc[r2]);
        }
      }
      {  // G2: hid[16][128] = relu(simin @ pta_w1 + b1) -> s_work (hv dead)
        const u16x8 a2 = *(const u16x8*)&s_simb[ln16 * BSTR + k0];
#pragma unroll
        for (int j2 = 0; j2 < 8; ++j2) {
          const int n = j2 * 16 + ln16;
          const float bias = bh1[n];
          f32x4 acc = {bias, bias, bias, bias};
          MFMA(acc, a2, *(const u16x8*)&wsc[WB_PTA + n * 32 + k0]);
          MFMA_FENCE(acc);
#pragma unroll
          for (int r2 = 0; r2 < 4; ++r2)
            s_work[(kg * 4 + r2) * HSTR + n] = f2b(fmaxf(acc[r2], 0.f));
        }
      }
      // G3 + fused softmax -> feats[i]
#pragma unroll
      for (int nb = 0; nb < 2; ++nb) {
        const int n = nb * 16 + ln16;
        const float bias = bh2[n];
        f32x4 acc = {bias, bias, bias, bias};
#pragma unroll
        for (int kk = 0; kk < 4; ++kk) {
          const u16x8 a3 = *(const u16x8*)&s_work[ln16 * HSTR + kk * 32 + k0];
          MFMA(acc, a3, *(const u16x8*)&wsc[WC_PTA + n * 128 + kk * 32 + k0]);
        }
        MFMA_FENCE(acc);
        const f32x4 rp = nb ? rpe1 : rpe0;
        float mx = fmaxf(fmaxf(acc[0], acc[1]), fmaxf(acc[2], acc[3]));
        mx = fmaxf(mx, __shfl_xor(mx, 16));
        mx = fmaxf(mx, __shfl_xor(mx, 32));
        float sum = 0.f, o = 0.f;
#pragma unroll
        for (int r2 = 0; r2 < 4; ++r2) {
          const int j = kg * 4 + r2;
          const float e = __expf(acc[r2] - mx);
          sum += e;
          o = fmaf(e, s_v[j * 32 + n] + rp[r2], o);
        }
        sum += __shfl_xor(sum, 16); o += __shfl_xor(o, 16);
        sum += __shfl_xor(sum, 32); o += __shfl_xor(o, 32);
        if (kg == 0) s_feats[i * 32 + n] = o / sum;
      }
    }
  }

  // ---- kk / vvb (overwrite q|k in s_ub, bf16) ----
  for (int m = 0; m < 8; ++m) {
    const int idx = l + 64 * m, k = idx >> 5, h = idx & 31;
    float akk = p.cak_b[h], avv = p.cav_b[h];
    for (int i = 0; i < 32; ++i) {
      const float f = s_feats[k * 32 + i];
      akk = fmaf(f, p.cak_w[i * 32 + h], akk);
      avv = fmaf(f, p.cav_w[i * 32 + h], avv);
    }
    s_ub[k * 32 + h] = f2b(akk);
    s_ub[512 + k * 32 + h] = f2b(avv);
  }

  // ---- Phase D: 8 march steps + epilogue, all within the wave ----
  {
    const float* w1d = p.cap_w1;
    const float* b1d = p.cap_b1;
    const float* b2d = p.cap_b2;
    const float* bc1 = p.caa_b1;
    const float* bc2 = p.caa_b2;
    const float* fw1 = p.fw1; const float* fw2 = p.fw2; const float* fw3 = p.fw3;
    const float* cqw = p.caq_w;
    const float* iw1 = p.im_w1; const float* iw2 = p.im_w2; const float* iw3 = p.im_w3;
    const unsigned short* wsd = ws;
    for (int s = 0; s <= 8; ++s) {
      asm volatile("" : "+s"(w1d), "+s"(b1d), "+s"(b2d), "+s"(bc1), "+s"(bc2), "+s"(wsd));
      asm volatile("" : "+s"(fw1), "+s"(fw2), "+s"(fw3), "+s"(cqw), "+s"(iw1), "+s"(iw2), "+s"(iw3));
      float rv0 = 0.f, rv1 = 0.f, rv2 = 0.f;
      if (s < 8 && l < 16) {  // rel + o_ld
        const float r0 = s_coords[l * 3 + 0] - s_op[0];
        const float r1 = s_coords[l * 3 + 1] - s_op[1];
        const float r2 = s_coords[l * 3 + 2] - s_op[2];
        const float rd = sqrtf(r0 * r0 + r1 * r1 + r2 * r2);
        const float inv = 1.f / rd;
        rv0 = r0 * inv; rv1 = r1 * inv; rv2 = r2 * inv;
        s_reld[l] = rd;
        s_relv[l * 3 + 0] = rv0; s_relv[l * 3 + 1] = rv1; s_relv[l * 3 + 2] = rv2;
        p.o_ld[b * 128 + s * 16 + l] = rd;
      }
      // secA: pe-hidden hv -> s_work (row ln16, d = kg*32..+31)
      {
        float c0, c1, c2;
        if (s < 8) {
          c0 = s_coords[ln16 * 3 + 0] - s_op[0];
          c1 = s_coords[ln16 * 3 + 1] - s_op[1];
          c2 = s_coords[ln16 * 3 + 2] - s_op[2];
        } else {
          const float rd = s_reld[ln16];
          c0 = s_relv[ln16 * 3 + 0] * rd; c1 = s_relv[ln16 * 3 + 1] * rd; c2 = s_relv[ln16 * 3 + 2] * rd;
        }
        for (int x = 0; x < 32; x += 2) {
          const int d = kg * 32 + x;
          const float h0v = fmaxf(fmaf(c0, w1d[d],
                             fmaf(c1, w1d[128 + d],
                             fmaf(c2, w1d[256 + d], b1d[d]))), 0.f);
          const float h1v = fmaxf(fmaf(c0, w1d[d + 1],
                             fmaf(c1, w1d[128 + d + 1],
                             fmaf(c2, w1d[256 + d + 1], b1d[d + 1]))), 0.f);
          ((unsigned*)s_work)[(ln16 * HSTR + d) >> 1] = pack2(h0v, h1v);
        }
      }
      {  // qq chain (all lanes, width-32 shuffles; halves duplicate)
        const int h = l & 31;
        float opc0, opc1, opc2;
        if (s < 8) {
          const float cum = s_cum;
          opc0 = s_qry[0] * cum; opc1 = s_qry[1] * cum; opc2 = s_qry[2] * cum;
        } else {
          opc0 = s_op[0]; opc1 = s_op[1]; opc2 = s_op[2];
        }
        float v1 = fmaxf(fmaf(opc0, fw1[h],
                      fmaf(opc1, fw1[32 + h],
                      fmaf(opc2, fw1[64 + h], p.fb1[h]))), 0.f);
        float a = p.fb2[h];
        for (int i2 = 0; i2 < 32; ++i2) a = fmaf(__shfl(v1, i2, 32), fw2[i2 * 32 + h], a);
        const float v2 = fmaxf(a, 0.f);
        a = p.fb3[h];
        for (int i2 = 0; i2 < 32; ++i2) a = fmaf(__shfl(v2, i2, 32), fw3[i2 * 32 + h], a);
        const float opf = a;
        a = p.caq_b[h];
        for (int i2 = 0; i2 < 32; ++i2) a = fmaf(__shfl(opf, i2, 32), cqw[i2 * 32 + h], a);
        if (l < 32) s_qq[h] = a;
      }
      f32x4 pe0, pe1;
      {  // secB nb=0: pe = hv @ cap_w2 + b2 (A from LDS)
        const int n = ln16;
        const float bias = b2d[n];
        f32x4 acc = {bias, bias, bias, bias};
#pragma unroll
        for (int kk = 0; kk < 4; ++kk) {
          const u16x8 a = *(const u16x8*)&s_work[ln16 * HSTR + kk * 32 + k0];
          MFMA(acc, a, *(const u16x8*)&wsd[WA_CAP + n * 128 + kk * 32 + k0]);
        }
        MFMA_FENCE(acc);
        pe0 = acc;
#pragma unroll
        for (int r2 = 0; r2 < 4; ++r2) {
          const int row = kg * 4 + r2;
          s_simb[row * BSTR + n] = f2b(s_qq[n] - b2f(s_ub[row * 32 + n]) + acc[r2]);
        }
      }
      {  // secB nb=1
        const int n = 16 + ln16;
        const float bias = b2d[n];
        f32x4 acc = {bias, bias, bias, bias};
#pragma unroll
        for (int kk = 0; kk < 4; ++kk) {
          const u16x8 a = *(const u16x8*)&s_work[ln16 * HSTR + kk * 32 + k0];
          MFMA(acc, a, *(const u16x8*)&wsd[WA_CAP + n * 128 + kk * 32 + k0]);
        }
        MFMA_FENCE(acc);
        pe1 = acc;
#pragma unroll
        for (int r2 = 0; r2 < 4; ++r2) {
          const int row = kg * 4 + r2;
          s_simb[row * BSTR + n] = f2b(s_qq[n] - b2f(s_ub[row * 32 + n]) + acc[r2]);
        }
      }
      {  // secC: hid = relu(ain @ caa_w1 + b1) -> s_work (hv dead)
        const u16x8 a2 = *(const u16x8*)&s_simb[ln16 * BSTR + k0];
#pragma unroll
        for (int j2 = 0; j2 < 8; ++j2) {
          const int n = j2 * 16 + ln16;
          const float bias = bc1[n];
          f32x4 acc = {bias, bias, bias, bias};
          MFMA(acc, a2, *(const u16x8*)&wsd[WB_CAA + n * 32 + k0]);
          MFMA_FENCE(acc);
#pragma unroll
          for (int r2 = 0; r2 < 4; ++r2)
            s_work[(kg * 4 + r2) * HSTR + n] = f2b(fmaxf(acc[r2], 0.f));
        }
      }
      // secD + in-register softmax -> ca0/ca1
      float ca0 = 0.f, ca1 = 0.f;
#pragma unroll
      for (int nb = 0; nb < 2; ++nb) {
        const int n = nb * 16 + ln16;
        const float bias = bc2[n];
        f32x4 acc = {bias, bias, bias, bias};
#pragma unroll
        for (int kk = 0; kk < 4; ++kk) {
          const u16x8 a3 = *(const u16x8*)&s_work[ln16 * HSTR + kk * 32 + k0];
          MFMA(acc, a3, *(const u16x8*)&wsd[WC_CAA + n * 128 + kk * 32 + k0]);
        }
        MFMA_FENCE(acc);
        const f32x4 rp = nb ? pe1 : pe0;
        float mx = fmaxf(fmaxf(acc[0], acc[1]), fmaxf(acc[2], acc[3]));
        mx = fmaxf(mx, __shfl_xor(mx, 16));
        mx = fmaxf(mx, __shfl_xor(mx, 32));
        float sum = 0.f, o = 0.f;
#pragma unroll
        for (int r2 = 0; r2 < 4; ++r2) {
          const int row = kg * 4 + r2;
          const float e = __expf(acc[r2] - mx);
          sum += e;
          o = fmaf(e, b2f(s_ub[512 + row * 32 + n]) + rp[r2], o);
        }
        sum += __shfl_xor(sum, 16); o += __shfl_xor(o, 16);
        sum += __shfl_xor(sum, 32); o += __shfl_xor(o, 32);
        if (nb == 0) ca0 = o / sum; else ca1 = o / sum;
      }
      if (kg == 0) { s_ca[ln16] = ca0; s_ca[16 + ln16] = ca1; }
      {  // im / ep chain (width-32; halves duplicate; writes guarded)
        const int h = l & 31;
        const float cav = s_ca[h];
        if (s < 8) {
          float a = p.im_b1[h];
          for (int i2 = 0; i2 < 32; ++i2) a = fmaf(__shfl(cav, i2, 32), iw1[i2 * 32 + h], a);
          const float m1 = fmaxf(a, 0.f);
          a = p.im_b2[h];
          for (int i2 = 0; i2 < 32; ++i2) a = fmaf(__shfl(m1, i2, 32), iw2[i2 * 32 + h], a);
          const float m2 = fmaxf(a, 0.f);
          float p0 = m2 * iw3[h * 3 + 0];
          float p1 = m2 * iw3[h * 3 + 1];
          float p2 = m2 * iw3[h * 3 + 2];
#pragma unroll
          for (int m = 1; m < 32; m <<= 1) {
            p0 += __shfl_xor(p0, m, 32);
            p1 += __shfl_xor(p1, m, 32);
            p2 += __shfl_xor(p2, m, 32);
          }
          p0 += p.im_b3[0]; p1 += p.im_b3[1]; p2 += p.im_b3[2];
          const float step = sqrtf(p0 * p0 + p1 * p1 + p2 * p2);
          const float cum = s_cum;
          const float opc0 = s_qry[0] * cum, opc1 = s_qry[1] * cum, opc2 = s_qry[2] * cum;
          const float inv = 1.f / step;
          const float tg0 = p0 * inv, tg1 = p1 * inv, tg2 = p2 * inv;
          if (l == 0) {
            p.o_ms[b * 8 + s] = step;
            p.o_ip[(b * 8 + s) * 3 + 0] = opc0 + p0;
            s_op[0] = opc0 + s_qry[0] * step;
          } else if (l == 1) {
            p.o_ip[(b * 8 + s) * 3 + 1] = opc1 + p1;
            s_op[1] = opc1 + s_qry[1] * step;
          } else if (l == 2) {
            p.o_ip[(b * 8 + s) * 3 + 2] = opc2 + p2;
            s_op[2] = opc2 + s_qry[2] * step;
          } else if (l == 3) {
            s_cum = cum + step;
          }
          if (l < 16) {
            p.o_cs[b * 128 + s * 16 + l] = tg0 * rv0 + tg1 * rv1 + tg2 * rv2;
          }
        } else {
          float a = p.ep_b1[h];
          for (int i2 = 0; i2 < 32; ++i2) a = fmaf(__shfl(cav, i2, 32), p.ep_w1[i2 * 32 + h], a);
          a = fmaf(s_qry[0], p.ep_w1[1024 + h], a);
          a = fmaf(s_qry[1], p.ep_w1[1056 + h], a);
          a = fmaf(s_qry[2], p.ep_w1[1088 + h], a);
          const float e1 = fmaxf(a, 0.f);
          a = p.ep_b2[h];
          for (int i2 = 0; i2 < 32; ++i2) a = fmaf(__shfl(e1, i2, 32), p.ep_w2[i2 * 32 + h], a);
          const float e2 = fmaxf(a, 0.f);
          float pp = e2 * p.ep_w3[h];
#pragma unroll
          for (int m = 1; m < 32; m <<= 1) pp += __shfl_xor(pp, m, 32);
          if (l == 0) {
            p.o_eps[b] = pp + p.ep_b3[0];
            p.o_cum[b] = s_cum;
          }
        }
      }
    }
  }
}

extern "C" void kernel_launch(void* const* d_in, const int* in_sizes, int n_in,
                              void* d_out, int out_size, void* d_ws, size_t ws_size,
                              hipStream_t stream) {
  Params p;
  const float** f = (const float**)(void*)&p;
  for (int i = 0; i < 43; ++i) f[i] = (const float*)d_in[i];
  float* out = (float*)d_out;
  p.o_ld  = out;
  p.o_ms  = out + OFF_MS;
  p.o_cs  = out + OFF_CS;
  p.o_ip  = out + OFF_IP;
  p.o_cum = out + OFF_CUM;
  p.o_eps = out + OFF_EPS;
  unsigned short* ws = (unsigned short*)d_ws;
  prep_kernel<<<dim3(16), dim3(256), 0, stream>>>(p, ws);
  puray_kernel<<<dim3(4096), dim3(64), 0, stream>>>(p, ws);
}

// Round 19
// 658.963 us; speedup vs baseline: 1.4641x; 1.4641x over previous
//
#include <hip/hip_runtime.h>

// Problem constants: B=4096, K=16, H=32, HM=128, STEPS=8
#define OFF_MS  524288
#define OFF_CS  557056
#define OFF_IP  1081344
#define OFF_CUM 1179648
#define OFF_EPS 1183744

#define HSTR 136   // padded bf16 row stride (272B -> 2-way banks)
#define BSTR 40    // padded bf16 row stride (80B)

// d_ws layout (u16): bf16 weights transposed to [n][k]
#define WA_PTP 0        // ptp_w2T [32][128]
#define WB_PTA 4096     // pta_w1T [128][32]
#define WC_PTA 8192     // pta_w2T [32][128]
#define WA_CAP 12288    // cap_w2T [32][128]
#define WB_CAA 16384    // caa_w1T [128][32]
#define WC_CAA 20480    // caa_w2T [32][128]

struct Params {
  const float *knn, *query, *fw1, *fb1, *fw2, *fb2, *fw3, *fb3, *qkv_w,
    *ptp_w1, *ptp_b1, *ptp_w2, *ptp_b2, *pta_w1, *pta_b1, *pta_w2, *pta_b2,
    *caq_w, *caq_b, *cak_w, *cak_b, *cav_w, *cav_b,
    *cap_w1, *cap_b1, *cap_w2, *cap_b2, *caa_w1, *caa_b1, *caa_w2, *caa_b2,
    *im_w1, *im_b1, *im_w2, *im_b2, *im_w3, *im_b3,
    *ep_w1, *ep_b1, *ep_w2, *ep_b2, *ep_w3, *ep_b3;
  float *o_ld, *o_ms, *o_cs, *o_ip, *o_cum, *o_eps;
};
static_assert(sizeof(Params) == 49 * sizeof(void*), "Params layout");

typedef float f32x4 __attribute__((ext_vector_type(4)));
typedef unsigned short u16x8 __attribute__((ext_vector_type(8)));

__device__ __forceinline__ unsigned short f2b(float x) {  // fp32->bf16 RNE
  unsigned u = __float_as_uint(x);
  u += 0x7fffu + ((u >> 16) & 1u);
  return (unsigned short)(u >> 16);
}
__device__ __forceinline__ float b2f(unsigned short x) {
  return __uint_as_float((unsigned)x << 16);
}
__device__ __forceinline__ unsigned pack2(float lo, float hi) {
  return (unsigned)f2b(lo) | ((unsigned)f2b(hi) << 16);
}

#define MFMA(acc, a, bb) \
  asm volatile("s_nop 2\n\tv_mfma_f32_16x16x32_bf16 %0, %1, %2, %0" \
               : "+v"(acc) : "v"(a), "v"(bb))
#define MFMA_FENCE(acc) asm volatile("s_nop 7\n\ts_nop 7" : "+v"(acc))

// Prep: transpose+convert the 6 MFMA weight matrices into d_ws (once/launch).
__global__ void prep_kernel(Params p, unsigned short* ws) {
  const int t = blockIdx.x * 256 + threadIdx.x;  // 0..4095
  const int n = t >> 7, k = t & 127;
  ws[WA_PTP + t] = f2b(p.ptp_w2[k * 32 + n]);
  ws[WC_PTA + t] = f2b(p.pta_w2[k * 32 + n]);
  ws[WA_CAP + t] = f2b(p.cap_w2[k * 32 + n]);
  ws[WC_CAA + t] = f2b(p.caa_w2[k * 32 + n]);
  const int n2 = t >> 5, k2 = t & 31;
  ws[WB_PTA + t] = f2b(p.pta_w1[k2 * 128 + n2]);
  ws[WB_CAA + t] = f2b(p.caa_w1[k2 * 128 + n2]);
}

// WAVE-PER-BATCH, small-LDS variant (round 18 layout: s_work union + bf16
// s_ub => 12.8KB -> 12 blocks/CU by LDS). Round 18's (64,4) made the
// compiler budget VGPRs for 4 waves/SIMD (collapsed to 64 VGPR + 298MB
// spill). (64,3): budget ~170 VGPR (kernel needs ~120-136 -> no spill),
// residency cap 3 waves/SIMD = 12/CU == the LDS limit. Aligned config.
__launch_bounds__(64, 3)
__global__ void puray_kernel(Params p, const unsigned short* ws) {
  const int b = blockIdx.x;
  const int l = threadIdx.x;
  const int ln16 = l & 15, kg = l >> 4, k0 = kg * 8;

  __shared__ __align__(16) unsigned short s_work[16 * HSTR];  // hv THEN hid
  __shared__ __align__(16) unsigned short s_simb[16 * BSTR];
  __shared__ __align__(16) unsigned short s_ub[1024];  // bf16: h1|h2 ; q|k ; kk|vvb
  __shared__ float s_feats[512], s_v[512];
  __shared__ float s_coords[48], s_relv[48], s_reld[16];
  __shared__ float s_qry[3], s_op[3], s_qq[32], s_ca[32];
  __shared__ float s_cum;

  if (l < 48) s_coords[l] = p.knn[b * 48 + l];
  else if (l < 51) s_qry[l - 48] = p.query[b * 3 + (l - 48)];
  else if (l == 51) s_cum = 0.f;
  else if (l < 55) s_op[l - 52] = 0.f;
  __syncthreads();

  // ---- Phase A: feats (h1 -> s_ub[0:512], h2 -> s_ub[512:1024]) ----
  for (int m = 0; m < 8; ++m) {
    const int idx = l + 64 * m, pp = idx >> 5, jj = idx & 31;
    float a = p.fb1[jj];
    for (int c = 0; c < 3; ++c) a = fmaf(s_coords[pp * 3 + c], p.fw1[c * 32 + jj], a);
    s_ub[idx] = f2b(fmaxf(a, 0.f));
  }
  for (int m = 0; m < 8; ++m) {
    const int idx = l + 64 * m, pp = idx >> 5, jj = idx & 31;
    float a = p.fb2[jj];
    for (int i = 0; i < 32; ++i) a = fmaf(b2f(s_ub[pp * 32 + i]), p.fw2[i * 32 + jj], a);
    s_ub[512 + idx] = f2b(fmaxf(a, 0.f));
  }
  for (int m = 0; m < 8; ++m) {
    const int idx = l + 64 * m, pp = idx >> 5, jj = idx & 31;
    float a = p.fb3[jj];
    for (int i = 0; i < 32; ++i) a = fmaf(b2f(s_ub[512 + pp * 32 + i]), p.fw3[i * 32 + jj], a);
    s_feats[idx] = a;
  }
  // ---- Phase B: qkv -> s_ub (q|k) + s_v ----
  for (int m = 0; m < 24; ++m) {
    const int idx = l + 64 * m, pp = idx / 96, o = idx % 96;
    float a = 0.f;
    for (int i = 0; i < 32; ++i) a = fmaf(s_feats[pp * 32 + i], p.qkv_w[i * 96 + o], a);
    if (o < 32) s_ub[pp * 32 + o] = f2b(a);
    else if (o < 64) s_ub[512 + pp * 32 + o - 32] = f2b(a);
    else s_v[pp * 32 + o - 64] = a;
  }

  // ---- Phase C: one i-row at a time, all within the wave ----
  {
    const float* w1c = p.ptp_w1;
    const float* b1c = p.ptp_b1;
    const float* b2c = p.ptp_b2;
    const float* bh1 = p.pta_b1;
    const float* bh2 = p.pta_b2;
    const unsigned short* wsc = ws;
    for (int i = 0; i < 16; ++i) {
      asm volatile("" : "+s"(w1c), "+s"(b1c), "+s"(b2c), "+s"(bh1), "+s"(bh2), "+s"(wsc));
      const float c0 = s_coords[i * 3 + 0] - s_coords[ln16 * 3 + 0];
      const float c1 = s_coords[i * 3 + 1] - s_coords[ln16 * 3 + 1];
      const float c2 = s_coords[i * 3 + 2] - s_coords[ln16 * 3 + 2];
      // hv -> s_work (row ln16, d = kg*32 .. kg*32+31; 2 live values only)
      for (int x = 0; x < 32; x += 2) {
        const int d = kg * 32 + x;
        const float h0v = fmaxf(fmaf(c0, w1c[d],
                           fmaf(c1, w1c[128 + d],
                           fmaf(c2, w1c[256 + d], b1c[d]))), 0.f);
        const float h1v = fmaxf(fmaf(c0, w1c[d + 1],
                           fmaf(c1, w1c[128 + d + 1],
                           fmaf(c2, w1c[256 + d + 1], b1c[d + 1]))), 0.f);
        ((unsigned*)s_work)[(ln16 * HSTR + d) >> 1] = pack2(h0v, h1v);
      }
      f32x4 rpe0, rpe1;
      {  // G1 nb=0: rpe = hv @ ptp_w2 + b2 (A from LDS)
        const int n = ln16;
        const float bias = b2c[n];
        f32x4 acc = {bias, bias, bias, bias};
#pragma unroll
        for (int kk = 0; kk < 4; ++kk) {
          const u16x8 a = *(const u16x8*)&s_work[ln16 * HSTR + kk * 32 + k0];
          MFMA(acc, a, *(const u16x8*)&wsc[WA_PTP + n * 128 + kk * 32 + k0]);
        }
        MFMA_FENCE(acc);
        rpe0 = acc;
#pragma unroll
        for (int r2 = 0; r2 < 4; ++r2) {
          const int j = kg * 4 + r2;
          s_simb[j * BSTR + n] =
            f2b(b2f(s_ub[i * 32 + n]) - b2f(s_ub[512 + j * 32 + n]) + acc[r2]);
        }
      }
      {  // G1 nb=1
        const int n = 16 + ln16;
        const float bias = b2c[n];
        f32x4 acc = {bias, bias, bias, bias};
#pragma unroll
        for (int kk = 0; kk < 4; ++kk) {
          const u16x8 a = *(const u16x8*)&s_work[ln16 * HSTR + kk * 32 + k0];
          MFMA(acc, a, *(const u16x8*)&wsc[WA_PTP + n * 128 + kk * 32 + k0]);
        }
        MFMA_FENCE(acc);
        rpe1 = acc;
#pragma unroll
        for (int r2 = 0; r2 < 4; ++r2) {
          const int j = kg * 4 + r2;
          s_simb[j * BSTR + n] =
            f2b(b2f(s_ub[i * 32 + n]) - b2f(s_ub[512 + j * 32 + n]) + acc[r2]);
        }
      }
      {  // G2: hid[16][128] = relu(simin @ pta_w1 + b1) -> s_work (hv dead)
        const u16x8 a2 = *(const u16x8*)&s_simb[ln16 * BSTR + k0];
#pragma unroll
        for (int j2 = 0; j2 < 8; ++j2) {
          const int n = j2 * 16 + ln16;
          const float bias = bh1[n];
          f32x4 acc = {bias, bias, bias, bias};
          MFMA(acc, a2, *(const u16x8*)&wsc[WB_PTA + n * 32 + k0]);
          MFMA_FENCE(acc);
#pragma unroll
          for (int r2 = 0; r2 < 4; ++r2)
            s_work[(kg * 4 + r2) * HSTR + n] = f2b(fmaxf(acc[r2], 0.f));
        }
      }
      // G3 + fused softmax -> feats[i]
#pragma unroll
      for (int nb = 0; nb < 2; ++nb) {
        const int n = nb * 16 + ln16;
        const float bias = bh2[n];
        f32x4 acc = {bias, bias, bias, bias};
#pragma unroll
        for (int kk = 0; kk < 4; ++kk) {
          const u16x8 a3 = *(const u16x8*)&s_work[ln16 * HSTR + kk * 32 + k0];
          MFMA(acc, a3, *(const u16x8*)&wsc[WC_PTA + n * 128 + kk * 32 + k0]);
        }
        MFMA_FENCE(acc);
        const f32x4 rp = nb ? rpe1 : rpe0;
        float mx = fmaxf(fmaxf(acc[0], acc[1]), fmaxf(acc[2], acc[3]));
        mx = fmaxf(mx, __shfl_xor(mx, 16));
        mx = fmaxf(mx, __shfl_xor(mx, 32));
        float sum = 0.f, o = 0.f;
#pragma unroll
        for (int r2 = 0; r2 < 4; ++r2) {
          const int j = kg * 4 + r2;
          const float e = __expf(acc[r2] - mx);
          sum += e;
          o = fmaf(e, s_v[j * 32 + n] + rp[r2], o);
        }
        sum += __shfl_xor(sum, 16); o += __shfl_xor(o, 16);
        sum += __shfl_xor(sum, 32); o += __shfl_xor(o, 32);
        if (kg == 0) s_feats[i * 32 + n] = o / sum;
      }
    }
  }

  // ---- kk / vvb (overwrite q|k in s_ub, bf16) ----
  for (int m = 0; m < 8; ++m) {
    const int idx = l + 64 * m, k = idx >> 5, h = idx & 31;
    float akk = p.cak_b[h], avv = p.cav_b[h];
    for (int i = 0; i < 32; ++i) {
      const float f = s_feats[k * 32 + i];
      akk = fmaf(f, p.cak_w[i * 32 + h], akk);
      avv = fmaf(f, p.cav_w[i * 32 + h], avv);
    }
    s_ub[k * 32 + h] = f2b(akk);
    s_ub[512 + k * 32 + h] = f2b(avv);
  }

  // ---- Phase D: 8 march steps + epilogue, all within the wave ----
  {
    const float* w1d = p.cap_w1;
    const float* b1d = p.cap_b1;
    const float* b2d = p.cap_b2;
    const float* bc1 = p.caa_b1;
    const float* bc2 = p.caa_b2;
    const float* fw1 = p.fw1; const float* fw2 = p.fw2; const float* fw3 = p.fw3;
    const float* cqw = p.caq_w;
    const float* iw1 = p.im_w1; const float* iw2 = p.im_w2; const float* iw3 = p.im_w3;
    const unsigned short* wsd = ws;
    for (int s = 0; s <= 8; ++s) {
      asm volatile("" : "+s"(w1d), "+s"(b1d), "+s"(b2d), "+s"(bc1), "+s"(bc2), "+s"(wsd));
      asm volatile("" : "+s"(fw1), "+s"(fw2), "+s"(fw3), "+s"(cqw), "+s"(iw1), "+s"(iw2), "+s"(iw3));
      float rv0 = 0.f, rv1 = 0.f, rv2 = 0.f;
      if (s < 8 && l < 16) {  // rel + o_ld
        const float r0 = s_coords[l * 3 + 0] - s_op[0];
        const float r1 = s_coords[l * 3 + 1] - s_op[1];
        const float r2 = s_coords[l * 3 + 2] - s_op[2];
        const float rd = sqrtf(r0 * r0 + r1 * r1 + r2 * r2);
        const float inv = 1.f / rd;
        rv0 = r0 * inv; rv1 = r1 * inv; rv2 = r2 * inv;
        s_reld[l] = rd;
        s_relv[l * 3 + 0] = rv0; s_relv[l * 3 + 1] = rv1; s_relv[l * 3 + 2] = rv2;
        p.o_ld[b * 128 + s * 16 + l] = rd;
      }
      // secA: pe-hidden hv -> s_work (row ln16, d = kg*32..+31)
      {
        float c0, c1, c2;
        if (s < 8) {
          c0 = s_coords[ln16 * 3 + 0] - s_op[0];
          c1 = s_coords[ln16 * 3 + 1] - s_op[1];
          c2 = s_coords[ln16 * 3 + 2] - s_op[2];
        } else {
          const float rd = s_reld[ln16];
          c0 = s_relv[ln16 * 3 + 0] * rd; c1 = s_relv[ln16 * 3 + 1] * rd; c2 = s_relv[ln16 * 3 + 2] * rd;
        }
        for (int x = 0; x < 32; x += 2) {
          const int d = kg * 32 + x;
          const float h0v = fmaxf(fmaf(c0, w1d[d],
                             fmaf(c1, w1d[128 + d],
                             fmaf(c2, w1d[256 + d], b1d[d]))), 0.f);
          const float h1v = fmaxf(fmaf(c0, w1d[d + 1],
                             fmaf(c1, w1d[128 + d + 1],
                             fmaf(c2, w1d[256 + d + 1], b1d[d + 1]))), 0.f);
          ((unsigned*)s_work)[(ln16 * HSTR + d) >> 1] = pack2(h0v, h1v);
        }
      }
      {  // qq chain (all lanes, width-32 shuffles; halves duplicate)
        const int h = l & 31;
        float opc0, opc1, opc2;
        if (s < 8) {
          const float cum = s_cum;
          opc0 = s_qry[0] * cum; opc1 = s_qry[1] * cum; opc2 = s_qry[2] * cum;
        } else {
          opc0 = s_op[0]; opc1 = s_op[1]; opc2 = s_op[2];
        }
        float v1 = fmaxf(fmaf(opc0, fw1[h],
                      fmaf(opc1, fw1[32 + h],
                      fmaf(opc2, fw1[64 + h], p.fb1[h]))), 0.f);
        float a = p.fb2[h];
        for (int i2 = 0; i2 < 32; ++i2) a = fmaf(__shfl(v1, i2, 32), fw2[i2 * 32 + h], a);
        const float v2 = fmaxf(a, 0.f);
        a = p.fb3[h];
        for (int i2 = 0; i2 < 32; ++i2) a = fmaf(__shfl(v2, i2, 32), fw3[i2 * 32 + h], a);
        const float opf = a;
        a = p.caq_b[h];
        for (int i2 = 0; i2 < 32; ++i2) a = fmaf(__shfl(opf, i2, 32), cqw[i2 * 32 + h], a);
        if (l < 32) s_qq[h] = a;
      }
      f32x4 pe0, pe1;
      {  // secB nb=0: pe = hv @ cap_w2 + b2 (A from LDS)
        const int n = ln16;
        const float bias = b2d[n];
        f32x4 acc = {bias, bias, bias, bias};
#pragma unroll
        for (int kk = 0; kk < 4; ++kk) {
          const u16x8 a = *(const u16x8*)&s_work[ln16 * HSTR + kk * 32 + k0];
          MFMA(acc, a, *(const u16x8*)&wsd[WA_CAP + n * 128 + kk * 32 + k0]);
        }
        MFMA_FENCE(acc);
        pe0 = acc;
#pragma unroll
        for (int r2 = 0; r2 < 4; ++r2) {
          const int row = kg * 4 + r2;
          s_simb[row * BSTR + n] = f2b(s_qq[n] - b2f(s_ub[row * 32 + n]) + acc[r2]);
        }
      }
      {  // secB nb=1
        const int n = 16 + ln16;
        const float bias = b2d[n];
        f32x4 acc = {bias, bias, bias, bias};
#pragma unroll
        for (int kk = 0; kk < 4; ++kk) {
          const u16x8 a = *(const u16x8*)&s_work[ln16 * HSTR + kk * 32 + k0];
          MFMA(acc, a, *(const u16x8*)&wsd[WA_CAP + n * 128 + kk * 32 + k0]);
        }
        MFMA_FENCE(acc);
        pe1 = acc;
#pragma unroll
        for (int r2 = 0; r2 < 4; ++r2) {
          const int row = kg * 4 + r2;
          s_simb[row * BSTR + n] = f2b(s_qq[n] - b2f(s_ub[row * 32 + n]) + acc[r2]);
        }
      }
      {  // secC: hid = relu(ain @ caa_w1 + b1) -> s_work (hv dead)
        const u16x8 a2 = *(const u16x8*)&s_simb[ln16 * BSTR + k0];
#pragma unroll
        for (int j2 = 0; j2 < 8; ++j2) {
          const int n = j2 * 16 + ln16;
          const float bias = bc1[n];
          f32x4 acc = {bias, bias, bias, bias};
          MFMA(acc, a2, *(const u16x8*)&wsd[WB_CAA + n * 32 + k0]);
          MFMA_FENCE(acc);
#pragma unroll
          for (int r2 = 0; r2 < 4; ++r2)
            s_work[(kg * 4 + r2) * HSTR + n] = f2b(fmaxf(acc[r2], 0.f));
        }
      }
      // secD + in-register softmax -> ca0/ca1
      float ca0 = 0.f, ca1 = 0.f;
#pragma unroll
      for (int nb = 0; nb < 2; ++nb) {
        const int n = nb * 16 + ln16;
        const float bias = bc2[n];
        f32x4 acc = {bias, bias, bias, bias};
#pragma unroll
        for (int kk = 0; kk < 4; ++kk) {
          const u16x8 a3 = *(const u16x8*)&s_work[ln16 * HSTR + kk * 32 + k0];
          MFMA(acc, a3, *(const u16x8*)&wsd[WC_CAA + n * 128 + kk * 32 + k0]);
        }
        MFMA_FENCE(acc);
        const f32x4 rp = nb ? pe1 : pe0;
        float mx = fmaxf(fmaxf(acc[0], acc[1]), fmaxf(acc[2], acc[3]));
        mx = fmaxf(mx, __shfl_xor(mx, 16));
        mx = fmaxf(mx, __shfl_xor(mx, 32));
        float sum = 0.f, o = 0.f;
#pragma unroll
        for (int r2 = 0; r2 < 4; ++r2) {
          const int row = kg * 4 + r2;
          const float e = __expf(acc[r2] - mx);
          sum += e;
          o = fmaf(e, b2f(s_ub[512 + row * 32 + n]) + rp[r2], o);
        }
        sum += __shfl_xor(sum, 16); o += __shfl_xor(o, 16);
        sum += __shfl_xor(sum, 32); o += __shfl_xor(o, 32);
        if (nb == 0) ca0 = o / sum; else ca1 = o / sum;
      }
      if (kg == 0) { s_ca[ln16] = ca0; s_ca[16 + ln16] = ca1; }
      {  // im / ep chain (width-32; halves duplicate; writes guarded)
        const int h = l & 31;
        const float cav = s_ca[h];
        if (s < 8) {
          float a = p.im_b1[h];
          for (int i2 = 0; i2 < 32; ++i2) a = fmaf(__shfl(cav, i2, 32), iw1[i2 * 32 + h], a);
          const float m1 = fmaxf(a, 0.f);
          a = p.im_b2[h];
          for (int i2 = 0; i2 < 32; ++i2) a = fmaf(__shfl(m1, i2, 32), iw2[i2 * 32 + h], a);
          const float m2 = fmaxf(a, 0.f);
          float p0 = m2 * iw3[h * 3 + 0];
          float p1 = m2 * iw3[h * 3 + 1];
          float p2 = m2 * iw3[h * 3 + 2];
#pragma unroll
          for (int m = 1; m < 32; m <<= 1) {
            p0 += __shfl_xor(p0, m, 32);
            p1 += __shfl_xor(p1, m, 32);
            p2 += __shfl_xor(p2, m, 32);
          }
          p0 += p.im_b3[0]; p1 += p.im_b3[1]; p2 += p.im_b3[2];
          const float step = sqrtf(p0 * p0 + p1 * p1 + p2 * p2);
          const float cum = s_cum;
          const float opc0 = s_qry[0] * cum, opc1 = s_qry[1] * cum, opc2 = s_qry[2] * cum;
          const float inv = 1.f / step;
          const float tg0 = p0 * inv, tg1 = p1 * inv, tg2 = p2 * inv;
          if (l == 0) {
            p.o_ms[b * 8 + s] = step;
            p.o_ip[(b * 8 + s) * 3 + 0] = opc0 + p0;
            s_op[0] = opc0 + s_qry[0] * step;
          } else if (l == 1) {
            p.o_ip[(b * 8 + s) * 3 + 1] = opc1 + p1;
            s_op[1] = opc1 + s_qry[1] * step;
          } else if (l == 2) {
            p.o_ip[(b * 8 + s) * 3 + 2] = opc2 + p2;
            s_op[2] = opc2 + s_qry[2] * step;
          } else if (l == 3) {
            s_cum = cum + step;
          }
          if (l < 16) {
            p.o_cs[b * 128 + s * 16 + l] = tg0 * rv0 + tg1 * rv1 + tg2 * rv2;
          }
        } else {
          float a = p.ep_b1[h];
          for (int i2 = 0; i2 < 32; ++i2) a = fmaf(__shfl(cav, i2, 32), p.ep_w1[i2 * 32 + h], a);
          a = fmaf(s_qry[0], p.ep_w1[1024 + h], a);
          a = fmaf(s_qry[1], p.ep_w1[1056 + h], a);
          a = fmaf(s_qry[2], p.ep_w1[1088 + h], a);
          const float e1 = fmaxf(a, 0.f);
          a = p.ep_b2[h];
          for (int i2 = 0; i2 < 32; ++i2) a = fmaf(__shfl(e1, i2, 32), p.ep_w2[i2 * 32 + h], a);
          const float e2 = fmaxf(a, 0.f);
          float pp = e2 * p.ep_w3[h];
#pragma unroll
          for (int m = 1; m < 32; m <<= 1) pp += __shfl_xor(pp, m, 32);
          if (l == 0) {
            p.o_eps[b] = pp + p.ep_b3[0];
            p.o_cum[b] = s_cum;
          }
        }
      }
    }
  }
}

extern "C" void kernel_launch(void* const* d_in, const int* in_sizes, int n_in,
                              void* d_out, int out_size, void* d_ws, size_t ws_size,
                              hipStream_t stream) {
  Params p;
  const float** f = (const float**)(void*)&p;
  for (int i = 0; i < 43; ++i) f[i] = (const float*)d_in[i];
  float* out = (float*)d_out;
  p.o_ld  = out;
  p.o_ms  = out + OFF_MS;
  p.o_cs  = out + OFF_CS;
  p.o_ip  = out + OFF_IP;
  p.o_cum = out + OFF_CUM;
  p.o_eps = out + OFF_EPS;
  unsigned short* ws = (unsigned short*)d_ws;
  prep_kernel<<<dim3(16), dim3(256), 0, stream>>>(p, ws);
  puray_kernel<<<dim3(4096), dim3(64), 0, stream>>>(p, ws);
}

// Round 20
// 454.719 us; speedup vs baseline: 2.1217x; 1.4492x over previous
//
#include <hip/hip_runtime.h>

// Problem constants: B=4096, K=16, H=32, HM=128, STEPS=8
#define OFF_MS  524288
#define OFF_CS  557056
#define OFF_IP  1081344
#define OFF_CUM 1179648
#define OFF_EPS 1183744

#define HSTR 136   // padded bf16 row stride (272B -> 2-way banks)
#define BSTR 40    // padded bf16 row stride (80B)

// d_ws layout (u16): bf16 weights transposed to [n][k]
#define WA_PTP 0        // ptp_w2T [32][128]
#define WB_PTA 4096     // pta_w1T [128][32]
#define WC_PTA 8192     // pta_w2T [32][128]
#define WA_CAP 12288    // cap_w2T [32][128]
#define WB_CAA 16384    // caa_w1T [128][32]
#define WC_CAA 20480    // caa_w2T [32][128]
#define WH_PTP 24576    // ptp_w1T [128 n][32 k] (k=0..2 w1, k=3 bias, else 0)
#define WH_CAP 28672    // cap_w1T [128 n][32 k] (same trick)

struct Params {
  const float *knn, *query, *fw1, *fb1, *fw2, *fb2, *fw3, *fb3, *qkv_w,
    *ptp_w1, *ptp_b1, *ptp_w2, *ptp_b2, *pta_w1, *pta_b1, *pta_w2, *pta_b2,
    *caq_w, *caq_b, *cak_w, *cak_b, *cav_w, *cav_b,
    *cap_w1, *cap_b1, *cap_w2, *cap_b2, *caa_w1, *caa_b1, *caa_w2, *caa_b2,
    *im_w1, *im_b1, *im_w2, *im_b2, *im_w3, *im_b3,
    *ep_w1, *ep_b1, *ep_w2, *ep_b2, *ep_w3, *ep_b3;
  float *o_ld, *o_ms, *o_cs, *o_ip, *o_cum, *o_eps;
};
static_assert(sizeof(Params) == 49 * sizeof(void*), "Params layout");

typedef float f32x4 __attribute__((ext_vector_type(4)));
typedef unsigned short u16x8 __attribute__((ext_vector_type(8)));

__device__ __forceinline__ unsigned short f2b(float x) {  // fp32->bf16 RNE
  unsigned u = __float_as_uint(x);
  u += 0x7fffu + ((u >> 16) & 1u);
  return (unsigned short)(u >> 16);
}
__device__ __forceinline__ unsigned pack2(float lo, float hi) {
  return (unsigned)f2b(lo) | ((unsigned)f2b(hi) << 16);
}

#define MFMA(acc, a, bb) \
  asm volatile("s_nop 2\n\tv_mfma_f32_16x16x32_bf16 %0, %1, %2, %0" \
               : "+v"(acc) : "v"(a), "v"(bb))
#define MFMA_FENCE(acc) asm volatile("s_nop 7\n\ts_nop 7" : "+v"(acc))

// Prep: transpose+convert the 8 MFMA weight tables into d_ws (once/launch).
__global__ void prep_kernel(Params p, unsigned short* ws) {
  const int t = blockIdx.x * 256 + threadIdx.x;  // 0..4095
  const int n = t >> 7, k = t & 127;
  ws[WA_PTP + t] = f2b(p.ptp_w2[k * 32 + n]);
  ws[WC_PTA + t] = f2b(p.pta_w2[k * 32 + n]);
  ws[WA_CAP + t] = f2b(p.cap_w2[k * 32 + n]);
  ws[WC_CAA + t] = f2b(p.caa_w2[k * 32 + n]);
  const int n2 = t >> 5, k2 = t & 31;
  ws[WB_PTA + t] = f2b(p.pta_w1[k2 * 128 + n2]);
  ws[WB_CAA + t] = f2b(p.caa_w1[k2 * 128 + n2]);
  // hv-layer B tables: [128 n][32 k], k<3 = w1 row k, k==3 = bias, else 0
  ws[WH_PTP + t] = (k2 < 3) ? f2b(p.ptp_w1[k2 * 128 + n2])
                  : (k2 == 3 ? f2b(p.ptp_b1[n2]) : (unsigned short)0);
  ws[WH_CAP + t] = (k2 < 3) ? f2b(p.cap_w1[k2 * 128 + n2])
                  : (k2 == 3 ? f2b(p.cap_b1[n2]) : (unsigned short)0);
}

// WAVE-PER-BATCH, round-16 config (452us, 120 VGPR, no spill, (64,2),
// 18.9KB LDS -> 8 independent batch-waves/CU). Rounds 17-19 proved
// occupancy knobs are a dead end (pinned ~8 wg/CU). This round instead cuts
// the wave's serial VALU work: the 3->128 hv layer (phase C x16, secA x9)
// is a 16x4 @ 4x128 GEMM -> 8 MFMAs with bias folded at k=3 of the
// A-fragment ({rel0,rel1,rel2,1.0,0..}), replacing ~230 VALU ops/iter.
__launch_bounds__(64, 2)
__global__ void puray_kernel(Params p, const unsigned short* ws) {
  const int b = blockIdx.x;
  const int l = threadIdx.x;
  const int ln16 = l & 15, kg = l >> 4, k0 = kg * 8;

  __shared__ __align__(16) unsigned short s_hvb[16 * HSTR];   // hv A-operand
  __shared__ __align__(16) unsigned short s_hidb[16 * HSTR];  // G2/secC out
  __shared__ __align__(16) unsigned short s_simb[16 * BSTR];
  __shared__ float s_feats[512], s_v[512];
  __shared__ float s_u[1024];    // A: h1|h2 ; B/C: q|k ; D: kk|vvb
  __shared__ float s_coords[48], s_relv[48], s_reld[16];
  __shared__ float s_qry[3], s_op[3], s_qq[32], s_ca[32];
  __shared__ float s_cum;

  if (l < 48) s_coords[l] = p.knn[b * 48 + l];
  else if (l < 51) s_qry[l - 48] = p.query[b * 3 + (l - 48)];
  else if (l == 51) s_cum = 0.f;
  else if (l < 55) s_op[l - 52] = 0.f;
  __syncthreads();

  // ---- Phase A: feats (h1 -> s_u[0:512], h2 -> s_u[512:1024]) ----
  for (int m = 0; m < 8; ++m) {
    const int idx = l + 64 * m, pp = idx >> 5, jj = idx & 31;
    float a = p.fb1[jj];
    for (int c = 0; c < 3; ++c) a = fmaf(s_coords[pp * 3 + c], p.fw1[c * 32 + jj], a);
    s_u[idx] = fmaxf(a, 0.f);
  }
  for (int m = 0; m < 8; ++m) {
    const int idx = l + 64 * m, pp = idx >> 5, jj = idx & 31;
    float a = p.fb2[jj];
    for (int i = 0; i < 32; ++i) a = fmaf(s_u[pp * 32 + i], p.fw2[i * 32 + jj], a);
    s_u[512 + idx] = fmaxf(a, 0.f);
  }
  for (int m = 0; m < 8; ++m) {
    const int idx = l + 64 * m, pp = idx >> 5, jj = idx & 31;
    float a = p.fb3[jj];
    for (int i = 0; i < 32; ++i) a = fmaf(s_u[512 + pp * 32 + i], p.fw3[i * 32 + jj], a);
    s_feats[idx] = a;
  }
  // ---- Phase B: qkv -> s_u (q|k) + s_v ----
  for (int m = 0; m < 24; ++m) {
    const int idx = l + 64 * m, pp = idx / 96, o = idx % 96;
    float a = 0.f;
    for (int i = 0; i < 32; ++i) a = fmaf(s_feats[pp * 32 + i], p.qkv_w[i * 96 + o], a);
    if (o < 32) s_u[pp * 32 + o] = a;
    else if (o < 64) s_u[512 + pp * 32 + o - 32] = a;
    else s_v[pp * 32 + o - 64] = a;
  }

  // ---- Phase C: one i-row at a time, all within the wave ----
  {
    const float* b2c = p.ptp_b2;
    const float* bh1 = p.pta_b1;
    const float* bh2 = p.pta_b2;
    const unsigned short* wsc = ws;
    for (int i = 0; i < 16; ++i) {
      asm volatile("" : "+s"(b2c), "+s"(bh1), "+s"(bh2), "+s"(wsc));
      const float c0 = s_coords[i * 3 + 0] - s_coords[ln16 * 3 + 0];
      const float c1 = s_coords[i * 3 + 1] - s_coords[ln16 * 3 + 1];
      const float c2 = s_coords[i * 3 + 2] - s_coords[ln16 * 3 + 2];
      {  // hv[16][128] = relu(rel @ ptp_w1 + b1) via MFMA -> s_hvb
        union { u16x8 v; unsigned u[4]; } cv;
        cv.u[0] = (kg == 0) ? pack2(c0, c1) : 0u;
        cv.u[1] = (kg == 0) ? pack2(c2, 1.0f) : 0u;
        cv.u[2] = 0u; cv.u[3] = 0u;
        const u16x8 afh = cv.v;
#pragma unroll
        for (int nb = 0; nb < 8; ++nb) {
          const int n = nb * 16 + ln16;
          f32x4 acc = {0.f, 0.f, 0.f, 0.f};
          MFMA(acc, afh, *(const u16x8*)&wsc[WH_PTP + n * 32 + k0]);
          MFMA_FENCE(acc);
#pragma unroll
          for (int r2 = 0; r2 < 4; ++r2)
            s_hvb[(kg * 4 + r2) * HSTR + n] = f2b(fmaxf(acc[r2], 0.f));
        }
      }
      f32x4 rpe0, rpe1;
      {  // G1 nb=0: rpe = hv @ ptp_w2 + b2 (A from LDS)
        const int n = ln16;
        const float bias = b2c[n];
        f32x4 acc = {bias, bias, bias, bias};
#pragma unroll
        for (int kk = 0; kk < 4; ++kk) {
          const u16x8 a = *(const u16x8*)&s_hvb[ln16 * HSTR + kk * 32 + k0];
          MFMA(acc, a, *(const u16x8*)&wsc[WA_PTP + n * 128 + kk * 32 + k0]);
        }
        MFMA_FENCE(acc);
        rpe0 = acc;
#pragma unroll
        for (int r2 = 0; r2 < 4; ++r2) {
          const int j = kg * 4 + r2;
          s_simb[j * BSTR + n] = f2b(s_u[i * 32 + n] - s_u[512 + j * 32 + n] + acc[r2]);
        }
      }
      {  // G1 nb=1
        const int n = 16 + ln16;
        const float bias = b2c[n];
        f32x4 acc = {bias, bias, bias, bias};
#pragma unroll
        for (int kk = 0; kk < 4; ++kk) {
          const u16x8 a = *(const u16x8*)&s_hvb[ln16 * HSTR + kk * 32 + k0];
          MFMA(acc, a, *(const u16x8*)&wsc[WA_PTP + n * 128 + kk * 32 + k0]);
        }
        MFMA_FENCE(acc);
        rpe1 = acc;
#pragma unroll
        for (int r2 = 0; r2 < 4; ++r2) {
          const int j = kg * 4 + r2;
          s_simb[j * BSTR + n] = f2b(s_u[i * 32 + n] - s_u[512 + j * 32 + n] + acc[r2]);
        }
      }
      {  // G2: hid[16][128] = relu(simin @ pta_w1 + b1)
        const u16x8 a2 = *(const u16x8*)&s_simb[ln16 * BSTR + k0];
#pragma unroll
        for (int j2 = 0; j2 < 8; ++j2) {
          const int n = j2 * 16 + ln16;
          const float bias = bh1[n];
          f32x4 acc = {bias, bias, bias, bias};
          MFMA(acc, a2, *(const u16x8*)&wsc[WB_PTA + n * 32 + k0]);
          MFMA_FENCE(acc);
#pragma unroll
          for (int r2 = 0; r2 < 4; ++r2)
            s_hidb[(kg * 4 + r2) * HSTR + n] = f2b(fmaxf(acc[r2], 0.f));
        }
      }
      // G3 + fused softmax -> feats[i]
#pragma unroll
      for (int nb = 0; nb < 2; ++nb) {
        const int n = nb * 16 + ln16;
        const float bias = bh2[n];
        f32x4 acc = {bias, bias, bias, bias};
#pragma unroll
        for (int kk = 0; kk < 4; ++kk) {
          const u16x8 a3 = *(const u16x8*)&s_hidb[ln16 * HSTR + kk * 32 + k0];
          MFMA(acc, a3, *(const u16x8*)&wsc[WC_PTA + n * 128 + kk * 32 + k0]);
        }
        MFMA_FENCE(acc);
        const f32x4 rp = nb ? rpe1 : rpe0;
        float mx = fmaxf(fmaxf(acc[0], acc[1]), fmaxf(acc[2], acc[3]));
        mx = fmaxf(mx, __shfl_xor(mx, 16));
        mx = fmaxf(mx, __shfl_xor(mx, 32));
        float sum = 0.f, o = 0.f;
#pragma unroll
        for (int r2 = 0; r2 < 4; ++r2) {
          const int j = kg * 4 + r2;
          const float e = __expf(acc[r2] - mx);
          sum += e;
          o = fmaf(e, s_v[j * 32 + n] + rp[r2], o);
        }
        sum += __shfl_xor(sum, 16); o += __shfl_xor(o, 16);
        sum += __shfl_xor(sum, 32); o += __shfl_xor(o, 32);
        if (kg == 0) s_feats[i * 32 + n] = o / sum;
      }
    }
  }

  // ---- kk / vvb (overwrite q|k in s_u) ----
  for (int m = 0; m < 8; ++m) {
    const int idx = l + 64 * m, k = idx >> 5, h = idx & 31;
    float akk = p.cak_b[h], avv = p.cav_b[h];
    for (int i = 0; i < 32; ++i) {
      const float f = s_feats[k * 32 + i];
      akk = fmaf(f, p.cak_w[i * 32 + h], akk);
      avv = fmaf(f, p.cav_w[i * 32 + h], avv);
    }
    s_u[k * 32 + h] = akk;
    s_u[512 + k * 32 + h] = avv;
  }

  // ---- Phase D: 8 march steps + epilogue, all within the wave ----
  {
    const float* b2d = p.cap_b2;
    const float* bc1 = p.caa_b1;
    const float* bc2 = p.caa_b2;
    const float* fw1 = p.fw1; const float* fw2 = p.fw2; const float* fw3 = p.fw3;
    const float* cqw = p.caq_w;
    const float* iw1 = p.im_w1; const float* iw2 = p.im_w2; const float* iw3 = p.im_w3;
    const unsigned short* wsd = ws;
    for (int s = 0; s <= 8; ++s) {
      asm volatile("" : "+s"(b2d), "+s"(bc1), "+s"(bc2), "+s"(wsd));
      asm volatile("" : "+s"(fw1), "+s"(fw2), "+s"(fw3), "+s"(cqw), "+s"(iw1), "+s"(iw2), "+s"(iw3));
      float rv0 = 0.f, rv1 = 0.f, rv2 = 0.f;
      if (s < 8 && l < 16) {  // rel + o_ld
        const float r0 = s_coords[l * 3 + 0] - s_op[0];
        const float r1 = s_coords[l * 3 + 1] - s_op[1];
        const float r2 = s_coords[l * 3 + 2] - s_op[2];
        const float rd = sqrtf(r0 * r0 + r1 * r1 + r2 * r2);
        const float inv = 1.f / rd;
        rv0 = r0 * inv; rv1 = r1 * inv; rv2 = r2 * inv;
        s_reld[l] = rd;
        s_relv[l * 3 + 0] = rv0; s_relv[l * 3 + 1] = rv1; s_relv[l * 3 + 2] = rv2;
        p.o_ld[b * 128 + s * 16 + l] = rd;
      }
      {  // secA: hv[16][128] = relu(rel @ cap_w1 + b1) via MFMA -> s_hvb
        float c0, c1, c2;
        if (s < 8) {
          c0 = s_coords[ln16 * 3 + 0] - s_op[0];
          c1 = s_coords[ln16 * 3 + 1] - s_op[1];
          c2 = s_coords[ln16 * 3 + 2] - s_op[2];
        } else {
          const float rd = s_reld[ln16];
          c0 = s_relv[ln16 * 3 + 0] * rd; c1 = s_relv[ln16 * 3 + 1] * rd; c2 = s_relv[ln16 * 3 + 2] * rd;
        }
        union { u16x8 v; unsigned u[4]; } cv;
        cv.u[0] = (kg == 0) ? pack2(c0, c1) : 0u;
        cv.u[1] = (kg == 0) ? pack2(c2, 1.0f) : 0u;
        cv.u[2] = 0u; cv.u[3] = 0u;
        const u16x8 afh = cv.v;
#pragma unroll
        for (int nb = 0; nb < 8; ++nb) {
          const int n = nb * 16 + ln16;
          f32x4 acc = {0.f, 0.f, 0.f, 0.f};
          MFMA(acc, afh, *(const u16x8*)&wsd[WH_CAP + n * 32 + k0]);
          MFMA_FENCE(acc);
#pragma unroll
          for (int r2 = 0; r2 < 4; ++r2)
            s_hvb[(kg * 4 + r2) * HSTR + n] = f2b(fmaxf(acc[r2], 0.f));
        }
      }
      {  // qq chain (all lanes, width-32 shuffles; halves duplicate)
        const int h = l & 31;
        float opc0, opc1, opc2;
        if (s < 8) {
          const float cum = s_cum;
          opc0 = s_qry[0] * cum; opc1 = s_qry[1] * cum; opc2 = s_qry[2] * cum;
        } else {
          opc0 = s_op[0]; opc1 = s_op[1]; opc2 = s_op[2];
        }
        float v1 = fmaxf(fmaf(opc0, fw1[h],
                      fmaf(opc1, fw1[32 + h],
                      fmaf(opc2, fw1[64 + h], p.fb1[h]))), 0.f);
        float a = p.fb2[h];
        for (int i2 = 0; i2 < 32; ++i2) a = fmaf(__shfl(v1, i2, 32), fw2[i2 * 32 + h], a);
        const float v2 = fmaxf(a, 0.f);
        a = p.fb3[h];
        for (int i2 = 0; i2 < 32; ++i2) a = fmaf(__shfl(v2, i2, 32), fw3[i2 * 32 + h], a);
        const float opf = a;
        a = p.caq_b[h];
        for (int i2 = 0; i2 < 32; ++i2) a = fmaf(__shfl(opf, i2, 32), cqw[i2 * 32 + h], a);
        if (l < 32) s_qq[h] = a;
      }
      f32x4 pe0, pe1;
      {  // secB nb=0: pe = hv @ cap_w2 + b2 (A from LDS)
        const int n = ln16;
        const float bias = b2d[n];
        f32x4 acc = {bias, bias, bias, bias};
#pragma unroll
        for (int kk = 0; kk < 4; ++kk) {
          const u16x8 a = *(const u16x8*)&s_hvb[ln16 * HSTR + kk * 32 + k0];
          MFMA(acc, a, *(const u16x8*)&wsd[WA_CAP + n * 128 + kk * 32 + k0]);
        }
        MFMA_FENCE(acc);
        pe0 = acc;
#pragma unroll
        for (int r2 = 0; r2 < 4; ++r2) {
          const int row = kg * 4 + r2;
          s_simb[row * BSTR + n] = f2b(s_qq[n] - s_u[row * 32 + n] + acc[r2]);
        }
      }
      {  // secB nb=1
        const int n = 16 + ln16;
        const float bias = b2d[n];
        f32x4 acc = {bias, bias, bias, bias};
#pragma unroll
        for (int kk = 0; kk < 4; ++kk) {
          const u16x8 a = *(const u16x8*)&s_hvb[ln16 * HSTR + kk * 32 + k0];
          MFMA(acc, a, *(const u16x8*)&wsd[WA_CAP + n * 128 + kk * 32 + k0]);
        }
        MFMA_FENCE(acc);
        pe1 = acc;
#pragma unroll
        for (int r2 = 0; r2 < 4; ++r2) {
          const int row = kg * 4 + r2;
          s_simb[row * BSTR + n] = f2b(s_qq[n] - s_u[row * 32 + n] + acc[r2]);
        }
      }
      {  // secC: hid = relu(ain @ caa_w1 + b1)
        const u16x8 a2 = *(const u16x8*)&s_simb[ln16 * BSTR + k0];
#pragma unroll
        for (int j2 = 0; j2 < 8; ++j2) {
          const int n = j2 * 16 + ln16;
          const float bias = bc1[n];
          f32x4 acc = {bias, bias, bias, bias};
          MFMA(acc, a2, *(const u16x8*)&wsd[WB_CAA + n * 32 + k0]);
          MFMA_FENCE(acc);
#pragma unroll
          for (int r2 = 0; r2 < 4; ++r2)
            s_hidb[(kg * 4 + r2) * HSTR + n] = f2b(fmaxf(acc[r2], 0.f));
        }
      }
      // secD + in-register softmax -> ca0/ca1
      float ca0 = 0.f, ca1 = 0.f;
#pragma unroll
      for (int nb = 0; nb < 2; ++nb) {
        const int n = nb * 16 + ln16;
        const float bias = bc2[n];
        f32x4 acc = {bias, bias, bias, bias};
#pragma unroll
        for (int kk = 0; kk < 4; ++kk) {
          const u16x8 a3 = *(const u16x8*)&s_hidb[ln16 * HSTR + kk * 32 + k0];
          MFMA(acc, a3, *(const u16x8*)&wsd[WC_CAA + n * 128 + kk * 32 + k0]);
        }
        MFMA_FENCE(acc);
        const f32x4 rp = nb ? pe1 : pe0;
        float mx = fmaxf(fmaxf(acc[0], acc[1]), fmaxf(acc[2], acc[3]));
        mx = fmaxf(mx, __shfl_xor(mx, 16));
        mx = fmaxf(mx, __shfl_xor(mx, 32));
        float sum = 0.f, o = 0.f;
#pragma unroll
        for (int r2 = 0; r2 < 4; ++r2) {
          const int row = kg * 4 + r2;
          const float e = __expf(acc[r2] - mx);
          sum += e;
          o = fmaf(e, s_u[512 + row * 32 + n] + rp[r2], o);
        }
        sum += __shfl_xor(sum, 16); o += __shfl_xor(o, 16);
        sum += __shfl_xor(sum, 32); o += __shfl_xor(o, 32);
        if (nb == 0) ca0 = o / sum; else ca1 = o / sum;
      }
      if (kg == 0) { s_ca[ln16] = ca0; s_ca[16 + ln16] = ca1; }
      {  // im / ep chain (width-32; halves duplicate; writes guarded)
        const int h = l & 31;
        const float cav = s_ca[h];
        if (s < 8) {
          float a = p.im_b1[h];
          for (int i2 = 0; i2 < 32; ++i2) a = fmaf(__shfl(cav, i2, 32), iw1[i2 * 32 + h], a);
          const float m1 = fmaxf(a, 0.f);
          a = p.im_b2[h];
          for (int i2 = 0; i2 < 32; ++i2) a = fmaf(__shfl(m1, i2, 32), iw2[i2 * 32 + h], a);
          const float m2 = fmaxf(a, 0.f);
          float p0 = m2 * iw3[h * 3 + 0];
          float p1 = m2 * iw3[h * 3 + 1];
          float p2 = m2 * iw3[h * 3 + 2];
#pragma unroll
          for (int m = 1; m < 32; m <<= 1) {
            p0 += __shfl_xor(p0, m, 32);
            p1 += __shfl_xor(p1, m, 32);
            p2 += __shfl_xor(p2, m, 32);
          }
          p0 += p.im_b3[0]; p1 += p.im_b3[1]; p2 += p.im_b3[2];
          const float step = sqrtf(p0 * p0 + p1 * p1 + p2 * p2);
          const float cum = s_cum;
          const float opc0 = s_qry[0] * cum, opc1 = s_qry[1] * cum, opc2 = s_qry[2] * cum;
          const float inv = 1.f / step;
          const float tg0 = p0 * inv, tg1 = p1 * inv, tg2 = p2 * inv;
          if (l == 0) {
            p.o_ms[b * 8 + s] = step;
            p.o_ip[(b * 8 + s) * 3 + 0] = opc0 + p0;
            s_op[0] = opc0 + s_qry[0] * step;
          } else if (l == 1) {
            p.o_ip[(b * 8 + s) * 3 + 1] = opc1 + p1;
            s_op[1] = opc1 + s_qry[1] * step;
          } else if (l == 2) {
            p.o_ip[(b * 8 + s) * 3 + 2] = opc2 + p2;
            s_op[2] = opc2 + s_qry[2] * step;
          } else if (l == 3) {
            s_cum = cum + step;
          }
          if (l < 16) {
            p.o_cs[b * 128 + s * 16 + l] = tg0 * rv0 + tg1 * rv1 + tg2 * rv2;
          }
        } else {
          float a = p.ep_b1[h];
          for (int i2 = 0; i2 < 32; ++i2) a = fmaf(__shfl(cav, i2, 32), p.ep_w1[i2 * 32 + h], a);
          a = fmaf(s_qry[0], p.ep_w1[1024 + h], a);
          a = fmaf(s_qry[1], p.ep_w1[1056 + h], a);
          a = fmaf(s_qry[2], p.ep_w1[1088 + h], a);
          const float e1 = fmaxf(a, 0.f);
          a = p.ep_b2[h];
          for (int i2 = 0; i2 < 32; ++i2) a = fmaf(__shfl(e1, i2, 32), p.ep_w2[i2 * 32 + h], a);
          const float e2 = fmaxf(a, 0.f);
          float pp = e2 * p.ep_w3[h];
#pragma unroll
          for (int m = 1; m < 32; m <<= 1) pp += __shfl_xor(pp, m, 32);
          if (l == 0) {
            p.o_eps[b] = pp + p.ep_b3[0];
            p.o_cum[b] = s_cum;
          }
        }
      }
    }
  }
}

extern "C" void kernel_launch(void* const* d_in, const int* in_sizes, int n_in,
                              void* d_out, int out_size, void* d_ws, size_t ws_size,
                              hipStream_t stream) {
  Params p;
  const float** f = (const float**)(void*)&p;
  for (int i = 0; i < 43; ++i) f[i] = (const float*)d_in[i];
  float* out = (float*)d_out;
  p.o_ld  = out;
  p.o_ms  = out + OFF_MS;
  p.o_cs  = out + OFF_CS;
  p.o_ip  = out + OFF_IP;
  p.o_cum = out + OFF_CUM;
  p.o_eps = out + OFF_EPS;
  unsigned short* ws = (unsigned short*)d_ws;
  prep_kernel<<<dim3(16), dim3(256), 0, stream>>>(p, ws);
  puray_kernel<<<dim3(4096), dim3(64), 0, stream>>>(p, ws);
}

// Round 21
// 395.397 us; speedup vs baseline: 2.4401x; 1.1500x over previous
//
#include <hip/hip_runtime.h>

// Problem constants: B=4096, K=16, H=32, HM=128, STEPS=8
#define OFF_MS  524288
#define OFF_CS  557056
#define OFF_IP  1081344
#define OFF_CUM 1179648
#define OFF_EPS 1183744

#define HSTR 136   // padded bf16 row stride (272B -> 2-way banks)
#define BSTR 40    // padded bf16 row stride (80B)

// d_ws layout (u16): bf16 weights transposed to [n][k]
#define WA_PTP 0        // ptp_w2T [32][128]
#define WB_PTA 4096     // pta_w1T [128][32]
#define WC_PTA 8192     // pta_w2T [32][128]
#define WA_CAP 12288    // cap_w2T [32][128]
#define WB_CAA 16384    // caa_w1T [128][32]
#define WC_CAA 20480    // caa_w2T [32][128]
#define WH_PTP 24576    // ptp_w1T [128 n][32 k] (k=0..2 w1, k=3 bias, else 0)
#define WH_CAP 28672    // cap_w1T [128 n][32 k] (same trick)

struct Params {
  const float *knn, *query, *fw1, *fb1, *fw2, *fb2, *fw3, *fb3, *qkv_w,
    *ptp_w1, *ptp_b1, *ptp_w2, *ptp_b2, *pta_w1, *pta_b1, *pta_w2, *pta_b2,
    *caq_w, *caq_b, *cak_w, *cak_b, *cav_w, *cav_b,
    *cap_w1, *cap_b1, *cap_w2, *cap_b2, *caa_w1, *caa_b1, *caa_w2, *caa_b2,
    *im_w1, *im_b1, *im_w2, *im_b2, *im_w3, *im_b3,
    *ep_w1, *ep_b1, *ep_w2, *ep_b2, *ep_w3, *ep_b3;
  float *o_ld, *o_ms, *o_cs, *o_ip, *o_cum, *o_eps;
};
static_assert(sizeof(Params) == 49 * sizeof(void*), "Params layout");

typedef float f32x4 __attribute__((ext_vector_type(4)));
typedef unsigned short u16x8 __attribute__((ext_vector_type(8)));

__device__ __forceinline__ unsigned short f2b(float x) {  // fp32->bf16 RNE
  unsigned u = __float_as_uint(x);
  u += 0x7fffu + ((u >> 16) & 1u);
  return (unsigned short)(u >> 16);
}
__device__ __forceinline__ unsigned pack2(float lo, float hi) {
  return (unsigned)f2b(lo) | ((unsigned)f2b(hi) << 16);
}

#define MFMA(acc, a, bb) \
  asm volatile("s_nop 2\n\tv_mfma_f32_16x16x32_bf16 %0, %1, %2, %0" \
               : "+v"(acc) : "v"(a), "v"(bb))
#define MFMA_FENCE(acc) asm volatile("s_nop 7\n\ts_nop 7" : "+v"(acc))
#define MFMA_FENCE4(a0, a1, a2, a3) \
  asm volatile("s_nop 7\n\ts_nop 7" : "+v"(a0), "+v"(a1), "+v"(a2), "+v"(a3))

// Prep: transpose+convert the 8 MFMA weight tables into d_ws (once/launch).
__global__ void prep_kernel(Params p, unsigned short* ws) {
  const int t = blockIdx.x * 256 + threadIdx.x;  // 0..4095
  const int n = t >> 7, k = t & 127;
  ws[WA_PTP + t] = f2b(p.ptp_w2[k * 32 + n]);
  ws[WC_PTA + t] = f2b(p.pta_w2[k * 32 + n]);
  ws[WA_CAP + t] = f2b(p.cap_w2[k * 32 + n]);
  ws[WC_CAA + t] = f2b(p.caa_w2[k * 32 + n]);
  const int n2 = t >> 5, k2 = t & 31;
  ws[WB_PTA + t] = f2b(p.pta_w1[k2 * 128 + n2]);
  ws[WB_CAA + t] = f2b(p.caa_w1[k2 * 128 + n2]);
  ws[WH_PTP + t] = (k2 < 3) ? f2b(p.ptp_w1[k2 * 128 + n2])
                  : (k2 == 3 ? f2b(p.ptp_b1[n2]) : (unsigned short)0);
  ws[WH_CAP + t] = (k2 < 3) ? f2b(p.cap_w1[k2 * 128 + n2])
                  : (k2 == 3 ? f2b(p.cap_b1[n2]) : (unsigned short)0);
}

// WAVE-PER-BATCH, round-16/20 config ((64,2), 18.9KB LDS, 8 waves/CU).
// Round-20 analysis: latency-chain-bound -- ~475 cyc/dependent-hop, i.e.
// each MFMA section pays per-fragment load latency SERIALLY (asm-volatile
// MFMAs pin order; allocator avoids hoisting loads). This round batches
// all B-fragment loads into NAMED registers BEFORE each MFMA group:
// 4 independent accs + one combined fence for hv/G2/secC; hoisted shared
// A-fragments + 4 batched B-loads for the chained G1/G3/secB/secD.
// One ~450c latency per group instead of 4-8.
__launch_bounds__(64, 2)
__global__ void puray_kernel(Params p, const unsigned short* ws) {
  const int b = blockIdx.x;
  const int l = threadIdx.x;
  const int ln16 = l & 15, kg = l >> 4, k0 = kg * 8;

  __shared__ __align__(16) unsigned short s_hvb[16 * HSTR];   // hv A-operand
  __shared__ __align__(16) unsigned short s_hidb[16 * HSTR];  // G2/secC out
  __shared__ __align__(16) unsigned short s_simb[16 * BSTR];
  __shared__ float s_feats[512], s_v[512];
  __shared__ float s_u[1024];    // A: h1|h2 ; B/C: q|k ; D: kk|vvb
  __shared__ float s_coords[48], s_relv[48], s_reld[16];
  __shared__ float s_qry[3], s_op[3], s_qq[32], s_ca[32];
  __shared__ float s_cum;

  if (l < 48) s_coords[l] = p.knn[b * 48 + l];
  else if (l < 51) s_qry[l - 48] = p.query[b * 3 + (l - 48)];
  else if (l == 51) s_cum = 0.f;
  else if (l < 55) s_op[l - 52] = 0.f;
  __syncthreads();

  // ---- Phase A: feats (h1 -> s_u[0:512], h2 -> s_u[512:1024]) ----
  for (int m = 0; m < 8; ++m) {
    const int idx = l + 64 * m, pp = idx >> 5, jj = idx & 31;
    float a = p.fb1[jj];
    for (int c = 0; c < 3; ++c) a = fmaf(s_coords[pp * 3 + c], p.fw1[c * 32 + jj], a);
    s_u[idx] = fmaxf(a, 0.f);
  }
  for (int m = 0; m < 8; ++m) {
    const int idx = l + 64 * m, pp = idx >> 5, jj = idx & 31;
    float a = p.fb2[jj];
    for (int i = 0; i < 32; ++i) a = fmaf(s_u[pp * 32 + i], p.fw2[i * 32 + jj], a);
    s_u[512 + idx] = fmaxf(a, 0.f);
  }
  for (int m = 0; m < 8; ++m) {
    const int idx = l + 64 * m, pp = idx >> 5, jj = idx & 31;
    float a = p.fb3[jj];
    for (int i = 0; i < 32; ++i) a = fmaf(s_u[512 + pp * 32 + i], p.fw3[i * 32 + jj], a);
    s_feats[idx] = a;
  }
  // ---- Phase B: qkv -> s_u (q|k) + s_v ----
  for (int m = 0; m < 24; ++m) {
    const int idx = l + 64 * m, pp = idx / 96, o = idx % 96;
    float a = 0.f;
    for (int i = 0; i < 32; ++i) a = fmaf(s_feats[pp * 32 + i], p.qkv_w[i * 96 + o], a);
    if (o < 32) s_u[pp * 32 + o] = a;
    else if (o < 64) s_u[512 + pp * 32 + o - 32] = a;
    else s_v[pp * 32 + o - 64] = a;
  }

  // ---- Phase C: one i-row at a time, all within the wave ----
  {
    const float* b2c = p.ptp_b2;
    const float* bh1 = p.pta_b1;
    const float* bh2 = p.pta_b2;
    const unsigned short* wsc = ws;
    for (int i = 0; i < 16; ++i) {
      asm volatile("" : "+s"(b2c), "+s"(bh1), "+s"(bh2), "+s"(wsc));
      const float c0 = s_coords[i * 3 + 0] - s_coords[ln16 * 3 + 0];
      const float c1 = s_coords[i * 3 + 1] - s_coords[ln16 * 3 + 1];
      const float c2 = s_coords[i * 3 + 2] - s_coords[ln16 * 3 + 2];
      {  // hv[16][128] via MFMA, batched loads, 4 accs + 1 fence per group
        union { u16x8 v; unsigned u[4]; } cv;
        cv.u[0] = (kg == 0) ? pack2(c0, c1) : 0u;
        cv.u[1] = (kg == 0) ? pack2(c2, 1.0f) : 0u;
        cv.u[2] = 0u; cv.u[3] = 0u;
        const u16x8 afh = cv.v;
#pragma unroll
        for (int g2b = 0; g2b < 2; ++g2b) {
          const int nbase = g2b * 4;
          const u16x8 w0 = *(const u16x8*)&wsc[WH_PTP + ((nbase + 0) * 16 + ln16) * 32 + k0];
          const u16x8 w1 = *(const u16x8*)&wsc[WH_PTP + ((nbase + 1) * 16 + ln16) * 32 + k0];
          const u16x8 w2 = *(const u16x8*)&wsc[WH_PTP + ((nbase + 2) * 16 + ln16) * 32 + k0];
          const u16x8 w3 = *(const u16x8*)&wsc[WH_PTP + ((nbase + 3) * 16 + ln16) * 32 + k0];
          f32x4 A0 = {0.f,0.f,0.f,0.f}, A1 = {0.f,0.f,0.f,0.f};
          f32x4 A2 = {0.f,0.f,0.f,0.f}, A3 = {0.f,0.f,0.f,0.f};
          MFMA(A0, afh, w0); MFMA(A1, afh, w1); MFMA(A2, afh, w2); MFMA(A3, afh, w3);
          MFMA_FENCE4(A0, A1, A2, A3);
#pragma unroll
          for (int r2 = 0; r2 < 4; ++r2) {
            const int row = (kg * 4 + r2) * HSTR;
            s_hvb[row + (nbase + 0) * 16 + ln16] = f2b(fmaxf(A0[r2], 0.f));
            s_hvb[row + (nbase + 1) * 16 + ln16] = f2b(fmaxf(A1[r2], 0.f));
            s_hvb[row + (nbase + 2) * 16 + ln16] = f2b(fmaxf(A2[r2], 0.f));
            s_hvb[row + (nbase + 3) * 16 + ln16] = f2b(fmaxf(A3[r2], 0.f));
          }
        }
      }
      f32x4 rpe0, rpe1;
      {  // G1: hoisted A-fragments + batched B-loads, chained MFMA
        const u16x8 a0 = *(const u16x8*)&s_hvb[ln16 * HSTR + 0 * 32 + k0];
        const u16x8 a1 = *(const u16x8*)&s_hvb[ln16 * HSTR + 1 * 32 + k0];
        const u16x8 a2f = *(const u16x8*)&s_hvb[ln16 * HSTR + 2 * 32 + k0];
        const u16x8 a3f = *(const u16x8*)&s_hvb[ln16 * HSTR + 3 * 32 + k0];
#pragma unroll
        for (int nb = 0; nb < 2; ++nb) {
          const int n = nb * 16 + ln16;
          const u16x8 w0 = *(const u16x8*)&wsc[WA_PTP + n * 128 + 0 * 32 + k0];
          const u16x8 w1 = *(const u16x8*)&wsc[WA_PTP + n * 128 + 1 * 32 + k0];
          const u16x8 w2 = *(const u16x8*)&wsc[WA_PTP + n * 128 + 2 * 32 + k0];
          const u16x8 w3 = *(const u16x8*)&wsc[WA_PTP + n * 128 + 3 * 32 + k0];
          const float bias = b2c[n];
          f32x4 acc = {bias, bias, bias, bias};
          MFMA(acc, a0, w0); MFMA(acc, a1, w1); MFMA(acc, a2f, w2); MFMA(acc, a3f, w3);
          MFMA_FENCE(acc);
          if (nb == 0) rpe0 = acc; else rpe1 = acc;
#pragma unroll
          for (int r2 = 0; r2 < 4; ++r2) {
            const int j = kg * 4 + r2;
            s_simb[j * BSTR + n] = f2b(s_u[i * 32 + n] - s_u[512 + j * 32 + n] + acc[r2]);
          }
        }
      }
      {  // G2: batched loads, 4 accs + 1 fence per group
        const u16x8 as = *(const u16x8*)&s_simb[ln16 * BSTR + k0];
#pragma unroll
        for (int g2b = 0; g2b < 2; ++g2b) {
          const int nbase = g2b * 4;
          const u16x8 w0 = *(const u16x8*)&wsc[WB_PTA + ((nbase + 0) * 16 + ln16) * 32 + k0];
          const u16x8 w1 = *(const u16x8*)&wsc[WB_PTA + ((nbase + 1) * 16 + ln16) * 32 + k0];
          const u16x8 w2 = *(const u16x8*)&wsc[WB_PTA + ((nbase + 2) * 16 + ln16) * 32 + k0];
          const u16x8 w3 = *(const u16x8*)&wsc[WB_PTA + ((nbase + 3) * 16 + ln16) * 32 + k0];
          const float b0 = bh1[(nbase + 0) * 16 + ln16];
          const float b1v = bh1[(nbase + 1) * 16 + ln16];
          const float b2v = bh1[(nbase + 2) * 16 + ln16];
          const float b3 = bh1[(nbase + 3) * 16 + ln16];
          f32x4 A0 = {b0,b0,b0,b0}, A1 = {b1v,b1v,b1v,b1v};
          f32x4 A2 = {b2v,b2v,b2v,b2v}, A3 = {b3,b3,b3,b3};
          MFMA(A0, as, w0); MFMA(A1, as, w1); MFMA(A2, as, w2); MFMA(A3, as, w3);
          MFMA_FENCE4(A0, A1, A2, A3);
#pragma unroll
          for (int r2 = 0; r2 < 4; ++r2) {
            const int row = (kg * 4 + r2) * HSTR;
            s_hidb[row + (nbase + 0) * 16 + ln16] = f2b(fmaxf(A0[r2], 0.f));
            s_hidb[row + (nbase + 1) * 16 + ln16] = f2b(fmaxf(A1[r2], 0.f));
            s_hidb[row + (nbase + 2) * 16 + ln16] = f2b(fmaxf(A2[r2], 0.f));
            s_hidb[row + (nbase + 3) * 16 + ln16] = f2b(fmaxf(A3[r2], 0.f));
          }
        }
      }
      {  // G3 + fused softmax: hoisted A-fragments + batched B-loads
        const u16x8 h0 = *(const u16x8*)&s_hidb[ln16 * HSTR + 0 * 32 + k0];
        const u16x8 h1 = *(const u16x8*)&s_hidb[ln16 * HSTR + 1 * 32 + k0];
        const u16x8 h2 = *(const u16x8*)&s_hidb[ln16 * HSTR + 2 * 32 + k0];
        const u16x8 h3 = *(const u16x8*)&s_hidb[ln16 * HSTR + 3 * 32 + k0];
#pragma unroll
        for (int nb = 0; nb < 2; ++nb) {
          const int n = nb * 16 + ln16;
          const u16x8 w0 = *(const u16x8*)&wsc[WC_PTA + n * 128 + 0 * 32 + k0];
          const u16x8 w1 = *(const u16x8*)&wsc[WC_PTA + n * 128 + 1 * 32 + k0];
          const u16x8 w2 = *(const u16x8*)&wsc[WC_PTA + n * 128 + 2 * 32 + k0];
          const u16x8 w3 = *(const u16x8*)&wsc[WC_PTA + n * 128 + 3 * 32 + k0];
          const float bias = bh2[n];
          f32x4 acc = {bias, bias, bias, bias};
          MFMA(acc, h0, w0); MFMA(acc, h1, w1); MFMA(acc, h2, w2); MFMA(acc, h3, w3);
          MFMA_FENCE(acc);
          const f32x4 rp = nb ? rpe1 : rpe0;
          float mx = fmaxf(fmaxf(acc[0], acc[1]), fmaxf(acc[2], acc[3]));
          mx = fmaxf(mx, __shfl_xor(mx, 16));
          mx = fmaxf(mx, __shfl_xor(mx, 32));
          float sum = 0.f, o = 0.f;
#pragma unroll
          for (int r2 = 0; r2 < 4; ++r2) {
            const int j = kg * 4 + r2;
            const float e = __expf(acc[r2] - mx);
            sum += e;
            o = fmaf(e, s_v[j * 32 + n] + rp[r2], o);
          }
          sum += __shfl_xor(sum, 16); o += __shfl_xor(o, 16);
          sum += __shfl_xor(sum, 32); o += __shfl_xor(o, 32);
          if (kg == 0) s_feats[i * 32 + n] = o / sum;
        }
      }
    }
  }

  // ---- kk / vvb (overwrite q|k in s_u) ----
  for (int m = 0; m < 8; ++m) {
    const int idx = l + 64 * m, k = idx >> 5, h = idx & 31;
    float akk = p.cak_b[h], avv = p.cav_b[h];
    for (int i = 0; i < 32; ++i) {
      const float f = s_feats[k * 32 + i];
      akk = fmaf(f, p.cak_w[i * 32 + h], akk);
      avv = fmaf(f, p.cav_w[i * 32 + h], avv);
    }
    s_u[k * 32 + h] = akk;
    s_u[512 + k * 32 + h] = avv;
  }

  // ---- Phase D: 8 march steps + epilogue, all within the wave ----
  {
    const float* b2d = p.cap_b2;
    const float* bc1 = p.caa_b1;
    const float* bc2 = p.caa_b2;
    const float* fw1 = p.fw1; const float* fw2 = p.fw2; const float* fw3 = p.fw3;
    const float* cqw = p.caq_w;
    const float* iw1 = p.im_w1; const float* iw2 = p.im_w2; const float* iw3 = p.im_w3;
    const unsigned short* wsd = ws;
    for (int s = 0; s <= 8; ++s) {
      asm volatile("" : "+s"(b2d), "+s"(bc1), "+s"(bc2), "+s"(wsd));
      asm volatile("" : "+s"(fw1), "+s"(fw2), "+s"(fw3), "+s"(cqw), "+s"(iw1), "+s"(iw2), "+s"(iw3));
      float rv0 = 0.f, rv1 = 0.f, rv2 = 0.f;
      if (s < 8 && l < 16) {  // rel + o_ld
        const float r0 = s_coords[l * 3 + 0] - s_op[0];
        const float r1 = s_coords[l * 3 + 1] - s_op[1];
        const float r2 = s_coords[l * 3 + 2] - s_op[2];
        const float rd = sqrtf(r0 * r0 + r1 * r1 + r2 * r2);
        const float inv = 1.f / rd;
        rv0 = r0 * inv; rv1 = r1 * inv; rv2 = r2 * inv;
        s_reld[l] = rd;
        s_relv[l * 3 + 0] = rv0; s_relv[l * 3 + 1] = rv1; s_relv[l * 3 + 2] = rv2;
        p.o_ld[b * 128 + s * 16 + l] = rd;
      }
      {  // secA: hv via MFMA, batched (same pattern as phase C)
        float c0, c1, c2;
        if (s < 8) {
          c0 = s_coords[ln16 * 3 + 0] - s_op[0];
          c1 = s_coords[ln16 * 3 + 1] - s_op[1];
          c2 = s_coords[ln16 * 3 + 2] - s_op[2];
        } else {
          const float rd = s_reld[ln16];
          c0 = s_relv[ln16 * 3 + 0] * rd; c1 = s_relv[ln16 * 3 + 1] * rd; c2 = s_relv[ln16 * 3 + 2] * rd;
        }
        union { u16x8 v; unsigned u[4]; } cv;
        cv.u[0] = (kg == 0) ? pack2(c0, c1) : 0u;
        cv.u[1] = (kg == 0) ? pack2(c2, 1.0f) : 0u;
        cv.u[2] = 0u; cv.u[3] = 0u;
        const u16x8 afh = cv.v;
#pragma unroll
        for (int g2b = 0; g2b < 2; ++g2b) {
          const int nbase = g2b * 4;
          const u16x8 w0 = *(const u16x8*)&wsd[WH_CAP + ((nbase + 0) * 16 + ln16) * 32 + k0];
          const u16x8 w1 = *(const u16x8*)&wsd[WH_CAP + ((nbase + 1) * 16 + ln16) * 32 + k0];
          const u16x8 w2 = *(const u16x8*)&wsd[WH_CAP + ((nbase + 2) * 16 + ln16) * 32 + k0];
          const u16x8 w3 = *(const u16x8*)&wsd[WH_CAP + ((nbase + 3) * 16 + ln16) * 32 + k0];
          f32x4 A0 = {0.f,0.f,0.f,0.f}, A1 = {0.f,0.f,0.f,0.f};
          f32x4 A2 = {0.f,0.f,0.f,0.f}, A3 = {0.f,0.f,0.f,0.f};
          MFMA(A0, afh, w0); MFMA(A1, afh, w1); MFMA(A2, afh, w2); MFMA(A3, afh, w3);
          MFMA_FENCE4(A0, A1, A2, A3);
#pragma unroll
          for (int r2 = 0; r2 < 4; ++r2) {
            const int row = (kg * 4 + r2) * HSTR;
            s_hvb[row + (nbase + 0) * 16 + ln16] = f2b(fmaxf(A0[r2], 0.f));
            s_hvb[row + (nbase + 1) * 16 + ln16] = f2b(fmaxf(A1[r2], 0.f));
            s_hvb[row + (nbase + 2) * 16 + ln16] = f2b(fmaxf(A2[r2], 0.f));
            s_hvb[row + (nbase + 3) * 16 + ln16] = f2b(fmaxf(A3[r2], 0.f));
          }
        }
      }
      {  // qq chain (all lanes, width-32 shuffles; halves duplicate)
        const int h = l & 31;
        float opc0, opc1, opc2;
        if (s < 8) {
          const float cum = s_cum;
          opc0 = s_qry[0] * cum; opc1 = s_qry[1] * cum; opc2 = s_qry[2] * cum;
        } else {
          opc0 = s_op[0]; opc1 = s_op[1]; opc2 = s_op[2];
        }
        float v1 = fmaxf(fmaf(opc0, fw1[h],
                      fmaf(opc1, fw1[32 + h],
                      fmaf(opc2, fw1[64 + h], p.fb1[h]))), 0.f);
        float a = p.fb2[h];
        for (int i2 = 0; i2 < 32; ++i2) a = fmaf(__shfl(v1, i2, 32), fw2[i2 * 32 + h], a);
        const float v2 = fmaxf(a, 0.f);
        a = p.fb3[h];
        for (int i2 = 0; i2 < 32; ++i2) a = fmaf(__shfl(v2, i2, 32), fw3[i2 * 32 + h], a);
        const float opf = a;
        a = p.caq_b[h];
        for (int i2 = 0; i2 < 32; ++i2) a = fmaf(__shfl(opf, i2, 32), cqw[i2 * 32 + h], a);
        if (l < 32) s_qq[h] = a;
      }
      f32x4 pe0, pe1;
      {  // secB: hoisted A-fragments + batched B-loads
        const u16x8 a0 = *(const u16x8*)&s_hvb[ln16 * HSTR + 0 * 32 + k0];
        const u16x8 a1 = *(const u16x8*)&s_hvb[ln16 * HSTR + 1 * 32 + k0];
        const u16x8 a2f = *(const u16x8*)&s_hvb[ln16 * HSTR + 2 * 32 + k0];
        const u16x8 a3f = *(const u16x8*)&s_hvb[ln16 * HSTR + 3 * 32 + k0];
#pragma unroll
        for (int nb = 0; nb < 2; ++nb) {
          const int n = nb * 16 + ln16;
          const u16x8 w0 = *(const u16x8*)&wsd[WA_CAP + n * 128 + 0 * 32 + k0];
          const u16x8 w1 = *(const u16x8*)&wsd[WA_CAP + n * 128 + 1 * 32 + k0];
          const u16x8 w2 = *(const u16x8*)&wsd[WA_CAP + n * 128 + 2 * 32 + k0];
          const u16x8 w3 = *(const u16x8*)&wsd[WA_CAP + n * 128 + 3 * 32 + k0];
          const float bias = b2d[n];
          f32x4 acc = {bias, bias, bias, bias};
          MFMA(acc, a0, w0); MFMA(acc, a1, w1); MFMA(acc, a2f, w2); MFMA(acc, a3f, w3);
          MFMA_FENCE(acc);
          if (nb == 0) pe0 = acc; else pe1 = acc;
#pragma unroll
          for (int r2 = 0; r2 < 4; ++r2) {
            const int row = kg * 4 + r2;
            s_simb[row * BSTR + n] = f2b(s_qq[n] - s_u[row * 32 + n] + acc[r2]);
          }
        }
      }
      {  // secC: batched loads, 4 accs + 1 fence per group
        const u16x8 as = *(const u16x8*)&s_simb[ln16 * BSTR + k0];
#pragma unroll
        for (int g2b = 0; g2b < 2; ++g2b) {
          const int nbase = g2b * 4;
          const u16x8 w0 = *(const u16x8*)&wsd[WB_CAA + ((nbase + 0) * 16 + ln16) * 32 + k0];
          const u16x8 w1 = *(const u16x8*)&wsd[WB_CAA + ((nbase + 1) * 16 + ln16) * 32 + k0];
          const u16x8 w2 = *(const u16x8*)&wsd[WB_CAA + ((nbase + 2) * 16 + ln16) * 32 + k0];
          const u16x8 w3 = *(const u16x8*)&wsd[WB_CAA + ((nbase + 3) * 16 + ln16) * 32 + k0];
          const float b0 = bc1[(nbase + 0) * 16 + ln16];
          const float b1v = bc1[(nbase + 1) * 16 + ln16];
          const float b2v = bc1[(nbase + 2) * 16 + ln16];
          const float b3 = bc1[(nbase + 3) * 16 + ln16];
          f32x4 A0 = {b0,b0,b0,b0}, A1 = {b1v,b1v,b1v,b1v};
          f32x4 A2 = {b2v,b2v,b2v,b2v}, A3 = {b3,b3,b3,b3};
          MFMA(A0, as, w0); MFMA(A1, as, w1); MFMA(A2, as, w2); MFMA(A3, as, w3);
          MFMA_FENCE4(A0, A1, A2, A3);
#pragma unroll
          for (int r2 = 0; r2 < 4; ++r2) {
            const int row = (kg * 4 + r2) * HSTR;
            s_hidb[row + (nbase + 0) * 16 + ln16] = f2b(fmaxf(A0[r2], 0.f));
            s_hidb[row + (nbase + 1) * 16 + ln16] = f2b(fmaxf(A1[r2], 0.f));
            s_hidb[row + (nbase + 2) * 16 + ln16] = f2b(fmaxf(A2[r2], 0.f));
            s_hidb[row + (nbase + 3) * 16 + ln16] = f2b(fmaxf(A3[r2], 0.f));
          }
        }
      }
      // secD + in-register softmax -> ca0/ca1 (hoisted A + batched B)
      float ca0 = 0.f, ca1 = 0.f;
      {
        const u16x8 h0 = *(const u16x8*)&s_hidb[ln16 * HSTR + 0 * 32 + k0];
        const u16x8 h1 = *(const u16x8*)&s_hidb[ln16 * HSTR + 1 * 32 + k0];
        const u16x8 h2 = *(const u16x8*)&s_hidb[ln16 * HSTR + 2 * 32 + k0];
        const u16x8 h3 = *(const u16x8*)&s_hidb[ln16 * HSTR + 3 * 32 + k0];
#pragma unroll
        for (int nb = 0; nb < 2; ++nb) {
          const int n = nb * 16 + ln16;
          const u16x8 w0 = *(const u16x8*)&wsd[WC_CAA + n * 128 + 0 * 32 + k0];
          const u16x8 w1 = *(const u16x8*)&wsd[WC_CAA + n * 128 + 1 * 32 + k0];
          const u16x8 w2 = *(const u16x8*)&wsd[WC_CAA + n * 128 + 2 * 32 + k0];
          const u16x8 w3 = *(const u16x8*)&wsd[WC_CAA + n * 128 + 3 * 32 + k0];
          const float bias = bc2[n];
          f32x4 acc = {bias, bias, bias, bias};
          MFMA(acc, h0, w0); MFMA(acc, h1, w1); MFMA(acc, h2, w2); MFMA(acc, h3, w3);
          MFMA_FENCE(acc);
          const f32x4 rp = nb ? pe1 : pe0;
          float mx = fmaxf(fmaxf(acc[0], acc[1]), fmaxf(acc[2], acc[3]));
          mx = fmaxf(mx, __shfl_xor(mx, 16));
          mx = fmaxf(mx, __shfl_xor(mx, 32));
          float sum = 0.f, o = 0.f;
#pragma unroll
          for (int r2 = 0; r2 < 4; ++r2) {
            const int row = kg * 4 + r2;
            const float e = __expf(acc[r2] - mx);
            sum += e;
            o = fmaf(e, s_u[512 + row * 32 + n] + rp[r2], o);
          }
          sum += __shfl_xor(sum, 16); o += __shfl_xor(o, 16);
          sum += __shfl_xor(sum, 32); o += __shfl_xor(o, 32);
          if (nb == 0) ca0 = o / sum; else ca1 = o / sum;
        }
      }
      if (kg == 0) { s_ca[ln16] = ca0; s_ca[16 + ln16] = ca1; }
      {  // im / ep chain (width-32; halves duplicate; writes guarded)
        const int h = l & 31;
        const float cav = s_ca[h];
        if (s < 8) {
          float a = p.im_b1[h];
          for (int i2 = 0; i2 < 32; ++i2) a = fmaf(__shfl(cav, i2, 32), iw1[i2 * 32 + h], a);
          const float m1 = fmaxf(a, 0.f);
          a = p.im_b2[h];
          for (int i2 = 0; i2 < 32; ++i2) a = fmaf(__shfl(m1, i2, 32), iw2[i2 * 32 + h], a);
          const float m2 = fmaxf(a, 0.f);
          float p0 = m2 * iw3[h * 3 + 0];
          float p1 = m2 * iw3[h * 3 + 1];
          float p2 = m2 * iw3[h * 3 + 2];
#pragma unroll
          for (int m = 1; m < 32; m <<= 1) {
            p0 += __shfl_xor(p0, m, 32);
            p1 += __shfl_xor(p1, m, 32);
            p2 += __shfl_xor(p2, m, 32);
          }
          p0 += p.im_b3[0]; p1 += p.im_b3[1]; p2 += p.im_b3[2];
          const float step = sqrtf(p0 * p0 + p1 * p1 + p2 * p2);
          const float cum = s_cum;
          const float opc0 = s_qry[0] * cum, opc1 = s_qry[1] * cum, opc2 = s_qry[2] * cum;
          const float inv = 1.f / step;
          const float tg0 = p0 * inv, tg1 = p1 * inv, tg2 = p2 * inv;
          if (l == 0) {
            p.o_ms[b * 8 + s] = step;
            p.o_ip[(b * 8 + s) * 3 + 0] = opc0 + p0;
            s_op[0] = opc0 + s_qry[0] * step;
          } else if (l == 1) {
            p.o_ip[(b * 8 + s) * 3 + 1] = opc1 + p1;
            s_op[1] = opc1 + s_qry[1] * step;
          } else if (l == 2) {
            p.o_ip[(b * 8 + s) * 3 + 2] = opc2 + p2;
            s_op[2] = opc2 + s_qry[2] * step;
          } else if (l == 3) {
            s_cum = cum + step;
          }
          if (l < 16) {
            p.o_cs[b * 128 + s * 16 + l] = tg0 * rv0 + tg1 * rv1 + tg2 * rv2;
          }
        } else {
          float a = p.ep_b1[h];
          for (int i2 = 0; i2 < 32; ++i2) a = fmaf(__shfl(cav, i2, 32), p.ep_w1[i2 * 32 + h], a);
          a = fmaf(s_qry[0], p.ep_w1[1024 + h], a);
          a = fmaf(s_qry[1], p.ep_w1[1056 + h], a);
          a = fmaf(s_qry[2], p.ep_w1[1088 + h], a);
          const float e1 = fmaxf(a, 0.f);
          a = p.ep_b2[h];
          for (int i2 = 0; i2 < 32; ++i2) a = fmaf(__shfl(e1, i2, 32), p.ep_w2[i2 * 32 + h], a);
          const float e2 = fmaxf(a, 0.f);
          float pp = e2 * p.ep_w3[h];
#pragma unroll
          for (int m = 1; m < 32; m <<= 1) pp += __shfl_xor(pp, m, 32);
          if (l == 0) {
            p.o_eps[b] = pp + p.ep_b3[0];
            p.o_cum[b] = s_cum;
          }
        }
      }
    }
  }
}

extern "C" void kernel_launch(void* const* d_in, const int* in_sizes, int n_in,
                              void* d_out, int out_size, void* d_ws, size_t ws_size,
                              hipStream_t stream) {
  Params p;
  const float** f = (const float**)(void*)&p;
  for (int i = 0; i < 43; ++i) f[i] = (const float*)d_in[i];
  float* out = (float*)d_out;
  p.o_ld  = out;
  p.o_ms  = out + OFF_MS;
  p.o_cs  = out + OFF_CS;
  p.o_ip  = out + OFF_IP;
  p.o_cum = out + OFF_CUM;
  p.o_eps = out + OFF_EPS;
  unsigned short* ws = (unsigned short*)d_ws;
  prep_kernel<<<dim3(16), dim3(256), 0, stream>>>(p, ws);
  puray_kernel<<<dim3(4096), dim3(64), 0, stream>>>(p, ws);
}

// Round 22
// 366.305 us; speedup vs baseline: 2.6338x; 1.0794x over previous
//
#include <hip/hip_runtime.h>

// Problem constants: B=4096, K=16, H=32, HM=128, STEPS=8
#define OFF_MS  524288
#define OFF_CS  557056
#define OFF_IP  1081344
#define OFF_CUM 1179648
#define OFF_EPS 1183744

#define HSTR 136   // padded bf16 row stride (272B -> 2-way banks)
#define BSTR 40    // padded bf16 row stride (80B)

// d_ws layout (u16): bf16 weights transposed to [n][k]
#define WA_PTP 0        // ptp_w2T [32][128]
#define WB_PTA 4096     // pta_w1T [128][32]
#define WC_PTA 8192     // pta_w2T [32][128]
#define WA_CAP 12288    // cap_w2T [32][128]
#define WB_CAA 16384    // caa_w1T [128][32]
#define WC_CAA 20480    // caa_w2T [32][128]
#define WH_PTP 24576    // ptp_w1T [128 n][32 k] (k<3 w1, k==3 bias, else 0)
#define WH_CAP 28672    // cap_w1T [128 n][32 k]
#define WF1    32768    // fw1T [32 n][32 k] (k<3 w1, k==3 fb1, else 0)
#define WF2    33792    // fw2T [32 n][32 k]
#define WF3    34816    // fw3T [32 n][32 k]
#define WQKV   35840    // qkv_wT [96 n][32 k]
#define WKK    38912    // cak_wT [32 n][32 k]
#define WVV    39936    // cav_wT [32 n][32 k]

struct Params {
  const float *knn, *query, *fw1, *fb1, *fw2, *fb2, *fw3, *fb3, *qkv_w,
    *ptp_w1, *ptp_b1, *ptp_w2, *ptp_b2, *pta_w1, *pta_b1, *pta_w2, *pta_b2,
    *caq_w, *caq_b, *cak_w, *cak_b, *cav_w, *cav_b,
    *cap_w1, *cap_b1, *cap_w2, *cap_b2, *caa_w1, *caa_b1, *caa_w2, *caa_b2,
    *im_w1, *im_b1, *im_w2, *im_b2, *im_w3, *im_b3,
    *ep_w1, *ep_b1, *ep_w2, *ep_b2, *ep_w3, *ep_b3;
  float *o_ld, *o_ms, *o_cs, *o_ip, *o_cum, *o_eps;
};
static_assert(sizeof(Params) == 49 * sizeof(void*), "Params layout");

typedef float f32x4 __attribute__((ext_vector_type(4)));
typedef unsigned short u16x8 __attribute__((ext_vector_type(8)));

__device__ __forceinline__ unsigned short f2b(float x) {  // fp32->bf16 RNE
  unsigned u = __float_as_uint(x);
  u += 0x7fffu + ((u >> 16) & 1u);
  return (unsigned short)(u >> 16);
}
__device__ __forceinline__ unsigned pack2(float lo, float hi) {
  return (unsigned)f2b(lo) | ((unsigned)f2b(hi) << 16);
}

#define MFMA(acc, a, bb) \
  asm volatile("s_nop 2\n\tv_mfma_f32_16x16x32_bf16 %0, %1, %2, %0" \
               : "+v"(acc) : "v"(a), "v"(bb))
#define MFMA_FENCE(acc) asm volatile("s_nop 7\n\ts_nop 7" : "+v"(acc))
#define MFMA_FENCE2(a0, a1) \
  asm volatile("s_nop 7\n\ts_nop 7" : "+v"(a0), "+v"(a1))
#define MFMA_FENCE4(a0, a1, a2, a3) \
  asm volatile("s_nop 7\n\ts_nop 7" : "+v"(a0), "+v"(a1), "+v"(a2), "+v"(a3))

// Prep: transpose+convert all 14 MFMA weight tables into d_ws (once/launch).
__global__ void prep_kernel(Params p, unsigned short* ws) {
  const int t = blockIdx.x * 256 + threadIdx.x;  // 0..4095
  const int n = t >> 7, k = t & 127;
  ws[WA_PTP + t] = f2b(p.ptp_w2[k * 32 + n]);
  ws[WC_PTA + t] = f2b(p.pta_w2[k * 32 + n]);
  ws[WA_CAP + t] = f2b(p.cap_w2[k * 32 + n]);
  ws[WC_CAA + t] = f2b(p.caa_w2[k * 32 + n]);
  const int n2 = t >> 5, k2 = t & 31;
  ws[WB_PTA + t] = f2b(p.pta_w1[k2 * 128 + n2]);
  ws[WB_CAA + t] = f2b(p.caa_w1[k2 * 128 + n2]);
  ws[WH_PTP + t] = (k2 < 3) ? f2b(p.ptp_w1[k2 * 128 + n2])
                  : (k2 == 3 ? f2b(p.ptp_b1[n2]) : (unsigned short)0);
  ws[WH_CAP + t] = (k2 < 3) ? f2b(p.cap_w1[k2 * 128 + n2])
                  : (k2 == 3 ? f2b(p.cap_b1[n2]) : (unsigned short)0);
  if (t < 1024) {
    ws[WF1 + t] = (k2 < 3) ? f2b(p.fw1[k2 * 32 + n2])
                 : (k2 == 3 ? f2b(p.fb1[n2]) : (unsigned short)0);
    ws[WF2 + t] = f2b(p.fw2[k2 * 32 + n2]);
    ws[WF3 + t] = f2b(p.fw3[k2 * 32 + n2]);
    ws[WKK + t] = f2b(p.cak_w[k2 * 32 + n2]);
    ws[WVV + t] = f2b(p.cav_w[k2 * 32 + n2]);
  }
  if (t < 3072) ws[WQKV + t] = f2b(p.qkv_w[k2 * 96 + n2]);
}

// WAVE-PER-BATCH round-21 structure (395us) + phases A/B/kk MFMA-ized.
// The last scalar GEMM islands (feat_mlp 3 layers, qkv, kk/vv -- ~1800
// chained fma+load per lane) become 12 MFMAs using the proven section
// patterns (K=3 bias-folding for layer 1, batched B-loads). s_feats(fp32)
// deleted; feats live as bf16 s_featb consumed directly as A-operands.
__launch_bounds__(64, 2)
__global__ void puray_kernel(Params p, const unsigned short* ws) {
  const int b = blockIdx.x;
  const int l = threadIdx.x;
  const int ln16 = l & 15, kg = l >> 4, k0 = kg * 8;

  __shared__ __align__(16) unsigned short s_hvb[16 * HSTR];   // hv A-operand
  __shared__ __align__(16) unsigned short s_hidb[16 * HSTR];  // G2/secC out
  __shared__ __align__(16) unsigned short s_simb[16 * BSTR];
  __shared__ __align__(16) unsigned short s_featb[16 * BSTR]; // bf16 feats
  __shared__ float s_v[512];
  __shared__ float s_u[1024];    // C: q|k ; D: kk|vvb
  __shared__ float s_coords[48], s_relv[48], s_reld[16];
  __shared__ float s_qry[3], s_op[3], s_qq[32], s_ca[32];
  __shared__ float s_cum;

  if (l < 48) s_coords[l] = p.knn[b * 48 + l];
  else if (l < 51) s_qry[l - 48] = p.query[b * 3 + (l - 48)];
  else if (l == 51) s_cum = 0.f;
  else if (l < 55) s_op[l - 52] = 0.f;
  __syncthreads();

  // ---- Phase A (MFMA): L1 (K=3 fold) -> L2 -> L3 -> s_featb ----
  {
    const unsigned short* wsa = ws;
    {  // L1: coords -> h1 (s_simb)
      union { u16x8 v; unsigned u[4]; } cv;
      cv.u[0] = (kg == 0) ? pack2(s_coords[ln16 * 3 + 0], s_coords[ln16 * 3 + 1]) : 0u;
      cv.u[1] = (kg == 0) ? pack2(s_coords[ln16 * 3 + 2], 1.0f) : 0u;
      cv.u[2] = 0u; cv.u[3] = 0u;
      const u16x8 af = cv.v;
      const u16x8 w0 = *(const u16x8*)&wsa[WF1 + (0 * 16 + ln16) * 32 + k0];
      const u16x8 w1 = *(const u16x8*)&wsa[WF1 + (1 * 16 + ln16) * 32 + k0];
      f32x4 A0 = {0.f,0.f,0.f,0.f}, A1 = {0.f,0.f,0.f,0.f};
      MFMA(A0, af, w0); MFMA(A1, af, w1);
      MFMA_FENCE2(A0, A1);
#pragma unroll
      for (int r2 = 0; r2 < 4; ++r2) {
        const int row = (kg * 4 + r2) * BSTR;
        s_simb[row + 0 * 16 + ln16] = f2b(fmaxf(A0[r2], 0.f));
        s_simb[row + 1 * 16 + ln16] = f2b(fmaxf(A1[r2], 0.f));
      }
    }
    {  // L2: h1 -> h2 (s_hvb)
      const u16x8 af = *(const u16x8*)&s_simb[ln16 * BSTR + k0];
      const u16x8 w0 = *(const u16x8*)&wsa[WF2 + (0 * 16 + ln16) * 32 + k0];
      const u16x8 w1 = *(const u16x8*)&wsa[WF2 + (1 * 16 + ln16) * 32 + k0];
      const float b0 = p.fb2[0 * 16 + ln16], b1 = p.fb2[1 * 16 + ln16];
      f32x4 A0 = {b0,b0,b0,b0}, A1 = {b1,b1,b1,b1};
      MFMA(A0, af, w0); MFMA(A1, af, w1);
      MFMA_FENCE2(A0, A1);
#pragma unroll
      for (int r2 = 0; r2 < 4; ++r2) {
        const int row = (kg * 4 + r2) * HSTR;
        s_hvb[row + 0 * 16 + ln16] = f2b(fmaxf(A0[r2], 0.f));
        s_hvb[row + 1 * 16 + ln16] = f2b(fmaxf(A1[r2], 0.f));
      }
    }
    {  // L3: h2 -> feats (s_featb, no relu)
      const u16x8 af = *(const u16x8*)&s_hvb[ln16 * HSTR + k0];
      const u16x8 w0 = *(const u16x8*)&wsa[WF3 + (0 * 16 + ln16) * 32 + k0];
      const u16x8 w1 = *(const u16x8*)&wsa[WF3 + (1 * 16 + ln16) * 32 + k0];
      const float b0 = p.fb3[0 * 16 + ln16], b1 = p.fb3[1 * 16 + ln16];
      f32x4 A0 = {b0,b0,b0,b0}, A1 = {b1,b1,b1,b1};
      MFMA(A0, af, w0); MFMA(A1, af, w1);
      MFMA_FENCE2(A0, A1);
#pragma unroll
      for (int r2 = 0; r2 < 4; ++r2) {
        const int row = (kg * 4 + r2) * BSTR;
        s_featb[row + 0 * 16 + ln16] = f2b(A0[r2]);
        s_featb[row + 1 * 16 + ln16] = f2b(A1[r2]);
      }
    }
    {  // Phase B: qkv = feats @ qkv_w (6 n-tiles, batched)
      const u16x8 af = *(const u16x8*)&s_featb[ln16 * BSTR + k0];
#pragma unroll
      for (int g6 = 0; g6 < 2; ++g6) {
        const int nb0 = g6 * 3;
        const u16x8 w0 = *(const u16x8*)&wsa[WQKV + ((nb0 + 0) * 16 + ln16) * 32 + k0];
        const u16x8 w1 = *(const u16x8*)&wsa[WQKV + ((nb0 + 1) * 16 + ln16) * 32 + k0];
        const u16x8 w2 = *(const u16x8*)&wsa[WQKV + ((nb0 + 2) * 16 + ln16) * 32 + k0];
        f32x4 A0 = {0.f,0.f,0.f,0.f}, A1 = {0.f,0.f,0.f,0.f}, A2 = {0.f,0.f,0.f,0.f};
        MFMA(A0, af, w0); MFMA(A1, af, w1); MFMA(A2, af, w2);
        asm volatile("s_nop 7\n\ts_nop 7" : "+v"(A0), "+v"(A1), "+v"(A2));
#pragma unroll
        for (int j6 = 0; j6 < 3; ++j6) {
          const int o = (nb0 + j6) * 16 + ln16;
          const f32x4 acc = (j6 == 0) ? A0 : (j6 == 1) ? A1 : A2;
#pragma unroll
          for (int r2 = 0; r2 < 4; ++r2) {
            const int row = kg * 4 + r2;
            if (o < 32) s_u[row * 32 + o] = acc[r2];
            else if (o < 64) s_u[512 + row * 32 + o - 32] = acc[r2];
            else s_v[row * 32 + o - 64] = acc[r2];
          }
        }
      }
    }
  }

  // ---- Phase C: one i-row at a time, all within the wave ----
  {
    const float* b2c = p.ptp_b2;
    const float* bh1 = p.pta_b1;
    const float* bh2 = p.pta_b2;
    const unsigned short* wsc = ws;
    for (int i = 0; i < 16; ++i) {
      asm volatile("" : "+s"(b2c), "+s"(bh1), "+s"(bh2), "+s"(wsc));
      const float c0 = s_coords[i * 3 + 0] - s_coords[ln16 * 3 + 0];
      const float c1 = s_coords[i * 3 + 1] - s_coords[ln16 * 3 + 1];
      const float c2 = s_coords[i * 3 + 2] - s_coords[ln16 * 3 + 2];
      {  // hv[16][128] via MFMA, batched loads, 4 accs + 1 fence per group
        union { u16x8 v; unsigned u[4]; } cv;
        cv.u[0] = (kg == 0) ? pack2(c0, c1) : 0u;
        cv.u[1] = (kg == 0) ? pack2(c2, 1.0f) : 0u;
        cv.u[2] = 0u; cv.u[3] = 0u;
        const u16x8 afh = cv.v;
#pragma unroll
        for (int g2b = 0; g2b < 2; ++g2b) {
          const int nbase = g2b * 4;
          const u16x8 w0 = *(const u16x8*)&wsc[WH_PTP + ((nbase + 0) * 16 + ln16) * 32 + k0];
          const u16x8 w1 = *(const u16x8*)&wsc[WH_PTP + ((nbase + 1) * 16 + ln16) * 32 + k0];
          const u16x8 w2 = *(const u16x8*)&wsc[WH_PTP + ((nbase + 2) * 16 + ln16) * 32 + k0];
          const u16x8 w3 = *(const u16x8*)&wsc[WH_PTP + ((nbase + 3) * 16 + ln16) * 32 + k0];
          f32x4 A0 = {0.f,0.f,0.f,0.f}, A1 = {0.f,0.f,0.f,0.f};
          f32x4 A2 = {0.f,0.f,0.f,0.f}, A3 = {0.f,0.f,0.f,0.f};
          MFMA(A0, afh, w0); MFMA(A1, afh, w1); MFMA(A2, afh, w2); MFMA(A3, afh, w3);
          MFMA_FENCE4(A0, A1, A2, A3);
#pragma unroll
          for (int r2 = 0; r2 < 4; ++r2) {
            const int row = (kg * 4 + r2) * HSTR;
            s_hvb[row + (nbase + 0) * 16 + ln16] = f2b(fmaxf(A0[r2], 0.f));
            s_hvb[row + (nbase + 1) * 16 + ln16] = f2b(fmaxf(A1[r2], 0.f));
            s_hvb[row + (nbase + 2) * 16 + ln16] = f2b(fmaxf(A2[r2], 0.f));
            s_hvb[row + (nbase + 3) * 16 + ln16] = f2b(fmaxf(A3[r2], 0.f));
          }
        }
      }
      f32x4 rpe0, rpe1;
      {  // G1: hoisted A-fragments + batched B-loads, chained MFMA
        const u16x8 a0 = *(const u16x8*)&s_hvb[ln16 * HSTR + 0 * 32 + k0];
        const u16x8 a1 = *(const u16x8*)&s_hvb[ln16 * HSTR + 1 * 32 + k0];
        const u16x8 a2f = *(const u16x8*)&s_hvb[ln16 * HSTR + 2 * 32 + k0];
        const u16x8 a3f = *(const u16x8*)&s_hvb[ln16 * HSTR + 3 * 32 + k0];
#pragma unroll
        for (int nb = 0; nb < 2; ++nb) {
          const int n = nb * 16 + ln16;
          const u16x8 w0 = *(const u16x8*)&wsc[WA_PTP + n * 128 + 0 * 32 + k0];
          const u16x8 w1 = *(const u16x8*)&wsc[WA_PTP + n * 128 + 1 * 32 + k0];
          const u16x8 w2 = *(const u16x8*)&wsc[WA_PTP + n * 128 + 2 * 32 + k0];
          const u16x8 w3 = *(const u16x8*)&wsc[WA_PTP + n * 128 + 3 * 32 + k0];
          const float bias = b2c[n];
          f32x4 acc = {bias, bias, bias, bias};
          MFMA(acc, a0, w0); MFMA(acc, a1, w1); MFMA(acc, a2f, w2); MFMA(acc, a3f, w3);
          MFMA_FENCE(acc);
          if (nb == 0) rpe0 = acc; else rpe1 = acc;
#pragma unroll
          for (int r2 = 0; r2 < 4; ++r2) {
            const int j = kg * 4 + r2;
            s_simb[j * BSTR + n] = f2b(s_u[i * 32 + n] - s_u[512 + j * 32 + n] + acc[r2]);
          }
        }
      }
      {  // G2: batched loads, 4 accs + 1 fence per group
        const u16x8 as = *(const u16x8*)&s_simb[ln16 * BSTR + k0];
#pragma unroll
        for (int g2b = 0; g2b < 2; ++g2b) {
          const int nbase = g2b * 4;
          const u16x8 w0 = *(const u16x8*)&wsc[WB_PTA + ((nbase + 0) * 16 + ln16) * 32 + k0];
          const u16x8 w1 = *(const u16x8*)&wsc[WB_PTA + ((nbase + 1) * 16 + ln16) * 32 + k0];
          const u16x8 w2 = *(const u16x8*)&wsc[WB_PTA + ((nbase + 2) * 16 + ln16) * 32 + k0];
          const u16x8 w3 = *(const u16x8*)&wsc[WB_PTA + ((nbase + 3) * 16 + ln16) * 32 + k0];
          const float b0 = bh1[(nbase + 0) * 16 + ln16];
          const float b1v = bh1[(nbase + 1) * 16 + ln16];
          const float b2v = bh1[(nbase + 2) * 16 + ln16];
          const float b3 = bh1[(nbase + 3) * 16 + ln16];
          f32x4 A0 = {b0,b0,b0,b0}, A1 = {b1v,b1v,b1v,b1v};
          f32x4 A2 = {b2v,b2v,b2v,b2v}, A3 = {b3,b3,b3,b3};
          MFMA(A0, as, w0); MFMA(A1, as, w1); MFMA(A2, as, w2); MFMA(A3, as, w3);
          MFMA_FENCE4(A0, A1, A2, A3);
#pragma unroll
          for (int r2 = 0; r2 < 4; ++r2) {
            const int row = (kg * 4 + r2) * HSTR;
            s_hidb[row + (nbase + 0) * 16 + ln16] = f2b(fmaxf(A0[r2], 0.f));
            s_hidb[row + (nbase + 1) * 16 + ln16] = f2b(fmaxf(A1[r2], 0.f));
            s_hidb[row + (nbase + 2) * 16 + ln16] = f2b(fmaxf(A2[r2], 0.f));
            s_hidb[row + (nbase + 3) * 16 + ln16] = f2b(fmaxf(A3[r2], 0.f));
          }
        }
      }
      {  // G3 + fused softmax: hoisted A-fragments + batched B-loads
        const u16x8 h0 = *(const u16x8*)&s_hidb[ln16 * HSTR + 0 * 32 + k0];
        const u16x8 h1 = *(const u16x8*)&s_hidb[ln16 * HSTR + 1 * 32 + k0];
        const u16x8 h2 = *(const u16x8*)&s_hidb[ln16 * HSTR + 2 * 32 + k0];
        const u16x8 h3 = *(const u16x8*)&s_hidb[ln16 * HSTR + 3 * 32 + k0];
#pragma unroll
        for (int nb = 0; nb < 2; ++nb) {
          const int n = nb * 16 + ln16;
          const u16x8 w0 = *(const u16x8*)&wsc[WC_PTA + n * 128 + 0 * 32 + k0];
          const u16x8 w1 = *(const u16x8*)&wsc[WC_PTA + n * 128 + 1 * 32 + k0];
          const u16x8 w2 = *(const u16x8*)&wsc[WC_PTA + n * 128 + 2 * 32 + k0];
          const u16x8 w3 = *(const u16x8*)&wsc[WC_PTA + n * 128 + 3 * 32 + k0];
          const float bias = bh2[n];
          f32x4 acc = {bias, bias, bias, bias};
          MFMA(acc, h0, w0); MFMA(acc, h1, w1); MFMA(acc, h2, w2); MFMA(acc, h3, w3);
          MFMA_FENCE(acc);
          const f32x4 rp = nb ? rpe1 : rpe0;
          float mx = fmaxf(fmaxf(acc[0], acc[1]), fmaxf(acc[2], acc[3]));
          mx = fmaxf(mx, __shfl_xor(mx, 16));
          mx = fmaxf(mx, __shfl_xor(mx, 32));
          float sum = 0.f, o = 0.f;
#pragma unroll
          for (int r2 = 0; r2 < 4; ++r2) {
            const int j = kg * 4 + r2;
            const float e = __expf(acc[r2] - mx);
            sum += e;
            o = fmaf(e, s_v[j * 32 + n] + rp[r2], o);
          }
          sum += __shfl_xor(sum, 16); o += __shfl_xor(o, 16);
          sum += __shfl_xor(sum, 32); o += __shfl_xor(o, 32);
          if (kg == 0) s_featb[i * BSTR + n] = f2b(o / sum);
        }
      }
    }
  }

  // ---- kk / vvb via MFMA (A = s_featb) -> s_u ----
  {
    const u16x8 af = *(const u16x8*)&s_featb[ln16 * BSTR + k0];
    const u16x8 wk0 = *(const u16x8*)&ws[WKK + (0 * 16 + ln16) * 32 + k0];
    const u16x8 wk1 = *(const u16x8*)&ws[WKK + (1 * 16 + ln16) * 32 + k0];
    const u16x8 wv0 = *(const u16x8*)&ws[WVV + (0 * 16 + ln16) * 32 + k0];
    const u16x8 wv1 = *(const u16x8*)&ws[WVV + (1 * 16 + ln16) * 32 + k0];
    const float bk0 = p.cak_b[ln16], bk1 = p.cak_b[16 + ln16];
    const float bv0 = p.cav_b[ln16], bv1 = p.cav_b[16 + ln16];
    f32x4 K0 = {bk0,bk0,bk0,bk0}, K1 = {bk1,bk1,bk1,bk1};
    f32x4 V0 = {bv0,bv0,bv0,bv0}, V1 = {bv1,bv1,bv1,bv1};
    MFMA(K0, af, wk0); MFMA(K1, af, wk1); MFMA(V0, af, wv0); MFMA(V1, af, wv1);
    MFMA_FENCE4(K0, K1, V0, V1);
#pragma unroll
    for (int r2 = 0; r2 < 4; ++r2) {
      const int row = kg * 4 + r2;
      s_u[row * 32 + ln16] = K0[r2];
      s_u[row * 32 + 16 + ln16] = K1[r2];
      s_u[512 + row * 32 + ln16] = V0[r2];
      s_u[512 + row * 32 + 16 + ln16] = V1[r2];
    }
  }

  // ---- Phase D: 8 march steps + epilogue, all within the wave ----
  {
    const float* b2d = p.cap_b2;
    const float* bc1 = p.caa_b1;
    const float* bc2 = p.caa_b2;
    const float* fw1 = p.fw1; const float* fw2 = p.fw2; const float* fw3 = p.fw3;
    const float* cqw = p.caq_w;
    const float* iw1 = p.im_w1; const float* iw2 = p.im_w2; const float* iw3 = p.im_w3;
    const unsigned short* wsd = ws;
    for (int s = 0; s <= 8; ++s) {
      asm volatile("" : "+s"(b2d), "+s"(bc1), "+s"(bc2), "+s"(wsd));
      asm volatile("" : "+s"(fw1), "+s"(fw2), "+s"(fw3), "+s"(cqw), "+s"(iw1), "+s"(iw2), "+s"(iw3));
      float rv0 = 0.f, rv1 = 0.f, rv2 = 0.f;
      if (s < 8 && l < 16) {  // rel + o_ld
        const float r0 = s_coords[l * 3 + 0] - s_op[0];
        const float r1 = s_coords[l * 3 + 1] - s_op[1];
        const float r2 = s_coords[l * 3 + 2] - s_op[2];
        const float rd = sqrtf(r0 * r0 + r1 * r1 + r2 * r2);
        const float inv = 1.f / rd;
        rv0 = r0 * inv; rv1 = r1 * inv; rv2 = r2 * inv;
        s_reld[l] = rd;
        s_relv[l * 3 + 0] = rv0; s_relv[l * 3 + 1] = rv1; s_relv[l * 3 + 2] = rv2;
        p.o_ld[b * 128 + s * 16 + l] = rd;
      }
      {  // secA: hv via MFMA, batched
        float c0, c1, c2;
        if (s < 8) {
          c0 = s_coords[ln16 * 3 + 0] - s_op[0];
          c1 = s_coords[ln16 * 3 + 1] - s_op[1];
          c2 = s_coords[ln16 * 3 + 2] - s_op[2];
        } else {
          const float rd = s_reld[ln16];
          c0 = s_relv[ln16 * 3 + 0] * rd; c1 = s_relv[ln16 * 3 + 1] * rd; c2 = s_relv[ln16 * 3 + 2] * rd;
        }
        union { u16x8 v; unsigned u[4]; } cv;
        cv.u[0] = (kg == 0) ? pack2(c0, c1) : 0u;
        cv.u[1] = (kg == 0) ? pack2(c2, 1.0f) : 0u;
        cv.u[2] = 0u; cv.u[3] = 0u;
        const u16x8 afh = cv.v;
#pragma unroll
        for (int g2b = 0; g2b < 2; ++g2b) {
          const int nbase = g2b * 4;
          const u16x8 w0 = *(const u16x8*)&wsd[WH_CAP + ((nbase + 0) * 16 + ln16) * 32 + k0];
          const u16x8 w1 = *(const u16x8*)&wsd[WH_CAP + ((nbase + 1) * 16 + ln16) * 32 + k0];
          const u16x8 w2 = *(const u16x8*)&wsd[WH_CAP + ((nbase + 2) * 16 + ln16) * 32 + k0];
          const u16x8 w3 = *(const u16x8*)&wsd[WH_CAP + ((nbase + 3) * 16 + ln16) * 32 + k0];
          f32x4 A0 = {0.f,0.f,0.f,0.f}, A1 = {0.f,0.f,0.f,0.f};
          f32x4 A2 = {0.f,0.f,0.f,0.f}, A3 = {0.f,0.f,0.f,0.f};
          MFMA(A0, afh, w0); MFMA(A1, afh, w1); MFMA(A2, afh, w2); MFMA(A3, afh, w3);
          MFMA_FENCE4(A0, A1, A2, A3);
#pragma unroll
          for (int r2 = 0; r2 < 4; ++r2) {
            const int row = (kg * 4 + r2) * HSTR;
            s_hvb[row + (nbase + 0) * 16 + ln16] = f2b(fmaxf(A0[r2], 0.f));
            s_hvb[row + (nbase + 1) * 16 + ln16] = f2b(fmaxf(A1[r2], 0.f));
            s_hvb[row + (nbase + 2) * 16 + ln16] = f2b(fmaxf(A2[r2], 0.f));
            s_hvb[row + (nbase + 3) * 16 + ln16] = f2b(fmaxf(A3[r2], 0.f));
          }
        }
      }
      {  // qq chain (all lanes, width-32 shuffles; halves duplicate)
        const int h = l & 31;
        float opc0, opc1, opc2;
        if (s < 8) {
          const float cum = s_cum;
          opc0 = s_qry[0] * cum; opc1 = s_qry[1] * cum; opc2 = s_qry[2] * cum;
        } else {
          opc0 = s_op[0]; opc1 = s_op[1]; opc2 = s_op[2];
        }
        float v1 = fmaxf(fmaf(opc0, fw1[h],
                      fmaf(opc1, fw1[32 + h],
                      fmaf(opc2, fw1[64 + h], p.fb1[h]))), 0.f);
        float a = p.fb2[h];
        for (int i2 = 0; i2 < 32; ++i2) a = fmaf(__shfl(v1, i2, 32), fw2[i2 * 32 + h], a);
        const float v2 = fmaxf(a, 0.f);
        a = p.fb3[h];
        for (int i2 = 0; i2 < 32; ++i2) a = fmaf(__shfl(v2, i2, 32), fw3[i2 * 32 + h], a);
        const float opf = a;
        a = p.caq_b[h];
        for (int i2 = 0; i2 < 32; ++i2) a = fmaf(__shfl(opf, i2, 32), cqw[i2 * 32 + h], a);
        if (l < 32) s_qq[h] = a;
      }
      f32x4 pe0, pe1;
      {  // secB: hoisted A-fragments + batched B-loads
        const u16x8 a0 = *(const u16x8*)&s_hvb[ln16 * HSTR + 0 * 32 + k0];
        const u16x8 a1 = *(const u16x8*)&s_hvb[ln16 * HSTR + 1 * 32 + k0];
        const u16x8 a2f = *(const u16x8*)&s_hvb[ln16 * HSTR + 2 * 32 + k0];
        const u16x8 a3f = *(const u16x8*)&s_hvb[ln16 * HSTR + 3 * 32 + k0];
#pragma unroll
        for (int nb = 0; nb < 2; ++nb) {
          const int n = nb * 16 + ln16;
          const u16x8 w0 = *(const u16x8*)&wsd[WA_CAP + n * 128 + 0 * 32 + k0];
          const u16x8 w1 = *(const u16x8*)&wsd[WA_CAP + n * 128 + 1 * 32 + k0];
          const u16x8 w2 = *(const u16x8*)&wsd[WA_CAP + n * 128 + 2 * 32 + k0];
          const u16x8 w3 = *(const u16x8*)&wsd[WA_CAP + n * 128 + 3 * 32 + k0];
          const float bias = b2d[n];
          f32x4 acc = {bias, bias, bias, bias};
          MFMA(acc, a0, w0); MFMA(acc, a1, w1); MFMA(acc, a2f, w2); MFMA(acc, a3f, w3);
          MFMA_FENCE(acc);
          if (nb == 0) pe0 = acc; else pe1 = acc;
#pragma unroll
          for (int r2 = 0; r2 < 4; ++r2) {
            const int row = kg * 4 + r2;
            s_simb[row * BSTR + n] = f2b(s_qq[n] - s_u[row * 32 + n] + acc[r2]);
          }
        }
      }
      {  // secC: batched loads, 4 accs + 1 fence per group
        const u16x8 as = *(const u16x8*)&s_simb[ln16 * BSTR + k0];
#pragma unroll
        for (int g2b = 0; g2b < 2; ++g2b) {
          const int nbase = g2b * 4;
          const u16x8 w0 = *(const u16x8*)&wsd[WB_CAA + ((nbase + 0) * 16 + ln16) * 32 + k0];
          const u16x8 w1 = *(const u16x8*)&wsd[WB_CAA + ((nbase + 1) * 16 + ln16) * 32 + k0];
          const u16x8 w2 = *(const u16x8*)&wsd[WB_CAA + ((nbase + 2) * 16 + ln16) * 32 + k0];
          const u16x8 w3 = *(const u16x8*)&wsd[WB_CAA + ((nbase + 3) * 16 + ln16) * 32 + k0];
          const float b0 = bc1[(nbase + 0) * 16 + ln16];
          const float b1v = bc1[(nbase + 1) * 16 + ln16];
          const float b2v = bc1[(nbase + 2) * 16 + ln16];
          const float b3 = bc1[(nbase + 3) * 16 + ln16];
          f32x4 A0 = {b0,b0,b0,b0}, A1 = {b1v,b1v,b1v,b1v};
          f32x4 A2 = {b2v,b2v,b2v,b2v}, A3 = {b3,b3,b3,b3};
          MFMA(A0, as, w0); MFMA(A1, as, w1); MFMA(A2, as, w2); MFMA(A3, as, w3);
          MFMA_FENCE4(A0, A1, A2, A3);
#pragma unroll
          for (int r2 = 0; r2 < 4; ++r2) {
            const int row = (kg * 4 + r2) * HSTR;
            s_hidb[row + (nbase + 0) * 16 + ln16] = f2b(fmaxf(A0[r2], 0.f));
            s_hidb[row + (nbase + 1) * 16 + ln16] = f2b(fmaxf(A1[r2], 0.f));
            s_hidb[row + (nbase + 2) * 16 + ln16] = f2b(fmaxf(A2[r2], 0.f));
            s_hidb[row + (nbase + 3) * 16 + ln16] = f2b(fmaxf(A3[r2], 0.f));
          }
        }
      }
      // secD + in-register softmax -> ca0/ca1 (hoisted A + batched B)
      float ca0 = 0.f, ca1 = 0.f;
      {
        const u16x8 h0 = *(const u16x8*)&s_hidb[ln16 * HSTR + 0 * 32 + k0];
        const u16x8 h1 = *(const u16x8*)&s_hidb[ln16 * HSTR + 1 * 32 + k0];
        const u16x8 h2 = *(const u16x8*)&s_hidb[ln16 * HSTR + 2 * 32 + k0];
        const u16x8 h3 = *(const u16x8*)&s_hidb[ln16 * HSTR + 3 * 32 + k0];
#pragma unroll
        for (int nb = 0; nb < 2; ++nb) {
          const int n = nb * 16 + ln16;
          const u16x8 w0 = *(const u16x8*)&wsd[WC_CAA + n * 128 + 0 * 32 + k0];
          const u16x8 w1 = *(const u16x8*)&wsd[WC_CAA + n * 128 + 1 * 32 + k0];
          const u16x8 w2 = *(const u16x8*)&wsd[WC_CAA + n * 128 + 2 * 32 + k0];
          const u16x8 w3 = *(const u16x8*)&wsd[WC_CAA + n * 128 + 3 * 32 + k0];
          const float bias = bc2[n];
          f32x4 acc = {bias, bias, bias, bias};
          MFMA(acc, h0, w0); MFMA(acc, h1, w1); MFMA(acc, h2, w2); MFMA(acc, h3, w3);
          MFMA_FENCE(acc);
          const f32x4 rp = nb ? pe1 : pe0;
          float mx = fmaxf(fmaxf(acc[0], acc[1]), fmaxf(acc[2], acc[3]));
          mx = fmaxf(mx, __shfl_xor(mx, 16));
          mx = fmaxf(mx, __shfl_xor(mx, 32));
          float sum = 0.f, o = 0.f;
#pragma unroll
          for (int r2 = 0; r2 < 4; ++r2) {
            const int row = kg * 4 + r2;
            const float e = __expf(acc[r2] - mx);
            sum += e;
            o = fmaf(e, s_u[512 + row * 32 + n] + rp[r2], o);
          }
          sum += __shfl_xor(sum, 16); o += __shfl_xor(o, 16);
          sum += __shfl_xor(sum, 32); o += __shfl_xor(o, 32);
          if (nb == 0) ca0 = o / sum; else ca1 = o / sum;
        }
      }
      if (kg == 0) { s_ca[ln16] = ca0; s_ca[16 + ln16] = ca1; }
      {  // im / ep chain (width-32; halves duplicate; writes guarded)
        const int h = l & 31;
        const float cav = s_ca[h];
        if (s < 8) {
          float a = p.im_b1[h];
          for (int i2 = 0; i2 < 32; ++i2) a = fmaf(__shfl(cav, i2, 32), iw1[i2 * 32 + h], a);
          const float m1 = fmaxf(a, 0.f);
          a = p.im_b2[h];
          for (int i2 = 0; i2 < 32; ++i2) a = fmaf(__shfl(m1, i2, 32), iw2[i2 * 32 + h], a);
          const float m2 = fmaxf(a, 0.f);
          float p0 = m2 * iw3[h * 3 + 0];
          float p1 = m2 * iw3[h * 3 + 1];
          float p2 = m2 * iw3[h * 3 + 2];
#pragma unroll
          for (int m = 1; m < 32; m <<= 1) {
            p0 += __shfl_xor(p0, m, 32);
            p1 += __shfl_xor(p1, m, 32);
            p2 += __shfl_xor(p2, m, 32);
          }
          p0 += p.im_b3[0]; p1 += p.im_b3[1]; p2 += p.im_b3[2];
          const float step = sqrtf(p0 * p0 + p1 * p1 + p2 * p2);
          const float cum = s_cum;
          const float opc0 = s_qry[0] * cum, opc1 = s_qry[1] * cum, opc2 = s_qry[2] * cum;
          const float inv = 1.f / step;
          const float tg0 = p0 * inv, tg1 = p1 * inv, tg2 = p2 * inv;
          if (l == 0) {
            p.o_ms[b * 8 + s] = step;
            p.o_ip[(b * 8 + s) * 3 + 0] = opc0 + p0;
            s_op[0] = opc0 + s_qry[0] * step;
          } else if (l == 1) {
            p.o_ip[(b * 8 + s) * 3 + 1] = opc1 + p1;
            s_op[1] = opc1 + s_qry[1] * step;
          } else if (l == 2) {
            p.o_ip[(b * 8 + s) * 3 + 2] = opc2 + p2;
            s_op[2] = opc2 + s_qry[2] * step;
          } else if (l == 3) {
            s_cum = cum + step;
          }
          if (l < 16) {
            p.o_cs[b * 128 + s * 16 + l] = tg0 * rv0 + tg1 * rv1 + tg2 * rv2;
          }
        } else {
          float a = p.ep_b1[h];
          for (int i2 = 0; i2 < 32; ++i2) a = fmaf(__shfl(cav, i2, 32), p.ep_w1[i2 * 32 + h], a);
          a = fmaf(s_qry[0], p.ep_w1[1024 + h], a);
          a = fmaf(s_qry[1], p.ep_w1[1056 + h], a);
          a = fmaf(s_qry[2], p.ep_w1[1088 + h], a);
          const float e1 = fmaxf(a, 0.f);
          a = p.ep_b2[h];
          for (int i2 = 0; i2 < 32; ++i2) a = fmaf(__shfl(e1, i2, 32), p.ep_w2[i2 * 32 + h], a);
          const float e2 = fmaxf(a, 0.f);
          float pp = e2 * p.ep_w3[h];
#pragma unroll
          for (int m = 1; m < 32; m <<= 1) pp += __shfl_xor(pp, m, 32);
          if (l == 0) {
            p.o_eps[b] = pp + p.ep_b3[0];
            p.o_cum[b] = s_cum;
          }
        }
      }
    }
  }
}

extern "C" void kernel_launch(void* const* d_in, const int* in_sizes, int n_in,
                              void* d_out, int out_size, void* d_ws, size_t ws_size,
                              hipStream_t stream) {
  Params p;
  const float** f = (const float**)(void*)&p;
  for (int i = 0; i < 43; ++i) f[i] = (const float*)d_in[i];
  float* out = (float*)d_out;
  p.o_ld  = out;
  p.o_ms  = out + OFF_MS;
  p.o_cs  = out + OFF_CS;
  p.o_ip  = out + OFF_IP;
  p.o_cum = out + OFF_CUM;
  p.o_eps = out + OFF_EPS;
  unsigned short* ws = (unsigned short*)d_ws;
  prep_kernel<<<dim3(16), dim3(256), 0, stream>>>(p, ws);
  puray_kernel<<<dim3(4096), dim3(64), 0, stream>>>(p, ws);
}

// Round 23
// 303.612 us; speedup vs baseline: 3.1777x; 1.2065x over previous
//
#include <hip/hip_runtime.h>

// Problem constants: B=4096, K=16, H=32, HM=128, STEPS=8
#define OFF_MS  524288
#define OFF_CS  557056
#define OFF_IP  1081344
#define OFF_CUM 1179648
#define OFF_EPS 1183744

#define HSTR 136   // padded bf16 row stride (272B -> 2-way banks)
#define BSTR 40    // padded bf16 row stride (80B)

// d_ws layout (u16): bf16 weights transposed to [n][k]
#define WA_PTP 0        // ptp_w2T [32][128]
#define WB_PTA 4096     // pta_w1T [128][32]
#define WC_PTA 8192     // pta_w2T [32][128]
#define WA_CAP 12288    // cap_w2T [32][128]
#define WB_CAA 16384    // caa_w1T [128][32]
#define WC_CAA 20480    // caa_w2T [32][128]
#define WH_PTP 24576    // ptp_w1T [128 n][32 k] (k<3 w1, k==3 bias, else 0)
#define WH_CAP 28672    // cap_w1T [128 n][32 k]
#define WF1    32768    // fw1T [32 n][32 k] (k<3 w1, k==3 fb1, else 0)
#define WF2    33792    // fw2T [32 n][32 k]
#define WF3    34816    // fw3T [32 n][32 k]
#define WQKV   35840    // qkv_wT [96 n][32 k]
#define WKK    38912    // cak_wT [32 n][32 k]
#define WVV    39936    // cav_wT [32 n][32 k]

struct Params {
  const float *knn, *query, *fw1, *fb1, *fw2, *fb2, *fw3, *fb3, *qkv_w,
    *ptp_w1, *ptp_b1, *ptp_w2, *ptp_b2, *pta_w1, *pta_b1, *pta_w2, *pta_b2,
    *caq_w, *caq_b, *cak_w, *cak_b, *cav_w, *cav_b,
    *cap_w1, *cap_b1, *cap_w2, *cap_b2, *caa_w1, *caa_b1, *caa_w2, *caa_b2,
    *im_w1, *im_b1, *im_w2, *im_b2, *im_w3, *im_b3,
    *ep_w1, *ep_b1, *ep_w2, *ep_b2, *ep_w3, *ep_b3;
  float *o_ld, *o_ms, *o_cs, *o_ip, *o_cum, *o_eps;
};
static_assert(sizeof(Params) == 49 * sizeof(void*), "Params layout");

typedef float f32x4 __attribute__((ext_vector_type(4)));
typedef unsigned short u16x8 __attribute__((ext_vector_type(8)));

__device__ __forceinline__ unsigned short f2b(float x) {  // fp32->bf16 RNE
  unsigned u = __float_as_uint(x);
  u += 0x7fffu + ((u >> 16) & 1u);
  return (unsigned short)(u >> 16);
}
__device__ __forceinline__ unsigned pack2(float lo, float hi) {
  return (unsigned)f2b(lo) | ((unsigned)f2b(hi) << 16);
}

#define MFMA(acc, a, bb) \
  asm volatile("s_nop 2\n\tv_mfma_f32_16x16x32_bf16 %0, %1, %2, %0" \
               : "+v"(acc) : "v"(a), "v"(bb))
#define MFMA_FENCE(acc) asm volatile("s_nop 7\n\ts_nop 7" : "+v"(acc))
#define MFMA_FENCE2(a0, a1) \
  asm volatile("s_nop 7\n\ts_nop 7" : "+v"(a0), "+v"(a1))
#define MFMA_FENCE4(a0, a1, a2, a3) \
  asm volatile("s_nop 7\n\ts_nop 7" : "+v"(a0), "+v"(a1), "+v"(a2), "+v"(a3))

// Prep: transpose+convert all 14 MFMA weight tables into d_ws (once/launch).
__global__ void prep_kernel(Params p, unsigned short* ws) {
  const int t = blockIdx.x * 256 + threadIdx.x;  // 0..4095
  const int n = t >> 7, k = t & 127;
  ws[WA_PTP + t] = f2b(p.ptp_w2[k * 32 + n]);
  ws[WC_PTA + t] = f2b(p.pta_w2[k * 32 + n]);
  ws[WA_CAP + t] = f2b(p.cap_w2[k * 32 + n]);
  ws[WC_CAA + t] = f2b(p.caa_w2[k * 32 + n]);
  const int n2 = t >> 5, k2 = t & 31;
  ws[WB_PTA + t] = f2b(p.pta_w1[k2 * 128 + n2]);
  ws[WB_CAA + t] = f2b(p.caa_w1[k2 * 128 + n2]);
  ws[WH_PTP + t] = (k2 < 3) ? f2b(p.ptp_w1[k2 * 128 + n2])
                  : (k2 == 3 ? f2b(p.ptp_b1[n2]) : (unsigned short)0);
  ws[WH_CAP + t] = (k2 < 3) ? f2b(p.cap_w1[k2 * 128 + n2])
                  : (k2 == 3 ? f2b(p.cap_b1[n2]) : (unsigned short)0);
  if (t < 1024) {
    ws[WF1 + t] = (k2 < 3) ? f2b(p.fw1[k2 * 32 + n2])
                 : (k2 == 3 ? f2b(p.fb1[n2]) : (unsigned short)0);
    ws[WF2 + t] = f2b(p.fw2[k2 * 32 + n2]);
    ws[WF3 + t] = f2b(p.fw3[k2 * 32 + n2]);
    ws[WKK + t] = f2b(p.cak_w[k2 * 32 + n2]);
    ws[WVV + t] = f2b(p.cav_w[k2 * 32 + n2]);
  }
  if (t < 3072) ws[WQKV + t] = f2b(p.qkv_w[k2 * 96 + n2]);
}

// WAVE-PER-BATCH round-22 (366us) + DUAL-I-STREAM phase C: iterations i,i+1
// are independent -> two interleaved streams per section (2x ILP on the
// latency path), B-fragments SHARED between streams (half the loads), outer
// iterations 16->8 (half the section-latency events). workA/workB use the
// round-18-proven hv/hid union (hv dead after G1). LDS 19.4KB (8 blocks/CU).
__launch_bounds__(64, 2)
__global__ void puray_kernel(Params p, const unsigned short* ws) {
  const int b = blockIdx.x;
  const int l = threadIdx.x;
  const int ln16 = l & 15, kg = l >> 4, k0 = kg * 8;

  __shared__ __align__(16) unsigned short s_workA[16 * HSTR]; // hv->hid (i0 / phase D)
  __shared__ __align__(16) unsigned short s_workB[16 * HSTR]; // hv->hid (i1)
  __shared__ __align__(16) unsigned short s_simbA[16 * BSTR];
  __shared__ __align__(16) unsigned short s_simbB[16 * BSTR];
  __shared__ __align__(16) unsigned short s_featb[16 * BSTR]; // bf16 feats
  __shared__ float s_v[512];
  __shared__ float s_u[1024];    // C: q|k ; D: kk|vvb
  __shared__ float s_coords[48], s_relv[48], s_reld[16];
  __shared__ float s_qry[3], s_op[3], s_qq[32], s_ca[32];
  __shared__ float s_cum;

  if (l < 48) s_coords[l] = p.knn[b * 48 + l];
  else if (l < 51) s_qry[l - 48] = p.query[b * 3 + (l - 48)];
  else if (l == 51) s_cum = 0.f;
  else if (l < 55) s_op[l - 52] = 0.f;
  __syncthreads();

  // ---- Phase A (MFMA): L1 (K=3 fold) -> L2 -> L3 -> s_featb ----
  {
    const unsigned short* wsa = ws;
    {  // L1: coords -> h1 (s_simbA)
      union { u16x8 v; unsigned u[4]; } cv;
      cv.u[0] = (kg == 0) ? pack2(s_coords[ln16 * 3 + 0], s_coords[ln16 * 3 + 1]) : 0u;
      cv.u[1] = (kg == 0) ? pack2(s_coords[ln16 * 3 + 2], 1.0f) : 0u;
      cv.u[2] = 0u; cv.u[3] = 0u;
      const u16x8 af = cv.v;
      const u16x8 w0 = *(const u16x8*)&wsa[WF1 + (0 * 16 + ln16) * 32 + k0];
      const u16x8 w1 = *(const u16x8*)&wsa[WF1 + (1 * 16 + ln16) * 32 + k0];
      f32x4 A0 = {0.f,0.f,0.f,0.f}, A1 = {0.f,0.f,0.f,0.f};
      MFMA(A0, af, w0); MFMA(A1, af, w1);
      MFMA_FENCE2(A0, A1);
#pragma unroll
      for (int r2 = 0; r2 < 4; ++r2) {
        const int row = (kg * 4 + r2) * BSTR;
        s_simbA[row + 0 * 16 + ln16] = f2b(fmaxf(A0[r2], 0.f));
        s_simbA[row + 1 * 16 + ln16] = f2b(fmaxf(A1[r2], 0.f));
      }
    }
    {  // L2: h1 -> h2 (s_workA)
      const u16x8 af = *(const u16x8*)&s_simbA[ln16 * BSTR + k0];
      const u16x8 w0 = *(const u16x8*)&wsa[WF2 + (0 * 16 + ln16) * 32 + k0];
      const u16x8 w1 = *(const u16x8*)&wsa[WF2 + (1 * 16 + ln16) * 32 + k0];
      const float b0 = p.fb2[0 * 16 + ln16], b1 = p.fb2[1 * 16 + ln16];
      f32x4 A0 = {b0,b0,b0,b0}, A1 = {b1,b1,b1,b1};
      MFMA(A0, af, w0); MFMA(A1, af, w1);
      MFMA_FENCE2(A0, A1);
#pragma unroll
      for (int r2 = 0; r2 < 4; ++r2) {
        const int row = (kg * 4 + r2) * HSTR;
        s_workA[row + 0 * 16 + ln16] = f2b(fmaxf(A0[r2], 0.f));
        s_workA[row + 1 * 16 + ln16] = f2b(fmaxf(A1[r2], 0.f));
      }
    }
    {  // L3: h2 -> feats (s_featb, no relu)
      const u16x8 af = *(const u16x8*)&s_workA[ln16 * HSTR + k0];
      const u16x8 w0 = *(const u16x8*)&wsa[WF3 + (0 * 16 + ln16) * 32 + k0];
      const u16x8 w1 = *(const u16x8*)&wsa[WF3 + (1 * 16 + ln16) * 32 + k0];
      const float b0 = p.fb3[0 * 16 + ln16], b1 = p.fb3[1 * 16 + ln16];
      f32x4 A0 = {b0,b0,b0,b0}, A1 = {b1,b1,b1,b1};
      MFMA(A0, af, w0); MFMA(A1, af, w1);
      MFMA_FENCE2(A0, A1);
#pragma unroll
      for (int r2 = 0; r2 < 4; ++r2) {
        const int row = (kg * 4 + r2) * BSTR;
        s_featb[row + 0 * 16 + ln16] = f2b(A0[r2]);
        s_featb[row + 1 * 16 + ln16] = f2b(A1[r2]);
      }
    }
    {  // Phase B: qkv = feats @ qkv_w (6 n-tiles, batched)
      const u16x8 af = *(const u16x8*)&s_featb[ln16 * BSTR + k0];
#pragma unroll
      for (int g6 = 0; g6 < 2; ++g6) {
        const int nb0 = g6 * 3;
        const u16x8 w0 = *(const u16x8*)&wsa[WQKV + ((nb0 + 0) * 16 + ln16) * 32 + k0];
        const u16x8 w1 = *(const u16x8*)&wsa[WQKV + ((nb0 + 1) * 16 + ln16) * 32 + k0];
        const u16x8 w2 = *(const u16x8*)&wsa[WQKV + ((nb0 + 2) * 16 + ln16) * 32 + k0];
        f32x4 A0 = {0.f,0.f,0.f,0.f}, A1 = {0.f,0.f,0.f,0.f}, A2 = {0.f,0.f,0.f,0.f};
        MFMA(A0, af, w0); MFMA(A1, af, w1); MFMA(A2, af, w2);
        asm volatile("s_nop 7\n\ts_nop 7" : "+v"(A0), "+v"(A1), "+v"(A2));
#pragma unroll
        for (int j6 = 0; j6 < 3; ++j6) {
          const int o = (nb0 + j6) * 16 + ln16;
          const f32x4 acc = (j6 == 0) ? A0 : (j6 == 1) ? A1 : A2;
#pragma unroll
          for (int r2 = 0; r2 < 4; ++r2) {
            const int row = kg * 4 + r2;
            if (o < 32) s_u[row * 32 + o] = acc[r2];
            else if (o < 64) s_u[512 + row * 32 + o - 32] = acc[r2];
            else s_v[row * 32 + o - 64] = acc[r2];
          }
        }
      }
    }
  }

  // ---- Phase C: DUAL i-stream (i0 = 2*ip, i1 = 2*ip+1) ----
  {
    const float* b2c = p.ptp_b2;
    const float* bh1 = p.pta_b1;
    const float* bh2 = p.pta_b2;
    const unsigned short* wsc = ws;
    for (int ip = 0; ip < 8; ++ip) {
      asm volatile("" : "+s"(b2c), "+s"(bh1), "+s"(bh2), "+s"(wsc));
      const int i0 = ip * 2, i1 = ip * 2 + 1;
      const float c00 = s_coords[i0 * 3 + 0] - s_coords[ln16 * 3 + 0];
      const float c01 = s_coords[i0 * 3 + 1] - s_coords[ln16 * 3 + 1];
      const float c02 = s_coords[i0 * 3 + 2] - s_coords[ln16 * 3 + 2];
      const float c10 = s_coords[i1 * 3 + 0] - s_coords[ln16 * 3 + 0];
      const float c11 = s_coords[i1 * 3 + 1] - s_coords[ln16 * 3 + 1];
      const float c12 = s_coords[i1 * 3 + 2] - s_coords[ln16 * 3 + 2];
      {  // hv dual: shared B, 2x4 accs per group
        union { u16x8 v; unsigned u[4]; } cv0, cv1;
        cv0.u[0] = (kg == 0) ? pack2(c00, c01) : 0u;
        cv0.u[1] = (kg == 0) ? pack2(c02, 1.0f) : 0u;
        cv0.u[2] = 0u; cv0.u[3] = 0u;
        cv1.u[0] = (kg == 0) ? pack2(c10, c11) : 0u;
        cv1.u[1] = (kg == 0) ? pack2(c12, 1.0f) : 0u;
        cv1.u[2] = 0u; cv1.u[3] = 0u;
        const u16x8 af0 = cv0.v, af1 = cv1.v;
#pragma unroll
        for (int g2b = 0; g2b < 2; ++g2b) {
          const int nbase = g2b * 4;
          const u16x8 w0 = *(const u16x8*)&wsc[WH_PTP + ((nbase + 0) * 16 + ln16) * 32 + k0];
          const u16x8 w1 = *(const u16x8*)&wsc[WH_PTP + ((nbase + 1) * 16 + ln16) * 32 + k0];
          const u16x8 w2 = *(const u16x8*)&wsc[WH_PTP + ((nbase + 2) * 16 + ln16) * 32 + k0];
          const u16x8 w3 = *(const u16x8*)&wsc[WH_PTP + ((nbase + 3) * 16 + ln16) * 32 + k0];
          f32x4 A00 = {0.f,0.f,0.f,0.f}, A01 = {0.f,0.f,0.f,0.f};
          f32x4 A02 = {0.f,0.f,0.f,0.f}, A03 = {0.f,0.f,0.f,0.f};
          f32x4 A10 = {0.f,0.f,0.f,0.f}, A11 = {0.f,0.f,0.f,0.f};
          f32x4 A12 = {0.f,0.f,0.f,0.f}, A13 = {0.f,0.f,0.f,0.f};
          MFMA(A00, af0, w0); MFMA(A10, af1, w0);
          MFMA(A01, af0, w1); MFMA(A11, af1, w1);
          MFMA(A02, af0, w2); MFMA(A12, af1, w2);
          MFMA(A03, af0, w3); MFMA(A13, af1, w3);
          MFMA_FENCE4(A00, A01, A02, A03);
          MFMA_FENCE4(A10, A11, A12, A13);
#pragma unroll
          for (int r2 = 0; r2 < 4; ++r2) {
            const int row = (kg * 4 + r2) * HSTR;
            s_workA[row + (nbase + 0) * 16 + ln16] = f2b(fmaxf(A00[r2], 0.f));
            s_workA[row + (nbase + 1) * 16 + ln16] = f2b(fmaxf(A01[r2], 0.f));
            s_workA[row + (nbase + 2) * 16 + ln16] = f2b(fmaxf(A02[r2], 0.f));
            s_workA[row + (nbase + 3) * 16 + ln16] = f2b(fmaxf(A03[r2], 0.f));
            s_workB[row + (nbase + 0) * 16 + ln16] = f2b(fmaxf(A10[r2], 0.f));
            s_workB[row + (nbase + 1) * 16 + ln16] = f2b(fmaxf(A11[r2], 0.f));
            s_workB[row + (nbase + 2) * 16 + ln16] = f2b(fmaxf(A12[r2], 0.f));
            s_workB[row + (nbase + 3) * 16 + ln16] = f2b(fmaxf(A13[r2], 0.f));
          }
        }
      }
      f32x4 rpe00, rpe01, rpe10, rpe11;
      {  // G1 dual: shared B, interleaved chained MFMAs
#pragma unroll
        for (int nb = 0; nb < 2; ++nb) {
          const int n = nb * 16 + ln16;
          const u16x8 w0 = *(const u16x8*)&wsc[WA_PTP + n * 128 + 0 * 32 + k0];
          const u16x8 w1 = *(const u16x8*)&wsc[WA_PTP + n * 128 + 1 * 32 + k0];
          const u16x8 w2 = *(const u16x8*)&wsc[WA_PTP + n * 128 + 2 * 32 + k0];
          const u16x8 w3 = *(const u16x8*)&wsc[WA_PTP + n * 128 + 3 * 32 + k0];
          const u16x8 a00 = *(const u16x8*)&s_workA[ln16 * HSTR + 0 * 32 + k0];
          const u16x8 a01 = *(const u16x8*)&s_workA[ln16 * HSTR + 1 * 32 + k0];
          const u16x8 a02 = *(const u16x8*)&s_workA[ln16 * HSTR + 2 * 32 + k0];
          const u16x8 a03 = *(const u16x8*)&s_workA[ln16 * HSTR + 3 * 32 + k0];
          const u16x8 a10 = *(const u16x8*)&s_workB[ln16 * HSTR + 0 * 32 + k0];
          const u16x8 a11 = *(const u16x8*)&s_workB[ln16 * HSTR + 1 * 32 + k0];
          const u16x8 a12 = *(const u16x8*)&s_workB[ln16 * HSTR + 2 * 32 + k0];
          const u16x8 a13 = *(const u16x8*)&s_workB[ln16 * HSTR + 3 * 32 + k0];
          const float bias = b2c[n];
          f32x4 acc0 = {bias, bias, bias, bias};
          f32x4 acc1 = {bias, bias, bias, bias};
          MFMA(acc0, a00, w0); MFMA(acc1, a10, w0);
          MFMA(acc0, a01, w1); MFMA(acc1, a11, w1);
          MFMA(acc0, a02, w2); MFMA(acc1, a12, w2);
          MFMA(acc0, a03, w3); MFMA(acc1, a13, w3);
          MFMA_FENCE2(acc0, acc1);
          if (nb == 0) { rpe00 = acc0; rpe10 = acc1; }
          else { rpe01 = acc0; rpe11 = acc1; }
#pragma unroll
          for (int r2 = 0; r2 < 4; ++r2) {
            const int j = kg * 4 + r2;
            s_simbA[j * BSTR + n] = f2b(s_u[i0 * 32 + n] - s_u[512 + j * 32 + n] + acc0[r2]);
            s_simbB[j * BSTR + n] = f2b(s_u[i1 * 32 + n] - s_u[512 + j * 32 + n] + acc1[r2]);
          }
        }
      }
      {  // G2 dual: shared B, 2x4 accs per group; writes hid into work bufs
        const u16x8 as0 = *(const u16x8*)&s_simbA[ln16 * BSTR + k0];
        const u16x8 as1 = *(const u16x8*)&s_simbB[ln16 * BSTR + k0];
#pragma unroll
        for (int g2b = 0; g2b < 2; ++g2b) {
          const int nbase = g2b * 4;
          const u16x8 w0 = *(const u16x8*)&wsc[WB_PTA + ((nbase + 0) * 16 + ln16) * 32 + k0];
          const u16x8 w1 = *(const u16x8*)&wsc[WB_PTA + ((nbase + 1) * 16 + ln16) * 32 + k0];
          const u16x8 w2 = *(const u16x8*)&wsc[WB_PTA + ((nbase + 2) * 16 + ln16) * 32 + k0];
          const u16x8 w3 = *(const u16x8*)&wsc[WB_PTA + ((nbase + 3) * 16 + ln16) * 32 + k0];
          const float b0 = bh1[(nbase + 0) * 16 + ln16];
          const float b1v = bh1[(nbase + 1) * 16 + ln16];
          const float b2v = bh1[(nbase + 2) * 16 + ln16];
          const float b3 = bh1[(nbase + 3) * 16 + ln16];
          f32x4 A00 = {b0,b0,b0,b0}, A01 = {b1v,b1v,b1v,b1v};
          f32x4 A02 = {b2v,b2v,b2v,b2v}, A03 = {b3,b3,b3,b3};
          f32x4 A10 = {b0,b0,b0,b0}, A11 = {b1v,b1v,b1v,b1v};
          f32x4 A12 = {b2v,b2v,b2v,b2v}, A13 = {b3,b3,b3,b3};
          MFMA(A00, as0, w0); MFMA(A10, as1, w0);
          MFMA(A01, as0, w1); MFMA(A11, as1, w1);
          MFMA(A02, as0, w2); MFMA(A12, as1, w2);
          MFMA(A03, as0, w3); MFMA(A13, as1, w3);
          MFMA_FENCE4(A00, A01, A02, A03);
          MFMA_FENCE4(A10, A11, A12, A13);
#pragma unroll
          for (int r2 = 0; r2 < 4; ++r2) {
            const int row = (kg * 4 + r2) * HSTR;
            s_workA[row + (nbase + 0) * 16 + ln16] = f2b(fmaxf(A00[r2], 0.f));
            s_workA[row + (nbase + 1) * 16 + ln16] = f2b(fmaxf(A01[r2], 0.f));
            s_workA[row + (nbase + 2) * 16 + ln16] = f2b(fmaxf(A02[r2], 0.f));
            s_workA[row + (nbase + 3) * 16 + ln16] = f2b(fmaxf(A03[r2], 0.f));
            s_workB[row + (nbase + 0) * 16 + ln16] = f2b(fmaxf(A10[r2], 0.f));
            s_workB[row + (nbase + 1) * 16 + ln16] = f2b(fmaxf(A11[r2], 0.f));
            s_workB[row + (nbase + 2) * 16 + ln16] = f2b(fmaxf(A12[r2], 0.f));
            s_workB[row + (nbase + 3) * 16 + ln16] = f2b(fmaxf(A13[r2], 0.f));
          }
        }
      }
      {  // G3 dual + fused softmax for both streams
#pragma unroll
        for (int nb = 0; nb < 2; ++nb) {
          const int n = nb * 16 + ln16;
          const u16x8 w0 = *(const u16x8*)&wsc[WC_PTA + n * 128 + 0 * 32 + k0];
          const u16x8 w1 = *(const u16x8*)&wsc[WC_PTA + n * 128 + 1 * 32 + k0];
          const u16x8 w2 = *(const u16x8*)&wsc[WC_PTA + n * 128 + 2 * 32 + k0];
          const u16x8 w3 = *(const u16x8*)&wsc[WC_PTA + n * 128 + 3 * 32 + k0];
          const u16x8 h00 = *(const u16x8*)&s_workA[ln16 * HSTR + 0 * 32 + k0];
          const u16x8 h01 = *(const u16x8*)&s_workA[ln16 * HSTR + 1 * 32 + k0];
          const u16x8 h02 = *(const u16x8*)&s_workA[ln16 * HSTR + 2 * 32 + k0];
          const u16x8 h03 = *(const u16x8*)&s_workA[ln16 * HSTR + 3 * 32 + k0];
          const u16x8 h10 = *(const u16x8*)&s_workB[ln16 * HSTR + 0 * 32 + k0];
          const u16x8 h11 = *(const u16x8*)&s_workB[ln16 * HSTR + 1 * 32 + k0];
          const u16x8 h12 = *(const u16x8*)&s_workB[ln16 * HSTR + 2 * 32 + k0];
          const u16x8 h13 = *(const u16x8*)&s_workB[ln16 * HSTR + 3 * 32 + k0];
          const float bias = bh2[n];
          f32x4 acc0 = {bias, bias, bias, bias};
          f32x4 acc1 = {bias, bias, bias, bias};
          MFMA(acc0, h00, w0); MFMA(acc1, h10, w0);
          MFMA(acc0, h01, w1); MFMA(acc1, h11, w1);
          MFMA(acc0, h02, w2); MFMA(acc1, h12, w2);
          MFMA(acc0, h03, w3); MFMA(acc1, h13, w3);
          MFMA_FENCE2(acc0, acc1);
          const f32x4 rp0 = nb ? rpe01 : rpe00;
          const f32x4 rp1 = nb ? rpe11 : rpe10;
          // stream 0 softmax
          float mx = fmaxf(fmaxf(acc0[0], acc0[1]), fmaxf(acc0[2], acc0[3]));
          mx = fmaxf(mx, __shfl_xor(mx, 16));
          mx = fmaxf(mx, __shfl_xor(mx, 32));
          float sum = 0.f, o = 0.f;
#pragma unroll
          for (int r2 = 0; r2 < 4; ++r2) {
            const int j = kg * 4 + r2;
            const float e = __expf(acc0[r2] - mx);
            sum += e;
            o = fmaf(e, s_v[j * 32 + n] + rp0[r2], o);
          }
          sum += __shfl_xor(sum, 16); o += __shfl_xor(o, 16);
          sum += __shfl_xor(sum, 32); o += __shfl_xor(o, 32);
          if (kg == 0) s_featb[i0 * BSTR + n] = f2b(o / sum);
          // stream 1 softmax
          float mx1 = fmaxf(fmaxf(acc1[0], acc1[1]), fmaxf(acc1[2], acc1[3]));
          mx1 = fmaxf(mx1, __shfl_xor(mx1, 16));
          mx1 = fmaxf(mx1, __shfl_xor(mx1, 32));
          float sum1 = 0.f, o1 = 0.f;
#pragma unroll
          for (int r2 = 0; r2 < 4; ++r2) {
            const int j = kg * 4 + r2;
            const float e = __expf(acc1[r2] - mx1);
            sum1 += e;
            o1 = fmaf(e, s_v[j * 32 + n] + rp1[r2], o1);
          }
          sum1 += __shfl_xor(sum1, 16); o1 += __shfl_xor(o1, 16);
          sum1 += __shfl_xor(sum1, 32); o1 += __shfl_xor(o1, 32);
          if (kg == 0) s_featb[i1 * BSTR + n] = f2b(o1 / sum1);
        }
      }
    }
  }

  // ---- kk / vvb via MFMA (A = s_featb) -> s_u ----
  {
    const u16x8 af = *(const u16x8*)&s_featb[ln16 * BSTR + k0];
    const u16x8 wk0 = *(const u16x8*)&ws[WKK + (0 * 16 + ln16) * 32 + k0];
    const u16x8 wk1 = *(const u16x8*)&ws[WKK + (1 * 16 + ln16) * 32 + k0];
    const u16x8 wv0 = *(const u16x8*)&ws[WVV + (0 * 16 + ln16) * 32 + k0];
    const u16x8 wv1 = *(const u16x8*)&ws[WVV + (1 * 16 + ln16) * 32 + k0];
    const float bk0 = p.cak_b[ln16], bk1 = p.cak_b[16 + ln16];
    const float bv0 = p.cav_b[ln16], bv1 = p.cav_b[16 + ln16];
    f32x4 K0 = {bk0,bk0,bk0,bk0}, K1 = {bk1,bk1,bk1,bk1};
    f32x4 V0 = {bv0,bv0,bv0,bv0}, V1 = {bv1,bv1,bv1,bv1};
    MFMA(K0, af, wk0); MFMA(K1, af, wk1); MFMA(V0, af, wv0); MFMA(V1, af, wv1);
    MFMA_FENCE4(K0, K1, V0, V1);
#pragma unroll
    for (int r2 = 0; r2 < 4; ++r2) {
      const int row = kg * 4 + r2;
      s_u[row * 32 + ln16] = K0[r2];
      s_u[row * 32 + 16 + ln16] = K1[r2];
      s_u[512 + row * 32 + ln16] = V0[r2];
      s_u[512 + row * 32 + 16 + ln16] = V1[r2];
    }
  }

  // ---- Phase D: 8 march steps + epilogue (workA union: hv then hid) ----
  {
    const float* b2d = p.cap_b2;
    const float* bc1 = p.caa_b1;
    const float* bc2 = p.caa_b2;
    const float* fw1 = p.fw1; const float* fw2 = p.fw2; const float* fw3 = p.fw3;
    const float* cqw = p.caq_w;
    const float* iw1 = p.im_w1; const float* iw2 = p.im_w2; const float* iw3 = p.im_w3;
    const unsigned short* wsd = ws;
    for (int s = 0; s <= 8; ++s) {
      asm volatile("" : "+s"(b2d), "+s"(bc1), "+s"(bc2), "+s"(wsd));
      asm volatile("" : "+s"(fw1), "+s"(fw2), "+s"(fw3), "+s"(cqw), "+s"(iw1), "+s"(iw2), "+s"(iw3));
      float rv0 = 0.f, rv1 = 0.f, rv2 = 0.f;
      if (s < 8 && l < 16) {  // rel + o_ld
        const float r0 = s_coords[l * 3 + 0] - s_op[0];
        const float r1 = s_coords[l * 3 + 1] - s_op[1];
        const float r2 = s_coords[l * 3 + 2] - s_op[2];
        const float rd = sqrtf(r0 * r0 + r1 * r1 + r2 * r2);
        const float inv = 1.f / rd;
        rv0 = r0 * inv; rv1 = r1 * inv; rv2 = r2 * inv;
        s_reld[l] = rd;
        s_relv[l * 3 + 0] = rv0; s_relv[l * 3 + 1] = rv1; s_relv[l * 3 + 2] = rv2;
        p.o_ld[b * 128 + s * 16 + l] = rd;
      }
      {  // secA: hv via MFMA, batched -> s_workA
        float c0, c1, c2;
        if (s < 8) {
          c0 = s_coords[ln16 * 3 + 0] - s_op[0];
          c1 = s_coords[ln16 * 3 + 1] - s_op[1];
          c2 = s_coords[ln16 * 3 + 2] - s_op[2];
        } else {
          const float rd = s_reld[ln16];
          c0 = s_relv[ln16 * 3 + 0] * rd; c1 = s_relv[ln16 * 3 + 1] * rd; c2 = s_relv[ln16 * 3 + 2] * rd;
        }
        union { u16x8 v; unsigned u[4]; } cv;
        cv.u[0] = (kg == 0) ? pack2(c0, c1) : 0u;
        cv.u[1] = (kg == 0) ? pack2(c2, 1.0f) : 0u;
        cv.u[2] = 0u; cv.u[3] = 0u;
        const u16x8 afh = cv.v;
#pragma unroll
        for (int g2b = 0; g2b < 2; ++g2b) {
          const int nbase = g2b * 4;
          const u16x8 w0 = *(const u16x8*)&wsd[WH_CAP + ((nbase + 0) * 16 + ln16) * 32 + k0];
          const u16x8 w1 = *(const u16x8*)&wsd[WH_CAP + ((nbase + 1) * 16 + ln16) * 32 + k0];
          const u16x8 w2 = *(const u16x8*)&wsd[WH_CAP + ((nbase + 2) * 16 + ln16) * 32 + k0];
          const u16x8 w3 = *(const u16x8*)&wsd[WH_CAP + ((nbase + 3) * 16 + ln16) * 32 + k0];
          f32x4 A0 = {0.f,0.f,0.f,0.f}, A1 = {0.f,0.f,0.f,0.f};
          f32x4 A2 = {0.f,0.f,0.f,0.f}, A3 = {0.f,0.f,0.f,0.f};
          MFMA(A0, afh, w0); MFMA(A1, afh, w1); MFMA(A2, afh, w2); MFMA(A3, afh, w3);
          MFMA_FENCE4(A0, A1, A2, A3);
#pragma unroll
          for (int r2 = 0; r2 < 4; ++r2) {
            const int row = (kg * 4 + r2) * HSTR;
            s_workA[row + (nbase + 0) * 16 + ln16] = f2b(fmaxf(A0[r2], 0.f));
            s_workA[row + (nbase + 1) * 16 + ln16] = f2b(fmaxf(A1[r2], 0.f));
            s_workA[row + (nbase + 2) * 16 + ln16] = f2b(fmaxf(A2[r2], 0.f));
            s_workA[row + (nbase + 3) * 16 + ln16] = f2b(fmaxf(A3[r2], 0.f));
          }
        }
      }
      {  // qq chain (all lanes, width-32 shuffles; halves duplicate)
        const int h = l & 31;
        float opc0, opc1, opc2;
        if (s < 8) {
          const float cum = s_cum;
          opc0 = s_qry[0] * cum; opc1 = s_qry[1] * cum; opc2 = s_qry[2] * cum;
        } else {
          opc0 = s_op[0]; opc1 = s_op[1]; opc2 = s_op[2];
        }
        float v1 = fmaxf(fmaf(opc0, fw1[h],
                      fmaf(opc1, fw1[32 + h],
                      fmaf(opc2, fw1[64 + h], p.fb1[h]))), 0.f);
        float a = p.fb2[h];
        for (int i2 = 0; i2 < 32; ++i2) a = fmaf(__shfl(v1, i2, 32), fw2[i2 * 32 + h], a);
        const float v2 = fmaxf(a, 0.f);
        a = p.fb3[h];
        for (int i2 = 0; i2 < 32; ++i2) a = fmaf(__shfl(v2, i2, 32), fw3[i2 * 32 + h], a);
        const float opf = a;
        a = p.caq_b[h];
        for (int i2 = 0; i2 < 32; ++i2) a = fmaf(__shfl(opf, i2, 32), cqw[i2 * 32 + h], a);
        if (l < 32) s_qq[h] = a;
      }
      f32x4 pe0, pe1;
      {  // secB: A from workA (hv), batched B
#pragma unroll
        for (int nb = 0; nb < 2; ++nb) {
          const int n = nb * 16 + ln16;
          const u16x8 w0 = *(const u16x8*)&wsd[WA_CAP + n * 128 + 0 * 32 + k0];
          const u16x8 w1 = *(const u16x8*)&wsd[WA_CAP + n * 128 + 1 * 32 + k0];
          const u16x8 w2 = *(const u16x8*)&wsd[WA_CAP + n * 128 + 2 * 32 + k0];
          const u16x8 w3 = *(const u16x8*)&wsd[WA_CAP + n * 128 + 3 * 32 + k0];
          const u16x8 a0 = *(const u16x8*)&s_workA[ln16 * HSTR + 0 * 32 + k0];
          const u16x8 a1 = *(const u16x8*)&s_workA[ln16 * HSTR + 1 * 32 + k0];
          const u16x8 a2f = *(const u16x8*)&s_workA[ln16 * HSTR + 2 * 32 + k0];
          const u16x8 a3f = *(const u16x8*)&s_workA[ln16 * HSTR + 3 * 32 + k0];
          const float bias = b2d[n];
          f32x4 acc = {bias, bias, bias, bias};
          MFMA(acc, a0, w0); MFMA(acc, a1, w1); MFMA(acc, a2f, w2); MFMA(acc, a3f, w3);
          MFMA_FENCE(acc);
          if (nb == 0) pe0 = acc; else pe1 = acc;
#pragma unroll
          for (int r2 = 0; r2 < 4; ++r2) {
            const int row = kg * 4 + r2;
            s_simbA[row * BSTR + n] = f2b(s_qq[n] - s_u[row * 32 + n] + acc[r2]);
          }
        }
      }
      {  // secC: batched loads -> hid into workA (hv dead)
        const u16x8 as = *(const u16x8*)&s_simbA[ln16 * BSTR + k0];
#pragma unroll
        for (int g2b = 0; g2b < 2; ++g2b) {
          const int nbase = g2b * 4;
          const u16x8 w0 = *(const u16x8*)&wsd[WB_CAA + ((nbase + 0) * 16 + ln16) * 32 + k0];
          const u16x8 w1 = *(const u16x8*)&wsd[WB_CAA + ((nbase + 1) * 16 + ln16) * 32 + k0];
          const u16x8 w2 = *(const u16x8*)&wsd[WB_CAA + ((nbase + 2) * 16 + ln16) * 32 + k0];
          const u16x8 w3 = *(const u16x8*)&wsd[WB_CAA + ((nbase + 3) * 16 + ln16) * 32 + k0];
          const float b0 = bc1[(nbase + 0) * 16 + ln16];
          const float b1v = bc1[(nbase + 1) * 16 + ln16];
          const float b2v = bc1[(nbase + 2) * 16 + ln16];
          const float b3 = bc1[(nbase + 3) * 16 + ln16];
          f32x4 A0 = {b0,b0,b0,b0}, A1 = {b1v,b1v,b1v,b1v};
          f32x4 A2 = {b2v,b2v,b2v,b2v}, A3 = {b3,b3,b3,b3};
          MFMA(A0, as, w0); MFMA(A1, as, w1); MFMA(A2, as, w2); MFMA(A3, as, w3);
          MFMA_FENCE4(A0, A1, A2, A3);
#pragma unroll
          for (int r2 = 0; r2 < 4; ++r2) {
            const int row = (kg * 4 + r2) * HSTR;
            s_workA[row + (nbase + 0) * 16 + ln16] = f2b(fmaxf(A0[r2], 0.f));
            s_workA[row + (nbase + 1) * 16 + ln16] = f2b(fmaxf(A1[r2], 0.f));
            s_workA[row + (nbase + 2) * 16 + ln16] = f2b(fmaxf(A2[r2], 0.f));
            s_workA[row + (nbase + 3) * 16 + ln16] = f2b(fmaxf(A3[r2], 0.f));
          }
        }
      }
      // secD + in-register softmax -> ca0/ca1
      float ca0 = 0.f, ca1 = 0.f;
      {
#pragma unroll
        for (int nb = 0; nb < 2; ++nb) {
          const int n = nb * 16 + ln16;
          const u16x8 w0 = *(const u16x8*)&wsd[WC_CAA + n * 128 + 0 * 32 + k0];
          const u16x8 w1 = *(const u16x8*)&wsd[WC_CAA + n * 128 + 1 * 32 + k0];
          const u16x8 w2 = *(const u16x8*)&wsd[WC_CAA + n * 128 + 2 * 32 + k0];
          const u16x8 w3 = *(const u16x8*)&wsd[WC_CAA + n * 128 + 3 * 32 + k0];
          const u16x8 h0 = *(const u16x8*)&s_workA[ln16 * HSTR + 0 * 32 + k0];
          const u16x8 h1 = *(const u16x8*)&s_workA[ln16 * HSTR + 1 * 32 + k0];
          const u16x8 h2 = *(const u16x8*)&s_workA[ln16 * HSTR + 2 * 32 + k0];
          const u16x8 h3 = *(const u16x8*)&s_workA[ln16 * HSTR + 3 * 32 + k0];
          const float bias = bc2[n];
          f32x4 acc = {bias, bias, bias, bias};
          MFMA(acc, h0, w0); MFMA(acc, h1, w1); MFMA(acc, h2, w2); MFMA(acc, h3, w3);
          MFMA_FENCE(acc);
          const f32x4 rp = nb ? pe1 : pe0;
          float mx = fmaxf(fmaxf(acc[0], acc[1]), fmaxf(acc[2], acc[3]));
          mx = fmaxf(mx, __shfl_xor(mx, 16));
          mx = fmaxf(mx, __shfl_xor(mx, 32));
          float sum = 0.f, o = 0.f;
#pragma unroll
          for (int r2 = 0; r2 < 4; ++r2) {
            const int row = kg * 4 + r2;
            const float e = __expf(acc[r2] - mx);
            sum += e;
            o = fmaf(e, s_u[512 + row * 32 + n] + rp[r2], o);
          }
          sum += __shfl_xor(sum, 16); o += __shfl_xor(o, 16);
          sum += __shfl_xor(sum, 32); o += __shfl_xor(o, 32);
          if (nb == 0) ca0 = o / sum; else ca1 = o / sum;
        }
      }
      if (kg == 0) { s_ca[ln16] = ca0; s_ca[16 + ln16] = ca1; }
      {  // im / ep chain (width-32; halves duplicate; writes guarded)
        const int h = l & 31;
        const float cav = s_ca[h];
        if (s < 8) {
          float a = p.im_b1[h];
          for (int i2 = 0; i2 < 32; ++i2) a = fmaf(__shfl(cav, i2, 32), iw1[i2 * 32 + h], a);
          const float m1 = fmaxf(a, 0.f);
          a = p.im_b2[h];
          for (int i2 = 0; i2 < 32; ++i2) a = fmaf(__shfl(m1, i2, 32), iw2[i2 * 32 + h], a);
          const float m2 = fmaxf(a, 0.f);
          float p0 = m2 * iw3[h * 3 + 0];
          float p1 = m2 * iw3[h * 3 + 1];
          float p2 = m2 * iw3[h * 3 + 2];
#pragma unroll
          for (int m = 1; m < 32; m <<= 1) {
            p0 += __shfl_xor(p0, m, 32);
            p1 += __shfl_xor(p1, m, 32);
            p2 += __shfl_xor(p2, m, 32);
          }
          p0 += p.im_b3[0]; p1 += p.im_b3[1]; p2 += p.im_b3[2];
          const float step = sqrtf(p0 * p0 + p1 * p1 + p2 * p2);
          const float cum = s_cum;
          const float opc0 = s_qry[0] * cum, opc1 = s_qry[1] * cum, opc2 = s_qry[2] * cum;
          const float inv = 1.f / step;
          const float tg0 = p0 * inv, tg1 = p1 * inv, tg2 = p2 * inv;
          if (l == 0) {
            p.o_ms[b * 8 + s] = step;
            p.o_ip[(b * 8 + s) * 3 + 0] = opc0 + p0;
            s_op[0] = opc0 + s_qry[0] * step;
          } else if (l == 1) {
            p.o_ip[(b * 8 + s) * 3 + 1] = opc1 + p1;
            s_op[1] = opc1 + s_qry[1] * step;
          } else if (l == 2) {
            p.o_ip[(b * 8 + s) * 3 + 2] = opc2 + p2;
            s_op[2] = opc2 + s_qry[2] * step;
          } else if (l == 3) {
            s_cum = cum + step;
          }
          if (l < 16) {
            p.o_cs[b * 128 + s * 16 + l] = tg0 * rv0 + tg1 * rv1 + tg2 * rv2;
          }
        } else {
          float a = p.ep_b1[h];
          for (int i2 = 0; i2 < 32; ++i2) a = fmaf(__shfl(cav, i2, 32), p.ep_w1[i2 * 32 + h], a);
          a = fmaf(s_qry[0], p.ep_w1[1024 + h], a);
          a = fmaf(s_qry[1], p.ep_w1[1056 + h], a);
          a = fmaf(s_qry[2], p.ep_w1[1088 + h], a);
          const float e1 = fmaxf(a, 0.f);
          a = p.ep_b2[h];
          for (int i2 = 0; i2 < 32; ++i2) a = fmaf(__shfl(e1, i2, 32), p.ep_w2[i2 * 32 + h], a);
          const float e2 = fmaxf(a, 0.f);
          float pp = e2 * p.ep_w3[h];
#pragma unroll
          for (int m = 1; m < 32; m <<= 1) pp += __shfl_xor(pp, m, 32);
          if (l == 0) {
            p.o_eps[b] = pp + p.ep_b3[0];
            p.o_cum[b] = s_cum;
          }
        }
      }
    }
  }
}

extern "C" void kernel_launch(void* const* d_in, const int* in_sizes, int n_in,
                              void* d_out, int out_size, void* d_ws, size_t ws_size,
                              hipStream_t stream) {
  Params p;
  const float** f = (const float**)(void*)&p;
  for (int i = 0; i < 43; ++i) f[i] = (const float*)d_in[i];
  float* out = (float*)d_out;
  p.o_ld  = out;
  p.o_ms  = out + OFF_MS;
  p.o_cs  = out + OFF_CS;
  p.o_ip  = out + OFF_IP;
  p.o_cum = out + OFF_CUM;
  p.o_eps = out + OFF_EPS;
  unsigned short* ws = (unsigned short*)d_ws;
  prep_kernel<<<dim3(16), dim3(256), 0, stream>>>(p, ws);
  puray_kernel<<<dim3(4096), dim3(64), 0, stream>>>(p, ws);
}

// Round 24
// 241.497 us; speedup vs baseline: 3.9950x; 1.2572x over previous
//
#include <hip/hip_runtime.h>

// Problem constants: B=4096, K=16, H=32, HM=128, STEPS=8
#define OFF_MS  524288
#define OFF_CS  557056
#define OFF_IP  1081344
#define OFF_CUM 1179648
#define OFF_EPS 1183744

#define HSTR 136
#define BSTR 40

// d_ws layout (u16): bf16 weights transposed to [n][k]
#define WA_PTP 0
#define WB_PTA 4096
#define WC_PTA 8192
#define WA_CAP 12288
#define WB_CAA 16384
#define WC_CAA 20480
#define WH_PTP 24576
#define WH_CAP 28672
#define WF1    32768
#define WF2    33792
#define WF3    34816
#define WQKV   35840
#define WKK    38912
#define WVV    39936

struct Params {
  const float *knn, *query, *fw1, *fb1, *fw2, *fb2, *fw3, *fb3, *qkv_w,
    *ptp_w1, *ptp_b1, *ptp_w2, *ptp_b2, *pta_w1, *pta_b1, *pta_w2, *pta_b2,
    *caq_w, *caq_b, *cak_w, *cak_b, *cav_w, *cav_b,
    *cap_w1, *cap_b1, *cap_w2, *cap_b2, *caa_w1, *caa_b1, *caa_w2, *caa_b2,
    *im_w1, *im_b1, *im_w2, *im_b2, *im_w3, *im_b3,
    *ep_w1, *ep_b1, *ep_w2, *ep_b2, *ep_w3, *ep_b3;
  float *o_ld, *o_ms, *o_cs, *o_ip, *o_cum, *o_eps;
};
static_assert(sizeof(Params) == 49 * sizeof(void*), "Params layout");

typedef float f32x4 __attribute__((ext_vector_type(4)));
typedef unsigned short u16x8 __attribute__((ext_vector_type(8)));

__device__ __forceinline__ unsigned short f2b(float x) {
  unsigned u = __float_as_uint(x);
  u += 0x7fffu + ((u >> 16) & 1u);
  return (unsigned short)(u >> 16);
}
__device__ __forceinline__ float b2f(unsigned short x) {
  return __uint_as_float((unsigned)x << 16);
}
__device__ __forceinline__ unsigned pack2(float lo, float hi) {
  return (unsigned)f2b(lo) | ((unsigned)f2b(hi) << 16);
}

#define MFMA(acc, a, bb) \
  asm volatile("s_nop 2\n\tv_mfma_f32_16x16x32_bf16 %0, %1, %2, %0" \
               : "+v"(acc) : "v"(a), "v"(bb))
#define MFMA_FENCE(acc) asm volatile("s_nop 7\n\ts_nop 7" : "+v"(acc))
#define MFMA_FENCE2(a0, a1) \
  asm volatile("s_nop 7\n\ts_nop 7" : "+v"(a0), "+v"(a1))
#define MFMA_FENCE4(a0, a1, a2, a3) \
  asm volatile("s_nop 7\n\ts_nop 7" : "+v"(a0), "+v"(a1), "+v"(a2), "+v"(a3))

__global__ void prep_kernel(Params p, unsigned short* ws) {
  const int t = blockIdx.x * 256 + threadIdx.x;
  const int n = t >> 7, k = t & 127;
  ws[WA_PTP + t] = f2b(p.ptp_w2[k * 32 + n]);
  ws[WC_PTA + t] = f2b(p.pta_w2[k * 32 + n]);
  ws[WA_CAP + t] = f2b(p.cap_w2[k * 32 + n]);
  ws[WC_CAA + t] = f2b(p.caa_w2[k * 32 + n]);
  const int n2 = t >> 5, k2 = t & 31;
  ws[WB_PTA + t] = f2b(p.pta_w1[k2 * 128 + n2]);
  ws[WB_CAA + t] = f2b(p.caa_w1[k2 * 128 + n2]);
  ws[WH_PTP + t] = (k2 < 3) ? f2b(p.ptp_w1[k2 * 128 + n2])
                  : (k2 == 3 ? f2b(p.ptp_b1[n2]) : (unsigned short)0);
  ws[WH_CAP + t] = (k2 < 3) ? f2b(p.cap_w1[k2 * 128 + n2])
                  : (k2 == 3 ? f2b(p.cap_b1[n2]) : (unsigned short)0);
  if (t < 1024) {
    ws[WF1 + t] = (k2 < 3) ? f2b(p.fw1[k2 * 32 + n2])
                 : (k2 == 3 ? f2b(p.fb1[n2]) : (unsigned short)0);
    ws[WF2 + t] = f2b(p.fw2[k2 * 32 + n2]);
    ws[WF3 + t] = f2b(p.fw3[k2 * 32 + n2]);
    ws[WKK + t] = f2b(p.cak_w[k2 * 32 + n2]);
    ws[WVV + t] = f2b(p.cav_w[k2 * 32 + n2]);
  }
  if (t < 3072) ws[WQKV + t] = f2b(p.qkv_w[k2 * 96 + n2]);
}

// DUAL-BATCH WAVE: grid 2048, one wave = 2 batches. A/B/C sequential per
// batch (C keeps dual-i streams); phase D dual-streamed across batches:
// MFMA sections share B-frags (workA=b0, workB=b1); scalar chains (qq/im/ep)
// run free-dual -- half 0 = batch 0, half 1 = batch 1 (width-32 shuffles stay
// in-half). q/k/kk/vv/v stored bf16 -> LDS 20408B <= 20480 (8 blocks/CU).
// Pass count 2 -> 1.
__launch_bounds__(64, 2)
__global__ void puray_kernel(Params p, const unsigned short* ws) {
  const int b0 = blockIdx.x * 2;
  const int l = threadIdx.x;
  const int ln16 = l & 15, kg = l >> 4, k0 = kg * 8;
  const int gH = l >> 5, lh = l & 31;   // half id = batch for scalar parts

  __shared__ __align__(16) unsigned short s_workA[16 * HSTR];
  __shared__ __align__(16) unsigned short s_workB[16 * HSTR];
  __shared__ __align__(16) unsigned short s_simbA[16 * BSTR];
  __shared__ __align__(16) unsigned short s_simbB[16 * BSTR];
  __shared__ __align__(16) unsigned short s_featb[2][16 * BSTR];
  __shared__ __align__(16) unsigned short s_ub[2][1024];  // bf16 q|k / kk|vv
  __shared__ __align__(16) unsigned short s_vb[512];      // bf16 v (per-batch C)
  __shared__ float s_coords[2][48], s_relv[2][48], s_reld[2][16];
  __shared__ float s_qry[2][3], s_op[2][3], s_qq[2][32], s_ca[2][32];
  __shared__ float s_cum[2];

  for (int idx = l; idx < 96; idx += 64) s_coords[idx / 48][idx % 48] = p.knn[b0 * 48 + idx];
  if (l < 6) s_qry[l / 3][l % 3] = p.query[b0 * 3 + l];
  else if (l < 8) s_cum[l - 6] = 0.f;
  else if (l < 14) s_op[(l - 8) / 3][(l - 8) % 3] = 0.f;
  __syncthreads();

  // ================= Phases A/B/C + kkvv per batch =================
  for (int g = 0; g < 2; ++g) {
    const float* cg = s_coords[g];
    {  // A-L1: coords -> h1 (s_simbA)
      union { u16x8 v; unsigned u[4]; } cv;
      cv.u[0] = (kg == 0) ? pack2(cg[ln16 * 3 + 0], cg[ln16 * 3 + 1]) : 0u;
      cv.u[1] = (kg == 0) ? pack2(cg[ln16 * 3 + 2], 1.0f) : 0u;
      cv.u[2] = 0u; cv.u[3] = 0u;
      const u16x8 af = cv.v;
      const u16x8 w0 = *(const u16x8*)&ws[WF1 + (0 * 16 + ln16) * 32 + k0];
      const u16x8 w1 = *(const u16x8*)&ws[WF1 + (1 * 16 + ln16) * 32 + k0];
      f32x4 A0 = {0.f,0.f,0.f,0.f}, A1 = {0.f,0.f,0.f,0.f};
      MFMA(A0, af, w0); MFMA(A1, af, w1);
      MFMA_FENCE2(A0, A1);
#pragma unroll
      for (int r2 = 0; r2 < 4; ++r2) {
        const int row = (kg * 4 + r2) * BSTR;
        s_simbA[row + 0 * 16 + ln16] = f2b(fmaxf(A0[r2], 0.f));
        s_simbA[row + 1 * 16 + ln16] = f2b(fmaxf(A1[r2], 0.f));
      }
    }
    {  // A-L2: h1 -> h2 (s_workA)
      const u16x8 af = *(const u16x8*)&s_simbA[ln16 * BSTR + k0];
      const u16x8 w0 = *(const u16x8*)&ws[WF2 + (0 * 16 + ln16) * 32 + k0];
      const u16x8 w1 = *(const u16x8*)&ws[WF2 + (1 * 16 + ln16) * 32 + k0];
      const float b0v = p.fb2[ln16], b1v = p.fb2[16 + ln16];
      f32x4 A0 = {b0v,b0v,b0v,b0v}, A1 = {b1v,b1v,b1v,b1v};
      MFMA(A0, af, w0); MFMA(A1, af, w1);
      MFMA_FENCE2(A0, A1);
#pragma unroll
      for (int r2 = 0; r2 < 4; ++r2) {
        const int row = (kg * 4 + r2) * HSTR;
        s_workA[row + 0 * 16 + ln16] = f2b(fmaxf(A0[r2], 0.f));
        s_workA[row + 1 * 16 + ln16] = f2b(fmaxf(A1[r2], 0.f));
      }
    }
    {  // A-L3: h2 -> feats (s_featb[g])
      const u16x8 af = *(const u16x8*)&s_workA[ln16 * HSTR + k0];
      const u16x8 w0 = *(const u16x8*)&ws[WF3 + (0 * 16 + ln16) * 32 + k0];
      const u16x8 w1 = *(const u16x8*)&ws[WF3 + (1 * 16 + ln16) * 32 + k0];
      const float b0v = p.fb3[ln16], b1v = p.fb3[16 + ln16];
      f32x4 A0 = {b0v,b0v,b0v,b0v}, A1 = {b1v,b1v,b1v,b1v};
      MFMA(A0, af, w0); MFMA(A1, af, w1);
      MFMA_FENCE2(A0, A1);
#pragma unroll
      for (int r2 = 0; r2 < 4; ++r2) {
        const int row = (kg * 4 + r2) * BSTR;
        s_featb[g][row + 0 * 16 + ln16] = f2b(A0[r2]);
        s_featb[g][row + 1 * 16 + ln16] = f2b(A1[r2]);
      }
    }
    {  // B: qkv -> s_ub[g] (q|k, bf16) + s_vb (bf16)
      const u16x8 af = *(const u16x8*)&s_featb[g][ln16 * BSTR + k0];
#pragma unroll
      for (int g6 = 0; g6 < 2; ++g6) {
        const int nb0 = g6 * 3;
        const u16x8 w0 = *(const u16x8*)&ws[WQKV + ((nb0 + 0) * 16 + ln16) * 32 + k0];
        const u16x8 w1 = *(const u16x8*)&ws[WQKV + ((nb0 + 1) * 16 + ln16) * 32 + k0];
        const u16x8 w2 = *(const u16x8*)&ws[WQKV + ((nb0 + 2) * 16 + ln16) * 32 + k0];
        f32x4 A0 = {0.f,0.f,0.f,0.f}, A1 = {0.f,0.f,0.f,0.f}, A2 = {0.f,0.f,0.f,0.f};
        MFMA(A0, af, w0); MFMA(A1, af, w1); MFMA(A2, af, w2);
        asm volatile("s_nop 7\n\ts_nop 7" : "+v"(A0), "+v"(A1), "+v"(A2));
#pragma unroll
        for (int j6 = 0; j6 < 3; ++j6) {
          const int o = (nb0 + j6) * 16 + ln16;
          const f32x4 acc = (j6 == 0) ? A0 : (j6 == 1) ? A1 : A2;
#pragma unroll
          for (int r2 = 0; r2 < 4; ++r2) {
            const int row = kg * 4 + r2;
            if (o < 32) s_ub[g][row * 32 + o] = f2b(acc[r2]);
            else if (o < 64) s_ub[g][512 + row * 32 + o - 32] = f2b(acc[r2]);
            else s_vb[row * 32 + o - 64] = f2b(acc[r2]);
          }
        }
      }
    }
    // ---- Phase C (dual-i streams within batch g) ----
    {
      const float* b2c = p.ptp_b2;
      const float* bh1 = p.pta_b1;
      const float* bh2 = p.pta_b2;
      const unsigned short* wsc = ws;
      for (int ip = 0; ip < 8; ++ip) {
        asm volatile("" : "+s"(b2c), "+s"(bh1), "+s"(bh2), "+s"(wsc));
        const int i0 = ip * 2, i1 = ip * 2 + 1;
        const float c00 = cg[i0 * 3 + 0] - cg[ln16 * 3 + 0];
        const float c01 = cg[i0 * 3 + 1] - cg[ln16 * 3 + 1];
        const float c02 = cg[i0 * 3 + 2] - cg[ln16 * 3 + 2];
        const float c10 = cg[i1 * 3 + 0] - cg[ln16 * 3 + 0];
        const float c11 = cg[i1 * 3 + 1] - cg[ln16 * 3 + 1];
        const float c12 = cg[i1 * 3 + 2] - cg[ln16 * 3 + 2];
        {  // hv dual
          union { u16x8 v; unsigned u[4]; } cv0, cv1;
          cv0.u[0] = (kg == 0) ? pack2(c00, c01) : 0u;
          cv0.u[1] = (kg == 0) ? pack2(c02, 1.0f) : 0u;
          cv0.u[2] = 0u; cv0.u[3] = 0u;
          cv1.u[0] = (kg == 0) ? pack2(c10, c11) : 0u;
          cv1.u[1] = (kg == 0) ? pack2(c12, 1.0f) : 0u;
          cv1.u[2] = 0u; cv1.u[3] = 0u;
          const u16x8 af0 = cv0.v, af1 = cv1.v;
#pragma unroll
          for (int g2b = 0; g2b < 2; ++g2b) {
            const int nbase = g2b * 4;
            const u16x8 w0 = *(const u16x8*)&wsc[WH_PTP + ((nbase + 0) * 16 + ln16) * 32 + k0];
            const u16x8 w1 = *(const u16x8*)&wsc[WH_PTP + ((nbase + 1) * 16 + ln16) * 32 + k0];
            const u16x8 w2 = *(const u16x8*)&wsc[WH_PTP + ((nbase + 2) * 16 + ln16) * 32 + k0];
            const u16x8 w3 = *(const u16x8*)&wsc[WH_PTP + ((nbase + 3) * 16 + ln16) * 32 + k0];
            f32x4 A00 = {0.f,0.f,0.f,0.f}, A01 = {0.f,0.f,0.f,0.f};
            f32x4 A02 = {0.f,0.f,0.f,0.f}, A03 = {0.f,0.f,0.f,0.f};
            f32x4 A10 = {0.f,0.f,0.f,0.f}, A11 = {0.f,0.f,0.f,0.f};
            f32x4 A12 = {0.f,0.f,0.f,0.f}, A13 = {0.f,0.f,0.f,0.f};
            MFMA(A00, af0, w0); MFMA(A10, af1, w0);
            MFMA(A01, af0, w1); MFMA(A11, af1, w1);
            MFMA(A02, af0, w2); MFMA(A12, af1, w2);
            MFMA(A03, af0, w3); MFMA(A13, af1, w3);
            MFMA_FENCE4(A00, A01, A02, A03);
            MFMA_FENCE4(A10, A11, A12, A13);
#pragma unroll
            for (int r2 = 0; r2 < 4; ++r2) {
              const int row = (kg * 4 + r2) * HSTR;
              s_workA[row + (nbase + 0) * 16 + ln16] = f2b(fmaxf(A00[r2], 0.f));
              s_workA[row + (nbase + 1) * 16 + ln16] = f2b(fmaxf(A01[r2], 0.f));
              s_workA[row + (nbase + 2) * 16 + ln16] = f2b(fmaxf(A02[r2], 0.f));
              s_workA[row + (nbase + 3) * 16 + ln16] = f2b(fmaxf(A03[r2], 0.f));
              s_workB[row + (nbase + 0) * 16 + ln16] = f2b(fmaxf(A10[r2], 0.f));
              s_workB[row + (nbase + 1) * 16 + ln16] = f2b(fmaxf(A11[r2], 0.f));
              s_workB[row + (nbase + 2) * 16 + ln16] = f2b(fmaxf(A12[r2], 0.f));
              s_workB[row + (nbase + 3) * 16 + ln16] = f2b(fmaxf(A13[r2], 0.f));
            }
          }
        }
        f32x4 rpe00, rpe01, rpe10, rpe11;
        {  // G1 dual
#pragma unroll
          for (int nb = 0; nb < 2; ++nb) {
            const int n = nb * 16 + ln16;
            const u16x8 w0 = *(const u16x8*)&wsc[WA_PTP + n * 128 + 0 * 32 + k0];
            const u16x8 w1 = *(const u16x8*)&wsc[WA_PTP + n * 128 + 1 * 32 + k0];
            const u16x8 w2 = *(const u16x8*)&wsc[WA_PTP + n * 128 + 2 * 32 + k0];
            const u16x8 w3 = *(const u16x8*)&wsc[WA_PTP + n * 128 + 3 * 32 + k0];
            const u16x8 a00 = *(const u16x8*)&s_workA[ln16 * HSTR + 0 * 32 + k0];
            const u16x8 a01 = *(const u16x8*)&s_workA[ln16 * HSTR + 1 * 32 + k0];
            const u16x8 a02 = *(const u16x8*)&s_workA[ln16 * HSTR + 2 * 32 + k0];
            const u16x8 a03 = *(const u16x8*)&s_workA[ln16 * HSTR + 3 * 32 + k0];
            const u16x8 a10 = *(const u16x8*)&s_workB[ln16 * HSTR + 0 * 32 + k0];
            const u16x8 a11 = *(const u16x8*)&s_workB[ln16 * HSTR + 1 * 32 + k0];
            const u16x8 a12 = *(const u16x8*)&s_workB[ln16 * HSTR + 2 * 32 + k0];
            const u16x8 a13 = *(const u16x8*)&s_workB[ln16 * HSTR + 3 * 32 + k0];
            const float bias = b2c[n];
            f32x4 acc0 = {bias, bias, bias, bias};
            f32x4 acc1 = {bias, bias, bias, bias};
            MFMA(acc0, a00, w0); MFMA(acc1, a10, w0);
            MFMA(acc0, a01, w1); MFMA(acc1, a11, w1);
            MFMA(acc0, a02, w2); MFMA(acc1, a12, w2);
            MFMA(acc0, a03, w3); MFMA(acc1, a13, w3);
            MFMA_FENCE2(acc0, acc1);
            if (nb == 0) { rpe00 = acc0; rpe10 = acc1; }
            else { rpe01 = acc0; rpe11 = acc1; }
#pragma unroll
            for (int r2 = 0; r2 < 4; ++r2) {
              const int j = kg * 4 + r2;
              s_simbA[j * BSTR + n] =
                f2b(b2f(s_ub[g][i0 * 32 + n]) - b2f(s_ub[g][512 + j * 32 + n]) + acc0[r2]);
              s_simbB[j * BSTR + n] =
                f2b(b2f(s_ub[g][i1 * 32 + n]) - b2f(s_ub[g][512 + j * 32 + n]) + acc1[r2]);
            }
          }
        }
        {  // G2 dual
          const u16x8 as0 = *(const u16x8*)&s_simbA[ln16 * BSTR + k0];
          const u16x8 as1 = *(const u16x8*)&s_simbB[ln16 * BSTR + k0];
#pragma unroll
          for (int g2b = 0; g2b < 2; ++g2b) {
            const int nbase = g2b * 4;
            const u16x8 w0 = *(const u16x8*)&wsc[WB_PTA + ((nbase + 0) * 16 + ln16) * 32 + k0];
            const u16x8 w1 = *(const u16x8*)&wsc[WB_PTA + ((nbase + 1) * 16 + ln16) * 32 + k0];
            const u16x8 w2 = *(const u16x8*)&wsc[WB_PTA + ((nbase + 2) * 16 + ln16) * 32 + k0];
            const u16x8 w3 = *(const u16x8*)&wsc[WB_PTA + ((nbase + 3) * 16 + ln16) * 32 + k0];
            const float b0v = bh1[(nbase + 0) * 16 + ln16];
            const float b1v = bh1[(nbase + 1) * 16 + ln16];
            const float b2v = bh1[(nbase + 2) * 16 + ln16];
            const float b3v = bh1[(nbase + 3) * 16 + ln16];
            f32x4 A00 = {b0v,b0v,b0v,b0v}, A01 = {b1v,b1v,b1v,b1v};
            f32x4 A02 = {b2v,b2v,b2v,b2v}, A03 = {b3v,b3v,b3v,b3v};
            f32x4 A10 = {b0v,b0v,b0v,b0v}, A11 = {b1v,b1v,b1v,b1v};
            f32x4 A12 = {b2v,b2v,b2v,b2v}, A13 = {b3v,b3v,b3v,b3v};
            MFMA(A00, as0, w0); MFMA(A10, as1, w0);
            MFMA(A01, as0, w1); MFMA(A11, as1, w1);
            MFMA(A02, as0, w2); MFMA(A12, as1, w2);
            MFMA(A03, as0, w3); MFMA(A13, as1, w3);
            MFMA_FENCE4(A00, A01, A02, A03);
            MFMA_FENCE4(A10, A11, A12, A13);
#pragma unroll
            for (int r2 = 0; r2 < 4; ++r2) {
              const int row = (kg * 4 + r2) * HSTR;
              s_workA[row + (nbase + 0) * 16 + ln16] = f2b(fmaxf(A00[r2], 0.f));
              s_workA[row + (nbase + 1) * 16 + ln16] = f2b(fmaxf(A01[r2], 0.f));
              s_workA[row + (nbase + 2) * 16 + ln16] = f2b(fmaxf(A02[r2], 0.f));
              s_workA[row + (nbase + 3) * 16 + ln16] = f2b(fmaxf(A03[r2], 0.f));
              s_workB[row + (nbase + 0) * 16 + ln16] = f2b(fmaxf(A10[r2], 0.f));
              s_workB[row + (nbase + 1) * 16 + ln16] = f2b(fmaxf(A11[r2], 0.f));
              s_workB[row + (nbase + 2) * 16 + ln16] = f2b(fmaxf(A12[r2], 0.f));
              s_workB[row + (nbase + 3) * 16 + ln16] = f2b(fmaxf(A13[r2], 0.f));
            }
          }
        }
        {  // G3 dual + softmax
#pragma unroll
          for (int nb = 0; nb < 2; ++nb) {
            const int n = nb * 16 + ln16;
            const u16x8 w0 = *(const u16x8*)&wsc[WC_PTA + n * 128 + 0 * 32 + k0];
            const u16x8 w1 = *(const u16x8*)&wsc[WC_PTA + n * 128 + 1 * 32 + k0];
            const u16x8 w2 = *(const u16x8*)&wsc[WC_PTA + n * 128 + 2 * 32 + k0];
            const u16x8 w3 = *(const u16x8*)&wsc[WC_PTA + n * 128 + 3 * 32 + k0];
            const u16x8 h00 = *(const u16x8*)&s_workA[ln16 * HSTR + 0 * 32 + k0];
            const u16x8 h01 = *(const u16x8*)&s_workA[ln16 * HSTR + 1 * 32 + k0];
            const u16x8 h02 = *(const u16x8*)&s_workA[ln16 * HSTR + 2 * 32 + k0];
            const u16x8 h03 = *(const u16x8*)&s_workA[ln16 * HSTR + 3 * 32 + k0];
            const u16x8 h10 = *(const u16x8*)&s_workB[ln16 * HSTR + 0 * 32 + k0];
            const u16x8 h11 = *(const u16x8*)&s_workB[ln16 * HSTR + 1 * 32 + k0];
            const u16x8 h12 = *(const u16x8*)&s_workB[ln16 * HSTR + 2 * 32 + k0];
            const u16x8 h13 = *(const u16x8*)&s_workB[ln16 * HSTR + 3 * 32 + k0];
            const float bias = bh2[n];
            f32x4 acc0 = {bias, bias, bias, bias};
            f32x4 acc1 = {bias, bias, bias, bias};
            MFMA(acc0, h00, w0); MFMA(acc1, h10, w0);
            MFMA(acc0, h01, w1); MFMA(acc1, h11, w1);
            MFMA(acc0, h02, w2); MFMA(acc1, h12, w2);
            MFMA(acc0, h03, w3); MFMA(acc1, h13, w3);
            MFMA_FENCE2(acc0, acc1);
            const f32x4 rp0 = nb ? rpe01 : rpe00;
            const f32x4 rp1 = nb ? rpe11 : rpe10;
            float mx = fmaxf(fmaxf(acc0[0], acc0[1]), fmaxf(acc0[2], acc0[3]));
            mx = fmaxf(mx, __shfl_xor(mx, 16));
            mx = fmaxf(mx, __shfl_xor(mx, 32));
            float sum = 0.f, o = 0.f;
#pragma unroll
            for (int r2 = 0; r2 < 4; ++r2) {
              const int j = kg * 4 + r2;
              const float e = __expf(acc0[r2] - mx);
              sum += e;
              o = fmaf(e, b2f(s_vb[j * 32 + n]) + rp0[r2], o);
            }
            sum += __shfl_xor(sum, 16); o += __shfl_xor(o, 16);
            sum += __shfl_xor(sum, 32); o += __shfl_xor(o, 32);
            if (kg == 0) s_featb[g][i0 * BSTR + n] = f2b(o / sum);
            float mx1 = fmaxf(fmaxf(acc1[0], acc1[1]), fmaxf(acc1[2], acc1[3]));
            mx1 = fmaxf(mx1, __shfl_xor(mx1, 16));
            mx1 = fmaxf(mx1, __shfl_xor(mx1, 32));
            float sum1 = 0.f, o1 = 0.f;
#pragma unroll
            for (int r2 = 0; r2 < 4; ++r2) {
              const int j = kg * 4 + r2;
              const float e = __expf(acc1[r2] - mx1);
              sum1 += e;
              o1 = fmaf(e, b2f(s_vb[j * 32 + n]) + rp1[r2], o1);
            }
            sum1 += __shfl_xor(sum1, 16); o1 += __shfl_xor(o1, 16);
            sum1 += __shfl_xor(sum1, 32); o1 += __shfl_xor(o1, 32);
            if (kg == 0) s_featb[g][i1 * BSTR + n] = f2b(o1 / sum1);
          }
        }
      }
    }
    // ---- kk / vvb for batch g ----
    {
      const u16x8 af = *(const u16x8*)&s_featb[g][ln16 * BSTR + k0];
      const u16x8 wk0 = *(const u16x8*)&ws[WKK + (0 * 16 + ln16) * 32 + k0];
      const u16x8 wk1 = *(const u16x8*)&ws[WKK + (1 * 16 + ln16) * 32 + k0];
      const u16x8 wv0 = *(const u16x8*)&ws[WVV + (0 * 16 + ln16) * 32 + k0];
      const u16x8 wv1 = *(const u16x8*)&ws[WVV + (1 * 16 + ln16) * 32 + k0];
      const float bk0 = p.cak_b[ln16], bk1 = p.cak_b[16 + ln16];
      const float bv0 = p.cav_b[ln16], bv1 = p.cav_b[16 + ln16];
      f32x4 K0 = {bk0,bk0,bk0,bk0}, K1 = {bk1,bk1,bk1,bk1};
      f32x4 V0 = {bv0,bv0,bv0,bv0}, V1 = {bv1,bv1,bv1,bv1};
      MFMA(K0, af, wk0); MFMA(K1, af, wk1); MFMA(V0, af, wv0); MFMA(V1, af, wv1);
      MFMA_FENCE4(K0, K1, V0, V1);
#pragma unroll
      for (int r2 = 0; r2 < 4; ++r2) {
        const int row = kg * 4 + r2;
        s_ub[g][row * 32 + ln16] = f2b(K0[r2]);
        s_ub[g][row * 32 + 16 + ln16] = f2b(K1[r2]);
        s_ub[g][512 + row * 32 + ln16] = f2b(V0[r2]);
        s_ub[g][512 + row * 32 + 16 + ln16] = f2b(V1[r2]);
      }
    }
  }

  // ================= Phase D: both batches dual-streamed =================
  {
    const float* b2d = p.cap_b2;
    const float* bc1 = p.caa_b1;
    const float* bc2 = p.caa_b2;
    const float* fw1 = p.fw1; const float* fw2 = p.fw2; const float* fw3 = p.fw3;
    const float* cqw = p.caq_w;
    const float* iw1 = p.im_w1; const float* iw2 = p.im_w2; const float* iw3 = p.im_w3;
    const unsigned short* wsd = ws;
    for (int s = 0; s <= 8; ++s) {
      asm volatile("" : "+s"(b2d), "+s"(bc1), "+s"(bc2), "+s"(wsd));
      asm volatile("" : "+s"(fw1), "+s"(fw2), "+s"(fw3), "+s"(cqw), "+s"(iw1), "+s"(iw2), "+s"(iw3));
      float rv0 = 0.f, rv1 = 0.f, rv2 = 0.f;
      // rel: lanes 0-15 batch0, lanes 32-47 batch1
      if (s < 8 && lh < 16) {
        const int k = lh;
        const float r0 = s_coords[gH][k * 3 + 0] - s_op[gH][0];
        const float r1 = s_coords[gH][k * 3 + 1] - s_op[gH][1];
        const float r2 = s_coords[gH][k * 3 + 2] - s_op[gH][2];
        const float rd = sqrtf(r0 * r0 + r1 * r1 + r2 * r2);
        const float inv = 1.f / rd;
        rv0 = r0 * inv; rv1 = r1 * inv; rv2 = r2 * inv;
        s_reld[gH][k] = rd;
        s_relv[gH][k * 3 + 0] = rv0; s_relv[gH][k * 3 + 1] = rv1; s_relv[gH][k * 3 + 2] = rv2;
        p.o_ld[(b0 + gH) * 128 + s * 16 + k] = rd;
      }
      {  // secA dual: hv for both batches -> workA/workB
        float c00, c01, c02, c10, c11, c12;
        if (s < 8) {
          c00 = s_coords[0][ln16 * 3 + 0] - s_op[0][0];
          c01 = s_coords[0][ln16 * 3 + 1] - s_op[0][1];
          c02 = s_coords[0][ln16 * 3 + 2] - s_op[0][2];
          c10 = s_coords[1][ln16 * 3 + 0] - s_op[1][0];
          c11 = s_coords[1][ln16 * 3 + 1] - s_op[1][1];
          c12 = s_coords[1][ln16 * 3 + 2] - s_op[1][2];
        } else {
          const float rd0 = s_reld[0][ln16], rd1 = s_reld[1][ln16];
          c00 = s_relv[0][ln16 * 3 + 0] * rd0; c01 = s_relv[0][ln16 * 3 + 1] * rd0;
          c02 = s_relv[0][ln16 * 3 + 2] * rd0;
          c10 = s_relv[1][ln16 * 3 + 0] * rd1; c11 = s_relv[1][ln16 * 3 + 1] * rd1;
          c12 = s_relv[1][ln16 * 3 + 2] * rd1;
        }
        union { u16x8 v; unsigned u[4]; } cv0, cv1;
        cv0.u[0] = (kg == 0) ? pack2(c00, c01) : 0u;
        cv0.u[1] = (kg == 0) ? pack2(c02, 1.0f) : 0u;
        cv0.u[2] = 0u; cv0.u[3] = 0u;
        cv1.u[0] = (kg == 0) ? pack2(c10, c11) : 0u;
        cv1.u[1] = (kg == 0) ? pack2(c12, 1.0f) : 0u;
        cv1.u[2] = 0u; cv1.u[3] = 0u;
        const u16x8 af0 = cv0.v, af1 = cv1.v;
#pragma unroll
        for (int g2b = 0; g2b < 2; ++g2b) {
          const int nbase = g2b * 4;
          const u16x8 w0 = *(const u16x8*)&wsd[WH_CAP + ((nbase + 0) * 16 + ln16) * 32 + k0];
          const u16x8 w1 = *(const u16x8*)&wsd[WH_CAP + ((nbase + 1) * 16 + ln16) * 32 + k0];
          const u16x8 w2 = *(const u16x8*)&wsd[WH_CAP + ((nbase + 2) * 16 + ln16) * 32 + k0];
          const u16x8 w3 = *(const u16x8*)&wsd[WH_CAP + ((nbase + 3) * 16 + ln16) * 32 + k0];
          f32x4 A00 = {0.f,0.f,0.f,0.f}, A01 = {0.f,0.f,0.f,0.f};
          f32x4 A02 = {0.f,0.f,0.f,0.f}, A03 = {0.f,0.f,0.f,0.f};
          f32x4 A10 = {0.f,0.f,0.f,0.f}, A11 = {0.f,0.f,0.f,0.f};
          f32x4 A12 = {0.f,0.f,0.f,0.f}, A13 = {0.f,0.f,0.f,0.f};
          MFMA(A00, af0, w0); MFMA(A10, af1, w0);
          MFMA(A01, af0, w1); MFMA(A11, af1, w1);
          MFMA(A02, af0, w2); MFMA(A12, af1, w2);
          MFMA(A03, af0, w3); MFMA(A13, af1, w3);
          MFMA_FENCE4(A00, A01, A02, A03);
          MFMA_FENCE4(A10, A11, A12, A13);
#pragma unroll
          for (int r2 = 0; r2 < 4; ++r2) {
            const int row = (kg * 4 + r2) * HSTR;
            s_workA[row + (nbase + 0) * 16 + ln16] = f2b(fmaxf(A00[r2], 0.f));
            s_workA[row + (nbase + 1) * 16 + ln16] = f2b(fmaxf(A01[r2], 0.f));
            s_workA[row + (nbase + 2) * 16 + ln16] = f2b(fmaxf(A02[r2], 0.f));
            s_workA[row + (nbase + 3) * 16 + ln16] = f2b(fmaxf(A03[r2], 0.f));
            s_workB[row + (nbase + 0) * 16 + ln16] = f2b(fmaxf(A10[r2], 0.f));
            s_workB[row + (nbase + 1) * 16 + ln16] = f2b(fmaxf(A11[r2], 0.f));
            s_workB[row + (nbase + 2) * 16 + ln16] = f2b(fmaxf(A12[r2], 0.f));
            s_workB[row + (nbase + 3) * 16 + ln16] = f2b(fmaxf(A13[r2], 0.f));
          }
        }
      }
      {  // qq chain: half gH computes its batch (width-32 shuffles in-half)
        const int h = lh;
        float opc0, opc1, opc2;
        if (s < 8) {
          const float cum = s_cum[gH];
          opc0 = s_qry[gH][0] * cum; opc1 = s_qry[gH][1] * cum; opc2 = s_qry[gH][2] * cum;
        } else {
          opc0 = s_op[gH][0]; opc1 = s_op[gH][1]; opc2 = s_op[gH][2];
        }
        float v1 = fmaxf(fmaf(opc0, fw1[h],
                      fmaf(opc1, fw1[32 + h],
                      fmaf(opc2, fw1[64 + h], p.fb1[h]))), 0.f);
        float a = p.fb2[h];
        for (int i2 = 0; i2 < 32; ++i2) a = fmaf(__shfl(v1, i2, 32), fw2[i2 * 32 + h], a);
        const float v2 = fmaxf(a, 0.f);
        a = p.fb3[h];
        for (int i2 = 0; i2 < 32; ++i2) a = fmaf(__shfl(v2, i2, 32), fw3[i2 * 32 + h], a);
        const float opf = a;
        a = p.caq_b[h];
        for (int i2 = 0; i2 < 32; ++i2) a = fmaf(__shfl(opf, i2, 32), cqw[i2 * 32 + h], a);
        s_qq[gH][h] = a;
      }
      f32x4 pe00, pe01, pe10, pe11;
      {  // secB dual
#pragma unroll
        for (int nb = 0; nb < 2; ++nb) {
          const int n = nb * 16 + ln16;
          const u16x8 w0 = *(const u16x8*)&wsd[WA_CAP + n * 128 + 0 * 32 + k0];
          const u16x8 w1 = *(const u16x8*)&wsd[WA_CAP + n * 128 + 1 * 32 + k0];
          const u16x8 w2 = *(const u16x8*)&wsd[WA_CAP + n * 128 + 2 * 32 + k0];
          const u16x8 w3 = *(const u16x8*)&wsd[WA_CAP + n * 128 + 3 * 32 + k0];
          const u16x8 a00 = *(const u16x8*)&s_workA[ln16 * HSTR + 0 * 32 + k0];
          const u16x8 a01 = *(const u16x8*)&s_workA[ln16 * HSTR + 1 * 32 + k0];
          const u16x8 a02 = *(const u16x8*)&s_workA[ln16 * HSTR + 2 * 32 + k0];
          const u16x8 a03 = *(const u16x8*)&s_workA[ln16 * HSTR + 3 * 32 + k0];
          const u16x8 a10 = *(const u16x8*)&s_workB[ln16 * HSTR + 0 * 32 + k0];
          const u16x8 a11 = *(const u16x8*)&s_workB[ln16 * HSTR + 1 * 32 + k0];
          const u16x8 a12 = *(const u16x8*)&s_workB[ln16 * HSTR + 2 * 32 + k0];
          const u16x8 a13 = *(const u16x8*)&s_workB[ln16 * HSTR + 3 * 32 + k0];
          const float bias = b2d[n];
          f32x4 acc0 = {bias, bias, bias, bias};
          f32x4 acc1 = {bias, bias, bias, bias};
          MFMA(acc0, a00, w0); MFMA(acc1, a10, w0);
          MFMA(acc0, a01, w1); MFMA(acc1, a11, w1);
          MFMA(acc0, a02, w2); MFMA(acc1, a12, w2);
          MFMA(acc0, a03, w3); MFMA(acc1, a13, w3);
          MFMA_FENCE2(acc0, acc1);
          if (nb == 0) { pe00 = acc0; pe10 = acc1; }
          else { pe01 = acc0; pe11 = acc1; }
#pragma unroll
          for (int r2 = 0; r2 < 4; ++r2) {
            const int row = kg * 4 + r2;
            s_simbA[row * BSTR + n] =
              f2b(s_qq[0][n] - b2f(s_ub[0][row * 32 + n]) + acc0[r2]);
            s_simbB[row * BSTR + n] =
              f2b(s_qq[1][n] - b2f(s_ub[1][row * 32 + n]) + acc1[r2]);
          }
        }
      }
      {  // secC dual
        const u16x8 as0 = *(const u16x8*)&s_simbA[ln16 * BSTR + k0];
        const u16x8 as1 = *(const u16x8*)&s_simbB[ln16 * BSTR + k0];
#pragma unroll
        for (int g2b = 0; g2b < 2; ++g2b) {
          const int nbase = g2b * 4;
          const u16x8 w0 = *(const u16x8*)&wsd[WB_CAA + ((nbase + 0) * 16 + ln16) * 32 + k0];
          const u16x8 w1 = *(const u16x8*)&wsd[WB_CAA + ((nbase + 1) * 16 + ln16) * 32 + k0];
          const u16x8 w2 = *(const u16x8*)&wsd[WB_CAA + ((nbase + 2) * 16 + ln16) * 32 + k0];
          const u16x8 w3 = *(const u16x8*)&wsd[WB_CAA + ((nbase + 3) * 16 + ln16) * 32 + k0];
          const float b0v = bc1[(nbase + 0) * 16 + ln16];
          const float b1v = bc1[(nbase + 1) * 16 + ln16];
          const float b2v = bc1[(nbase + 2) * 16 + ln16];
          const float b3v = bc1[(nbase + 3) * 16 + ln16];
          f32x4 A00 = {b0v,b0v,b0v,b0v}, A01 = {b1v,b1v,b1v,b1v};
          f32x4 A02 = {b2v,b2v,b2v,b2v}, A03 = {b3v,b3v,b3v,b3v};
          f32x4 A10 = {b0v,b0v,b0v,b0v}, A11 = {b1v,b1v,b1v,b1v};
          f32x4 A12 = {b2v,b2v,b2v,b2v}, A13 = {b3v,b3v,b3v,b3v};
          MFMA(A00, as0, w0); MFMA(A10, as1, w0);
          MFMA(A01, as0, w1); MFMA(A11, as1, w1);
          MFMA(A02, as0, w2); MFMA(A12, as1, w2);
          MFMA(A03, as0, w3); MFMA(A13, as1, w3);
          MFMA_FENCE4(A00, A01, A02, A03);
          MFMA_FENCE4(A10, A11, A12, A13);
#pragma unroll
          for (int r2 = 0; r2 < 4; ++r2) {
            const int row = (kg * 4 + r2) * HSTR;
            s_workA[row + (nbase + 0) * 16 + ln16] = f2b(fmaxf(A00[r2], 0.f));
            s_workA[row + (nbase + 1) * 16 + ln16] = f2b(fmaxf(A01[r2], 0.f));
            s_workA[row + (nbase + 2) * 16 + ln16] = f2b(fmaxf(A02[r2], 0.f));
            s_workA[row + (nbase + 3) * 16 + ln16] = f2b(fmaxf(A03[r2], 0.f));
            s_workB[row + (nbase + 0) * 16 + ln16] = f2b(fmaxf(A10[r2], 0.f));
            s_workB[row + (nbase + 1) * 16 + ln16] = f2b(fmaxf(A11[r2], 0.f));
            s_workB[row + (nbase + 2) * 16 + ln16] = f2b(fmaxf(A12[r2], 0.f));
            s_workB[row + (nbase + 3) * 16 + ln16] = f2b(fmaxf(A13[r2], 0.f));
          }
        }
      }
      {  // secD dual + softmax -> s_ca[g]
#pragma unroll
        for (int nb = 0; nb < 2; ++nb) {
          const int n = nb * 16 + ln16;
          const u16x8 w0 = *(const u16x8*)&wsd[WC_CAA + n * 128 + 0 * 32 + k0];
          const u16x8 w1 = *(const u16x8*)&wsd[WC_CAA + n * 128 + 1 * 32 + k0];
          const u16x8 w2 = *(const u16x8*)&wsd[WC_CAA + n * 128 + 2 * 32 + k0];
          const u16x8 w3 = *(const u16x8*)&wsd[WC_CAA + n * 128 + 3 * 32 + k0];
          const u16x8 h00 = *(const u16x8*)&s_workA[ln16 * HSTR + 0 * 32 + k0];
          const u16x8 h01 = *(const u16x8*)&s_workA[ln16 * HSTR + 1 * 32 + k0];
          const u16x8 h02 = *(const u16x8*)&s_workA[ln16 * HSTR + 2 * 32 + k0];
          const u16x8 h03 = *(const u16x8*)&s_workA[ln16 * HSTR + 3 * 32 + k0];
          const u16x8 h10 = *(const u16x8*)&s_workB[ln16 * HSTR + 0 * 32 + k0];
          const u16x8 h11 = *(const u16x8*)&s_workB[ln16 * HSTR + 1 * 32 + k0];
          const u16x8 h12 = *(const u16x8*)&s_workB[ln16 * HSTR + 2 * 32 + k0];
          const u16x8 h13 = *(const u16x8*)&s_workB[ln16 * HSTR + 3 * 32 + k0];
          const float bias = bc2[n];
          f32x4 acc0 = {bias, bias, bias, bias};
          f32x4 acc1 = {bias, bias, bias, bias};
          MFMA(acc0, h00, w0); MFMA(acc1, h10, w0);
          MFMA(acc0, h01, w1); MFMA(acc1, h11, w1);
          MFMA(acc0, h02, w2); MFMA(acc1, h12, w2);
          MFMA(acc0, h03, w3); MFMA(acc1, h13, w3);
          MFMA_FENCE2(acc0, acc1);
          const f32x4 rp0 = nb ? pe01 : pe00;
          const f32x4 rp1 = nb ? pe11 : pe10;
          float mx = fmaxf(fmaxf(acc0[0], acc0[1]), fmaxf(acc0[2], acc0[3]));
          mx = fmaxf(mx, __shfl_xor(mx, 16));
          mx = fmaxf(mx, __shfl_xor(mx, 32));
          float sum = 0.f, o = 0.f;
#pragma unroll
          for (int r2 = 0; r2 < 4; ++r2) {
            const int row = kg * 4 + r2;
            const float e = __expf(acc0[r2] - mx);
            sum += e;
            o = fmaf(e, b2f(s_ub[0][512 + row * 32 + n]) + rp0[r2], o);
          }
          sum += __shfl_xor(sum, 16); o += __shfl_xor(o, 16);
          sum += __shfl_xor(sum, 32); o += __shfl_xor(o, 32);
          if (kg == 0) s_ca[0][n] = o / sum;
          float mx1 = fmaxf(fmaxf(acc1[0], acc1[1]), fmaxf(acc1[2], acc1[3]));
          mx1 = fmaxf(mx1, __shfl_xor(mx1, 16));
          mx1 = fmaxf(mx1, __shfl_xor(mx1, 32));
          float sum1 = 0.f, o1 = 0.f;
#pragma unroll
          for (int r2 = 0; r2 < 4; ++r2) {
            const int row = kg * 4 + r2;
            const float e = __expf(acc1[r2] - mx1);
            sum1 += e;
            o1 = fmaf(e, b2f(s_ub[1][512 + row * 32 + n]) + rp1[r2], o1);
          }
          sum1 += __shfl_xor(sum1, 16); o1 += __shfl_xor(o1, 16);
          sum1 += __shfl_xor(sum1, 32); o1 += __shfl_xor(o1, 32);
          if (kg == 0) s_ca[1][n] = o1 / sum1;
        }
      }
      {  // im / ep chain: half gH = its batch; width-32 shuffles in-half
        const int h = lh;
        const int bD = b0 + gH;
        const float cav = s_ca[gH][h];
        if (s < 8) {
          float a = p.im_b1[h];
          for (int i2 = 0; i2 < 32; ++i2) a = fmaf(__shfl(cav, i2, 32), iw1[i2 * 32 + h], a);
          const float m1 = fmaxf(a, 0.f);
          a = p.im_b2[h];
          for (int i2 = 0; i2 < 32; ++i2) a = fmaf(__shfl(m1, i2, 32), iw2[i2 * 32 + h], a);
          const float m2 = fmaxf(a, 0.f);
          float p0 = m2 * iw3[h * 3 + 0];
          float p1 = m2 * iw3[h * 3 + 1];
          float p2 = m2 * iw3[h * 3 + 2];
#pragma unroll
          for (int m = 1; m < 32; m <<= 1) {
            p0 += __shfl_xor(p0, m, 32);
            p1 += __shfl_xor(p1, m, 32);
            p2 += __shfl_xor(p2, m, 32);
          }
          p0 += p.im_b3[0]; p1 += p.im_b3[1]; p2 += p.im_b3[2];
          const float step = sqrtf(p0 * p0 + p1 * p1 + p2 * p2);
          const float cum = s_cum[gH];
          const float opc0 = s_qry[gH][0] * cum;
          const float opc1 = s_qry[gH][1] * cum;
          const float opc2 = s_qry[gH][2] * cum;
          const float inv = 1.f / step;
          const float tg0 = p0 * inv, tg1 = p1 * inv, tg2 = p2 * inv;
          if (lh == 0) {
            p.o_ms[bD * 8 + s] = step;
            p.o_ip[(bD * 8 + s) * 3 + 0] = opc0 + p0;
            s_op[gH][0] = opc0 + s_qry[gH][0] * step;
          } else if (lh == 1) {
            p.o_ip[(bD * 8 + s) * 3 + 1] = opc1 + p1;
            s_op[gH][1] = opc1 + s_qry[gH][1] * step;
          } else if (lh == 2) {
            p.o_ip[(bD * 8 + s) * 3 + 2] = opc2 + p2;
            s_op[gH][2] = opc2 + s_qry[gH][2] * step;
          } else if (lh == 3) {
            s_cum[gH] = cum + step;
          }
          if (lh < 16) {
            p.o_cs[bD * 128 + s * 16 + lh] = tg0 * rv0 + tg1 * rv1 + tg2 * rv2;
          }
        } else {
          float a = p.ep_b1[h];
          for (int i2 = 0; i2 < 32; ++i2) a = fmaf(__shfl(cav, i2, 32), p.ep_w1[i2 * 32 + h], a);
          a = fmaf(s_qry[gH][0], p.ep_w1[1024 + h], a);
          a = fmaf(s_qry[gH][1], p.ep_w1[1056 + h], a);
          a = fmaf(s_qry[gH][2], p.ep_w1[1088 + h], a);
          const float e1 = fmaxf(a, 0.f);
          a = p.ep_b2[h];
          for (int i2 = 0; i2 < 32; ++i2) a = fmaf(__shfl(e1, i2, 32), p.ep_w2[i2 * 32 + h], a);
          const float e2 = fmaxf(a, 0.f);
          float pp = e2 * p.ep_w3[h];
#pragma unroll
          for (int m = 1; m < 32; m <<= 1) pp += __shfl_xor(pp, m, 32);
          if (lh == 0) {
            p.o_eps[bD] = pp + p.ep_b3[0];
            p.o_cum[bD] = s_cum[gH];
          }
        }
      }
    }
  }
}

extern "C" void kernel_launch(void* const* d_in, const int* in_sizes, int n_in,
                              void* d_out, int out_size, void* d_ws, size_t ws_size,
                              hipStream_t stream) {
  Params p;
  const float** f = (const float**)(void*)&p;
  for (int i = 0; i < 43; ++i) f[i] = (const float*)d_in[i];
  float* out = (float*)d_out;
  p.o_ld  = out;
  p.o_ms  = out + OFF_MS;
  p.o_cs  = out + OFF_CS;
  p.o_ip  = out + OFF_IP;
  p.o_cum = out + OFF_CUM;
  p.o_eps = out + OFF_EPS;
  unsigned short* ws = (unsigned short*)d_ws;
  prep_kernel<<<dim3(16), dim3(256), 0, stream>>>(p, ws);
  puray_kernel<<<dim3(2048), dim3(64), 0, stream>>>(p, ws);
}